// Round 8
// baseline (1243.916 us; speedup 1.0000x reference)
//
#include <hip/hip_runtime.h>

typedef _Float16 f16;
typedef _Float16 f16x2 __attribute__((ext_vector_type(2)));
typedef _Float16 f16x4 __attribute__((ext_vector_type(4)));
typedef _Float16 f16x8 __attribute__((ext_vector_type(8)));
typedef float f32x4 __attribute__((ext_vector_type(4)));

#define QSCALE 0.08838834764831845f  // DK^-0.5

// ------------------------------------------------------------------
// convert fp32 -> f16 (vectorized x4)
// ------------------------------------------------------------------
__global__ __launch_bounds__(256) void cvt16_kernel(const float* __restrict__ in,
                                                    f16* __restrict__ out, int n4) {
    int i = blockIdx.x * 256 + threadIdx.x;
    if (i >= n4) return;
    f32x4 v = ((const f32x4*)in)[i];
    f16x4 h;
    h[0] = (f16)v[0]; h[1] = (f16)v[1]; h[2] = (f16)v[2]; h[3] = (f16)v[3];
    ((f16x4*)out)[i] = h;
}

// ------------------------------------------------------------------
// transpose fp32 [R][C] -> f16 [C][R]
// ------------------------------------------------------------------
__global__ __launch_bounds__(256) void transpose16_kernel(const float* __restrict__ in,
                                                          f16* __restrict__ out, int R, int C) {
    __shared__ f16 tile[64][66];
    int c0 = blockIdx.x * 64, r0 = blockIdx.y * 64;
    int tid = threadIdx.x;
#pragma unroll
    for (int i = 0; i < 16; ++i) {
        int idx = i * 256 + tid;
        int r = idx >> 6, c = idx & 63;
        tile[r][c] = (f16)in[(long)(r0 + r) * C + (c0 + c)];
    }
    __syncthreads();
#pragma unroll
    for (int i = 0; i < 16; ++i) {
        int idx = i * 256 + tid;
        int orow = idx >> 6, oc = idx & 63;
        out[(long)(c0 + orow) * R + (r0 + oc)] = tile[oc][orow];
    }
}

// ------------------------------------------------------------------
// f16 MFMA GEMM: C[m][n] = sum_k A[m][k] * Bt[n][k]
// 128x128 tile, BK=64, 4 waves (2x2), XOR-swizzled LDS, reg-staged.
// ------------------------------------------------------------------
template <int F16OUT>
__global__ __launch_bounds__(256) void gemm16_kernel(const f16* __restrict__ A,
                                                     const f16* __restrict__ Bt,
                                                     void* __restrict__ Cout,
                                                     int M, int N, int Kd) {
    __shared__ f16 sA[128 * 64];
    __shared__ f16 sB[128 * 64];
    const int tid = threadIdx.x;
    const int lane = tid & 63, wv = tid >> 6;
    const int wm = wv >> 1, wn = wv & 1;
    const int m0 = blockIdx.y * 128, n0 = blockIdx.x * 128;
    const int lrow = lane & 15, lk = lane >> 4;
    f32x4 acc[4][4] = {};
    for (int k0 = 0; k0 < Kd; k0 += 64) {
        __syncthreads();
#pragma unroll
        for (int j = 0; j < 4; ++j) {
            int P = (tid + j * 256) * 16;
            int row = P >> 7;
            int sw = P ^ ((row & 7) << 4);
            int koff = P & 127;
            const char* ga = (const char*)(A + (long)(m0 + row) * Kd + k0) + koff;
            *(f32x4*)((char*)sA + sw) = *(const f32x4*)ga;
            const char* gb = (const char*)(Bt + (long)(n0 + row) * Kd + k0) + koff;
            *(f32x4*)((char*)sB + sw) = *(const f32x4*)gb;
        }
        __syncthreads();
#pragma unroll
        for (int kk = 0; kk < 2; ++kk) {
            f16x8 af[4], bf[4];
#pragma unroll
            for (int i = 0; i < 4; ++i) {
                int arow = wm * 64 + i * 16 + lrow;
                int abyte = arow * 128 + kk * 64 + lk * 16;
                af[i] = *(const f16x8*)((const char*)sA + (abyte ^ ((arow & 7) << 4)));
                int brow = wn * 64 + i * 16 + lrow;
                int bbyte = brow * 128 + kk * 64 + lk * 16;
                bf[i] = *(const f16x8*)((const char*)sB + (bbyte ^ ((brow & 7) << 4)));
            }
#pragma unroll
            for (int i = 0; i < 4; ++i)
#pragma unroll
                for (int j = 0; j < 4; ++j)
                    acc[i][j] = __builtin_amdgcn_mfma_f32_16x16x32_f16(af[i], bf[j], acc[i][j], 0, 0, 0);
        }
    }
#pragma unroll
    for (int i = 0; i < 4; ++i) {
        int gm_base = m0 + wm * 64 + i * 16 + lk * 4;
#pragma unroll
        for (int j = 0; j < 4; ++j) {
            int gn = n0 + wn * 64 + j * 16 + lrow;
#pragma unroll
            for (int r = 0; r < 4; ++r) {
                long idx = (long)(gm_base + r) * N + gn;
                if (F16OUT) ((f16*)Cout)[idx] = (f16)acc[i][j][r];
                else        ((float*)Cout)[idx] = acc[i][j][r];
            }
        }
    }
}

// ------------------------------------------------------------------
// ba = x @ w_ba   (fp32)
// ------------------------------------------------------------------
__global__ __launch_bounds__(256) void ba_gemm_kernel(const float* __restrict__ x,
                                                      const float* __restrict__ w,
                                                      float* __restrict__ ba) {
    __shared__ float xs[16][256];
    int tid = threadIdx.x;
    int t0 = blockIdx.x * 16;
    int o = tid & 63, tg = tid >> 6;
    float acc[4] = {0.f, 0.f, 0.f, 0.f};
    for (int kc = 0; kc < 2048; kc += 256) {
        __syncthreads();
#pragma unroll
        for (int i = 0; i < 16; ++i) {
            int idx = i * 256 + tid;
            int tok = idx >> 8, k = idx & 255;
            xs[tok][k] = x[(long)(t0 + tok) * 2048 + kc + k];
        }
        __syncthreads();
        for (int k = 0; k < 256; ++k) {
            float wv = w[(long)(kc + k) * 64 + o];
#pragma unroll
            for (int j = 0; j < 4; ++j) acc[j] += xs[tg * 4 + j][k] * wv;
        }
    }
#pragma unroll
    for (int j = 0; j < 4; ++j) ba[(long)(t0 + tg * 4 + j) * 64 + o] = acc[j];
}

// ------------------------------------------------------------------
// depthwise causal conv(K=4) + bias + SiLU (+ L2norm for q/k heads)
// ------------------------------------------------------------------
__global__ __launch_bounds__(256) void conv_kernel(const f16* __restrict__ qkvz,
                                                   const float* __restrict__ cw,
                                                   const float* __restrict__ cb,
                                                   f16* __restrict__ qh,
                                                   f16* __restrict__ kh,
                                                   f16* __restrict__ vh) {
    __shared__ float Lin[35 * 128];
    __shared__ float Lout[32 * 128];
    __shared__ float Lsc[32];
    int g = blockIdx.x;
    int s0 = blockIdx.y * 32;
    int b = blockIdx.z;
    int tid = threadIdx.x;
    int colbase, chbase;
    f16* outp;
    bool donorm;
    float nmul;
    if (g < 16) {
        colbase = g * 768; chbase = g * 128;
        outp = qh + (((long)b * 16 + g) * 2048 + s0) * 128;
        donorm = true; nmul = QSCALE;
    } else if (g < 32) {
        int hk = g - 16;
        colbase = hk * 768 + 128; chbase = 2048 + hk * 128;
        outp = kh + (((long)b * 16 + hk) * 2048 + s0) * 128;
        donorm = true; nmul = 1.f;
    } else {
        int hv = g - 32;
        colbase = (hv >> 1) * 768 + 256 + (hv & 1) * 128; chbase = 4096 + hv * 128;
        outp = vh + (((long)b * 32 + hv) * 2048 + s0) * 128;
        donorm = false; nmul = 1.f;
    }
    for (int idx = tid; idx < 35 * 128; idx += 256) {
        int sr = idx >> 7, c = idx & 127;
        int s = s0 + sr - 3;
        Lin[idx] = (s >= 0) ? (float)qkvz[((long)b * 2048 + s) * 12288 + colbase + c] : 0.f;
    }
    __syncthreads();
    int c = tid & 127, sg = tid >> 7;
    float w0 = cw[(chbase + c) * 4 + 0];
    float w1 = cw[(chbase + c) * 4 + 1];
    float w2 = cw[(chbase + c) * 4 + 2];
    float w3 = cw[(chbase + c) * 4 + 3];
    float bias = cb[chbase + c];
#pragma unroll
    for (int j = 0; j < 16; ++j) {
        int sl = sg * 16 + j;
        float v = w0 * Lin[sl * 128 + c] + w1 * Lin[(sl + 1) * 128 + c] +
                  w2 * Lin[(sl + 2) * 128 + c] + w3 * Lin[(sl + 3) * 128 + c] + bias;
        v = v / (1.f + expf(-v));  // SiLU
        Lout[sl * 128 + c] = v;
    }
    __syncthreads();
    if (donorm) {
        int token = tid >> 3, part = tid & 7;
        float ss = 0.f;
#pragma unroll
        for (int i = 0; i < 16; ++i) {
            float v = Lout[token * 128 + part * 16 + i];
            ss += v * v;
        }
        ss += __shfl_xor(ss, 1); ss += __shfl_xor(ss, 2); ss += __shfl_xor(ss, 4);
        if (part == 0) Lsc[token] = rsqrtf(ss + 1e-6f) * nmul;
        __syncthreads();
#pragma unroll
        for (int j = 0; j < 16; ++j) {
            int sl = sg * 16 + j;
            outp[(long)sl * 128 + c] = (f16)(Lout[sl * 128 + c] * Lsc[sl]);
        }
    } else {
#pragma unroll
        for (int j = 0; j < 16; ++j) {
            int sl = sg * 16 + j;
            outp[(long)sl * 128 + c] = (f16)Lout[sl * 128 + c];
        }
    }
}

// ------------------------------------------------------------------
// eg = exp(g), beta = sigmoid(b)
// ------------------------------------------------------------------
__global__ __launch_bounds__(256) void gb_kernel(const float* __restrict__ ba,
                                                 const float* __restrict__ a_log,
                                                 const float* __restrict__ dt_bias,
                                                 float* __restrict__ eg,
                                                 float* __restrict__ bt) {
    int idx = blockIdx.x * 256 + threadIdx.x;  // ((b*32+hv)*2048 + s)
    if (idx >= 2 * 32 * 2048) return;
    int s = idx & 2047;
    int hv = (idx >> 11) & 31;
    int b = idx >> 16;
    int gg = hv & 1, hk = hv >> 1;
    long base = ((long)b * 2048 + s) * 64 + hk * 4;
    float bv = ba[base + gg];
    float av = ba[base + 2 + gg];
    float xx = av + dt_bias[hv];
    float sp = (xx > 20.f) ? xx : log1pf(expf(xx));
    float gv = -expf(a_log[hv]) * sp;
    eg[idx] = expf(gv);
    bt[idx] = 1.f / (1.f + expf(-bv));
}

// ------------------------------------------------------------------
// 16-lane DPP row sums (constant-ctrl templated; interleaved x4 for ILP)
// ------------------------------------------------------------------
__device__ __forceinline__ float rowsum16(float x) {
    int v;
    v = __float_as_int(x);
    x += __int_as_float(__builtin_amdgcn_update_dpp(v, v, 0x121, 0xF, 0xF, false));
    v = __float_as_int(x);
    x += __int_as_float(__builtin_amdgcn_update_dpp(v, v, 0x122, 0xF, 0xF, false));
    v = __float_as_int(x);
    x += __int_as_float(__builtin_amdgcn_update_dpp(v, v, 0x124, 0xF, 0xF, false));
    v = __float_as_int(x);
    x += __int_as_float(__builtin_amdgcn_update_dpp(v, v, 0x128, 0xF, 0xF, false));
    return x;
}
template <int CTRL>
__device__ __forceinline__ void dpp_add4(float& a, float& b, float& c, float& d) {
    int va = __float_as_int(a), vb = __float_as_int(b), vc = __float_as_int(c), vd = __float_as_int(d);
    a += __int_as_float(__builtin_amdgcn_update_dpp(va, va, CTRL, 0xF, 0xF, false));
    b += __int_as_float(__builtin_amdgcn_update_dpp(vb, vb, CTRL, 0xF, 0xF, false));
    c += __int_as_float(__builtin_amdgcn_update_dpp(vc, vc, CTRL, 0xF, 0xF, false));
    d += __int_as_float(__builtin_amdgcn_update_dpp(vd, vd, CTRL, 0xF, 0xF, false));
}
__device__ __forceinline__ void rowsum16x4(float& a, float& b, float& c, float& d) {
    dpp_add4<0x121>(a, b, c, d);
    dpp_add4<0x122>(a, b, c, d);
    dpp_add4<0x124>(a, b, c, d);
    dpp_add4<0x128>(a, b, c, d);
}

// ------------------------------------------------------------------
// cross_kernel: per (b,hv,grp of 4 steps) precompute coeffs (see r6).
// ------------------------------------------------------------------
__global__ __launch_bounds__(256) void cross_kernel(const f16* __restrict__ qh,
                                                    const f16* __restrict__ kh,
                                                    const float* __restrict__ eg,
                                                    const float* __restrict__ bt,
                                                    float* __restrict__ scal) {
    __shared__ float dots[16];
    int bid = blockIdx.x;
    int grp0 = (bid & 127) * 4;
    int hv = (bid >> 7) & 31;
    int b = bid >> 12;
    int bh = b * 16 + (hv >> 1);
    int tid = threadIdx.x;
    int slot = tid >> 4, dkg = tid & 15;
    const unsigned long long AI = 0x3333222110333221ull;
    const unsigned long long BJ = 0x3210210100210100ull;
    int ii = (int)((AI >> (slot * 4)) & 15);
    int jj = (int)((BJ >> (slot * 4)) & 15);
    const f16* abase = (slot < 6) ? kh : qh;
    const float* egp = eg + ((long)b * 32 + hv) * 2048;
    const float* btp = bt + ((long)b * 32 + hv) * 2048;

    for (int gl = 0; gl < 4; ++gl) {
        int grp = grp0 + gl;
        int t0 = grp * 4;
        f16x8 av = *(const f16x8*)(abase + ((long)bh * 2048 + t0 + ii) * 128 + dkg * 8);
        f16x8 bv = *(const f16x8*)(kh + ((long)bh * 2048 + t0 + jj) * 128 + dkg * 8);
        float d = 0.f;
#pragma unroll
        for (int e = 0; e < 8; ++e) d = fmaf((float)av[e], (float)bv[e], d);
        d = rowsum16(d);
        if (dkg == 0) dots[slot] = d;
        __syncthreads();
        if (tid == 0) {
            float e0 = egp[t0], e1 = egp[t0 + 1], e2 = egp[t0 + 2], e3 = egp[t0 + 3];
            float P0 = e0, P1 = P0 * e1, P2 = P1 * e2, P3 = P2 * e3;
            float r10 = e1, r21 = e2, r32 = e3;
            float r20 = e1 * e2, r31 = e2 * e3;
            float r30 = r20 * e3;
            float* outp = scal + ((long)(b * 32 + hv) * 512 + grp) * 32;
            f32x4 o0 = {P0, P1, P2, P3};
            f32x4 o1 = {r10 * dots[0], r20 * dots[1], r21 * dots[2], r30 * dots[3]};
            f32x4 o2 = {r31 * dots[4], r32 * dots[5], dots[6], r10 * dots[7]};
            f32x4 o3 = {dots[8], r20 * dots[9], r21 * dots[10], dots[11]};
            f32x4 o4 = {r30 * dots[12], r31 * dots[13], r32 * dots[14], dots[15]};
            f32x4 o5 = {btp[t0], btp[t0 + 1], btp[t0 + 2], btp[t0 + 3]};
            f32x4 o6 = {r30, r31, r32, 0.f};  // R_j = P3/P_j
            ((f32x4*)outp)[0] = o0; ((f32x4*)outp)[1] = o1; ((f32x4*)outp)[2] = o2;
            ((f32x4*)outp)[3] = o3; ((f32x4*)outp)[4] = o4; ((f32x4*)outp)[5] = o5;
            ((f32x4*)outp)[6] = o6;
        }
        __syncthreads();
    }
}

// ------------------------------------------------------------------
// gated delta scan, 4-step blocked, f16 LDS, 1 dv-col per thread.
// block 256 = 16 dkg x 16 colq; grid 512 = (b, hv, vs in [0,8))
// 2 blocks/CU -> 2 waves/SIMD for latency hiding.
// ------------------------------------------------------------------
#define CH 32
#define NG 8  // groups of 4 per chunk

__global__ __launch_bounds__(256, 2) void scan_kernel(const f16* __restrict__ qh,
                                                      const f16* __restrict__ kh,
                                                      const f16* __restrict__ vh,
                                                      const float* __restrict__ scal,
                                                      f16* __restrict__ o) {
    __shared__ f16 Lk[CH * 128];
    __shared__ f16 Lq[CH * 128];
    __shared__ f16 Lv[CH * 16];

    int bid = blockIdx.x;
    int vs = bid & 7;
    int hv = (bid >> 3) & 31;
    int b = bid >> 8;
    int tid = threadIdx.x;
    int dkg = tid & 15, colq = tid >> 4;
    int c0 = vs * 16 + colq;
    const f16* kp = kh + ((long)b * 16 + (hv >> 1)) * 2048 * 128;
    const f16* qp = qh + ((long)b * 16 + (hv >> 1)) * 2048 * 128;
    const f16* vp = vh + ((long)b * 32 + hv) * 2048 * 128;
    const float* scp = scal + ((long)(b * 32 + hv) * 512) * 32;
    f16* op = o + ((long)b * 2048 * 32 + hv) * 128 + c0;

    f16x8 rk0, rk1, rq0, rq1;
    f16x2 rv;
    auto issue_loads = [&](int c) {
        long base = (long)c * CH * 128;
        rk0 = *(const f16x8*)(kp + base + tid * 8);
        rk1 = *(const f16x8*)(kp + base + 2048 + tid * 8);
        rq0 = *(const f16x8*)(qp + base + tid * 8);
        rq1 = *(const f16x8*)(qp + base + 2048 + tid * 8);
        rv = *(const f16x2*)(vp + base + (tid >> 3) * 128 + vs * 16 + (tid & 7) * 2);
    };
    auto commit = [&]() {
        *(f16x8*)(Lk + tid * 8) = rk0;
        *(f16x8*)(Lk + 2048 + tid * 8) = rk1;
        *(f16x8*)(Lq + tid * 8) = rq0;
        *(f16x8*)(Lq + 2048 + tid * 8) = rq1;
        *(f16x2*)(Lv + (tid >> 3) * 16 + (tid & 7) * 2) = rv;
    };

    float St[8] = {0.f, 0.f, 0.f, 0.f, 0.f, 0.f, 0.f, 0.f};

    issue_loads(0);
    commit();
    __syncthreads();

    // scalar coeffs for group 0
    f32x4 s0, s1, s2, s3, s4, s5, s6;
    {
        const f32x4* sq = (const f32x4*)scp;
        s0 = sq[0]; s1 = sq[1]; s2 = sq[2]; s3 = sq[3]; s4 = sq[4]; s5 = sq[5]; s6 = sq[6];
    }

    for (int c = 0; c < 2048 / CH; ++c) {
        if (c + 1 < 2048 / CH) issue_loads(c + 1);
#pragma unroll
        for (int g = 0; g < NG; ++g) {
            int gg = c * NG + g;
            // prefetch next group's coeffs (VMEM pipe; unrolled loop renames regs)
            int ng = (gg + 1 < 512) ? gg + 1 : gg;
            const f32x4* nq = (const f32x4*)(scp + (long)ng * 32);
            f32x4 t0v = nq[0], t1v = nq[1], t2v = nq[2], t3v = nq[3], t4v = nq[4], t5v = nq[5], t6v = nq[6];

            int sb = g * 4;
            f16x8 hk[4], hq[4];
            f16 vvh[4];
#pragma unroll
            for (int i = 0; i < 4; ++i) {
                hk[i] = *(const f16x8*)(Lk + (sb + i) * 128 + dkg * 8);
                hq[i] = *(const f16x8*)(Lq + (sb + i) * 128 + dkg * 8);
                vvh[i] = Lv[(sb + i) * 16 + colq];
            }

            // 8 independent dot chains (4 a=k.S, 4 c=q.S), f16 ops via fma_mix
            float a0 = 0.f, a1 = 0.f, a2 = 0.f, a3 = 0.f;
            float c0v = 0.f, c1v = 0.f, c2v = 0.f, c3v = 0.f;
#pragma unroll
            for (int e = 0; e < 8; ++e) {
                float st = St[e];
                a0 = fmaf((float)hk[0][e], st, a0);
                a1 = fmaf((float)hk[1][e], st, a1);
                a2 = fmaf((float)hk[2][e], st, a2);
                a3 = fmaf((float)hk[3][e], st, a3);
                c0v = fmaf((float)hq[0][e], st, c0v);
                c1v = fmaf((float)hq[1][e], st, c1v);
                c2v = fmaf((float)hq[2][e], st, c2v);
                c3v = fmaf((float)hq[3][e], st, c3v);
            }
            rowsum16x4(a0, a1, a2, a3);
            rowsum16x4(c0v, c1v, c2v, c3v);

            float P0 = s0[0], P1 = s0[1], P2 = s0[2], P3 = s0[3];
            float KK10 = s1[0], KK20 = s1[1], KK21 = s1[2], KK30 = s1[3];
            float KK31 = s2[0], KK32 = s2[1], QK00 = s2[2], QK10 = s2[3];
            float QK11 = s3[0], QK20 = s3[1], QK21 = s3[2], QK22 = s3[3];
            float QK30 = s4[0], QK31 = s4[1], QK32 = s4[2], QK33 = s4[3];
            float B0 = s5[0], B1 = s5[1], B2 = s5[2], B3 = s5[3];
            float R0 = s6[0], R1 = s6[1], R2 = s6[2];

            float x0 = (float)vvh[0], x1 = (float)vvh[1], x2 = (float)vvh[2], x3 = (float)vvh[3];
            float d0 = B0 * (x0 - P0 * a0);
            float d1 = B1 * (x1 - P1 * a1 - KK10 * d0);
            float d2 = B2 * (x2 - P2 * a2 - KK20 * d0 - KK21 * d1);
            float d3 = B3 * (x3 - P3 * a3 - KK30 * d0 - KK31 * d1 - KK32 * d2);
            float o0 = fmaf(QK00, d0, P0 * c0v);
            float o1 = P1 * c1v + QK10 * d0 + QK11 * d1;
            float o2 = P2 * c2v + QK20 * d0 + QK21 * d1 + QK22 * d2;
            float o3 = P3 * c3v + QK30 * d0 + QK31 * d1 + QK32 * d2 + QK33 * d3;

            // state update: S = P3*S + sum_j (R_j*d_j) k_j   (fma_mix on k)
            float w0 = R0 * d0, w1 = R1 * d1, w2 = R2 * d2, w3 = d3;
#pragma unroll
            for (int e = 0; e < 8; ++e) {
                float acc = w3 * (float)hk[3][e];
                acc = fmaf(w2, (float)hk[2][e], acc);
                acc = fmaf(w1, (float)hk[1][e], acc);
                acc = fmaf(w0, (float)hk[0][e], acc);
                St[e] = fmaf(P3, St[e], acc);
            }

            if (dkg == 0) {
                long tb = (long)(c * CH + sb) * 4096;
                op[tb] = (f16)o0;
                op[tb + 4096] = (f16)o1;
                op[tb + 8192] = (f16)o2;
                op[tb + 12288] = (f16)o3;
            }
            s0 = t0v; s1 = t1v; s2 = t2v; s3 = t3v; s4 = t4v; s5 = t5v; s6 = t6v;
        }
        __syncthreads();
        if (c + 1 < 2048 / CH) commit();
        __syncthreads();
    }
}

// ------------------------------------------------------------------
// y = rmsnorm(o * silu(z)) * norm_w  -> f16
// ------------------------------------------------------------------
__global__ __launch_bounds__(256) void gate_kernel(const f16* __restrict__ o,
                                                   const f16* __restrict__ qkvz,
                                                   const float* __restrict__ norm_w,
                                                   f16* __restrict__ y) {
    int token = blockIdx.x;  // b*2048 + s
    int tid = threadIdx.x;
    int hv = tid >> 3, part = tid & 7;
    int dv0 = part * 16;
    const f16* orow = o + ((long)token * 32 + hv) * 128 + dv0;
    long zcol = (long)(hv >> 1) * 768 + 512 + (hv & 1) * 128 + dv0;
    const f16* zrow = qkvz + (long)token * 12288 + zcol;
    float yv[16];
    float ss = 0.f;
#pragma unroll
    for (int i = 0; i < 16; ++i) {
        float ov = (float)orow[i];
        float zv = (float)zrow[i];
        float gt = zv / (1.f + expf(-zv));
        float v = ov * gt;
        yv[i] = v;
        ss += v * v;
    }
    ss += __shfl_xor(ss, 1); ss += __shfl_xor(ss, 2); ss += __shfl_xor(ss, 4);
    float scale = rsqrtf(ss * (1.f / 128.f) + 1e-6f);
    f16* yrow = y + (long)token * 4096 + hv * 128 + dv0;
#pragma unroll
    for (int i = 0; i < 16; ++i) yrow[i] = (f16)(yv[i] * scale * norm_w[dv0 + i]);
}

// ------------------------------------------------------------------
// Workspace (242 MB, time-aliased):
//   [0,96)        qkvz16           (gemm1 -> gate)
//   [96,112)      x16              (prep -> gemm1)
//   [112,160)     WT               (prep -> gemm1)
//   [96,128)      ob f16           (scan -> gate)   — over dead x16+part of WT
//   [128,132)     scal f32 4MB     (cross -> scan)  — over dead WT
//   [160,176)     WTo              (prep -> gemm2)
//   [176,240)     qh/kh/vh         (conv -> scan); [176,208) reused as y16
//   [240,242)     bab/egb/btb
// ------------------------------------------------------------------
extern "C" void kernel_launch(void* const* d_in, const int* in_sizes, int n_in,
                              void* d_out, int out_size, void* d_ws, size_t ws_size,
                              hipStream_t stream) {
    const float* x       = (const float*)d_in[0];
    const float* w_qkvz  = (const float*)d_in[1];
    const float* w_ba    = (const float*)d_in[2];
    const float* conv_w  = (const float*)d_in[3];
    const float* conv_b  = (const float*)d_in[4];
    const float* a_log   = (const float*)d_in[5];
    const float* dt_bias = (const float*)d_in[6];
    const float* norm_w  = (const float*)d_in[7];
    const float* w_o     = (const float*)d_in[8];
    float* out = (float*)d_out;

    char* ws = (char*)d_ws;
    const size_t MB = 1024 * 1024;
    f16*   qkvz16 = (f16*)ws;                      // 96 MB
    f16*   x16    = (f16*)(ws + 96 * MB);          // 16 MB
    f16*   WT     = (f16*)(ws + 112 * MB);         // 48 MB
    f16*   ob     = (f16*)(ws + 96 * MB);          // 32 MB (after gemm1)
    float* scal   = (float*)(ws + 128 * MB);       // 4 MB (after gemm1)
    f16*   WTo    = (f16*)(ws + 160 * MB);         // 16 MB
    f16*   qh     = (f16*)(ws + 176 * MB);         // 16 MB
    f16*   kh     = (f16*)(ws + 192 * MB);         // 16 MB
    f16*   vh     = (f16*)(ws + 208 * MB);         // 32 MB
    f16*   y16    = (f16*)(ws + 176 * MB);         // 32 MB (after scan)
    float* bab    = (float*)(ws + 240 * MB);       // 1 MB
    float* egb    = (float*)(ws + 241 * MB);       // 0.5 MB
    float* btb    = (float*)(ws + 241 * MB + 512 * 1024);  // 0.5 MB

    // prep
    cvt16_kernel<<<8192, 256, 0, stream>>>(x, x16, 4096 * 2048 / 4);
    transpose16_kernel<<<dim3(12288 / 64, 2048 / 64), 256, 0, stream>>>(w_qkvz, WT, 2048, 12288);
    transpose16_kernel<<<dim3(2048 / 64, 4096 / 64), 256, 0, stream>>>(w_o, WTo, 4096, 2048);

    // qkvz = x @ w_qkvz
    gemm16_kernel<1><<<dim3(12288 / 128, 4096 / 128), 256, 0, stream>>>(x16, WT, qkvz16, 4096, 12288, 2048);
    // ba = x @ w_ba
    ba_gemm_kernel<<<256, 256, 0, stream>>>(x, w_ba, bab);

    // conv + silu + l2norm
    conv_kernel<<<dim3(64, 64, 2), 256, 0, stream>>>(qkvz16, conv_w, conv_b, qh, kh, vh);
    // gate scalars
    gb_kernel<<<512, 256, 0, stream>>>(bab, a_log, dt_bias, egb, btb);
    // per-group cross coefficients
    cross_kernel<<<8192, 256, 0, stream>>>(qh, kh, egb, btb, scal);

    // 4-step blocked delta scan (grid 512, 1 col/thread, 2 blocks/CU)
    scan_kernel<<<512, 256, 0, stream>>>(qh, kh, vh, scal, ob);

    // gating + rmsnorm -> y16
    gate_kernel<<<4096, 256, 0, stream>>>(ob, qkvz16, norm_w, y16);

    // out = y @ w_o
    gemm16_kernel<0><<<dim3(2048 / 128, 4096 / 128), 256, 0, stream>>>(y16, WTo, out, 4096, 2048, 4096);
}

// Round 9
// 1206.603 us; speedup vs baseline: 1.0309x; 1.0309x over previous
//
#include <hip/hip_runtime.h>

typedef _Float16 f16;
typedef _Float16 f16x2 __attribute__((ext_vector_type(2)));
typedef _Float16 f16x4 __attribute__((ext_vector_type(4)));
typedef _Float16 f16x8 __attribute__((ext_vector_type(8)));
typedef float f32x4 __attribute__((ext_vector_type(4)));

typedef __attribute__((address_space(1))) void gvoid;
typedef __attribute__((address_space(3))) void lvoid;

#define QSCALE 0.08838834764831845f  // DK^-0.5

// ------------------------------------------------------------------
// convert fp32 -> f16 (vectorized x4)
// ------------------------------------------------------------------
__global__ __launch_bounds__(256) void cvt16_kernel(const float* __restrict__ in,
                                                    f16* __restrict__ out, int n4) {
    int i = blockIdx.x * 256 + threadIdx.x;
    if (i >= n4) return;
    f32x4 v = ((const f32x4*)in)[i];
    f16x4 h;
    h[0] = (f16)v[0]; h[1] = (f16)v[1]; h[2] = (f16)v[2]; h[3] = (f16)v[3];
    ((f16x4*)out)[i] = h;
}

// ------------------------------------------------------------------
// transpose fp32 [R][C] -> f16 [C][R]
// ------------------------------------------------------------------
__global__ __launch_bounds__(256) void transpose16_kernel(const float* __restrict__ in,
                                                          f16* __restrict__ out, int R, int C) {
    __shared__ f16 tile[64][66];
    int c0 = blockIdx.x * 64, r0 = blockIdx.y * 64;
    int tid = threadIdx.x;
#pragma unroll
    for (int i = 0; i < 16; ++i) {
        int idx = i * 256 + tid;
        int r = idx >> 6, c = idx & 63;
        tile[r][c] = (f16)in[(long)(r0 + r) * C + (c0 + c)];
    }
    __syncthreads();
#pragma unroll
    for (int i = 0; i < 16; ++i) {
        int idx = i * 256 + tid;
        int orow = idx >> 6, oc = idx & 63;
        out[(long)(c0 + orow) * R + (r0 + oc)] = tile[oc][orow];
    }
}

// ------------------------------------------------------------------
// f16 MFMA GEMM: C[m][n] = sum_k A[m][k] * Bt[n][k]
// 128x128 tile, BK=64, 4 waves (2x2).
// global_load_lds width-16 staging, LINEAR LDS (m97 pattern),
// bijective XCD swizzle on tile index (m204).
// ------------------------------------------------------------------
template <int F16OUT>
__global__ __launch_bounds__(256) void gemm16_kernel(const f16* __restrict__ A,
                                                     const f16* __restrict__ Bt,
                                                     void* __restrict__ Cout,
                                                     int M, int N, int Kd) {
    __shared__ f16 sA[128 * 64];
    __shared__ f16 sB[128 * 64];
    const int tid = threadIdx.x;
    const int lane = tid & 63, wv = tid >> 6;
    const int wm = wv >> 1, wn = wv & 1;
    // XCD-aware bijective swizzle of the tile index
    const int nbx = N >> 7;
    const int nwg = (M >> 7) * nbx;
    int bid = blockIdx.x;
    int q = nwg >> 3, r = nwg & 7;
    int xcd = bid & 7, rest = bid >> 3;
    int wgid = (xcd < r ? xcd * (q + 1) : r * (q + 1) + (xcd - r) * q) + rest;
    const int m0 = (wgid / nbx) * 128, n0 = (wgid % nbx) * 128;
    const int lrow = lane & 15, lk = lane >> 4;
    f32x4 acc[4][4] = {};
    for (int k0 = 0; k0 < Kd; k0 += 64) {
        __syncthreads();
#pragma unroll
        for (int j = 0; j < 4; ++j) {
            int P = (tid + j * 256) * 16;        // linear byte offset in 16KB tile
            int row = P >> 7;                    // tile row (128B per row)
            int koff = (P & 127) >> 1;           // k offset in f16 elems
            const f16* ga = A + (long)(m0 + row) * Kd + k0 + koff;
            __builtin_amdgcn_global_load_lds((const gvoid*)ga, (lvoid*)((char*)sA + P), 16, 0, 0);
            const f16* gb = Bt + (long)(n0 + row) * Kd + k0 + koff;
            __builtin_amdgcn_global_load_lds((const gvoid*)gb, (lvoid*)((char*)sB + P), 16, 0, 0);
        }
        __syncthreads();
#pragma unroll
        for (int kk = 0; kk < 2; ++kk) {
            f16x8 af[4], bf[4];
#pragma unroll
            for (int i = 0; i < 4; ++i) {
                int arow = wm * 64 + i * 16 + lrow;
                af[i] = *(const f16x8*)((const char*)sA + arow * 128 + kk * 64 + lk * 16);
                int brow = wn * 64 + i * 16 + lrow;
                bf[i] = *(const f16x8*)((const char*)sB + brow * 128 + kk * 64 + lk * 16);
            }
#pragma unroll
            for (int i = 0; i < 4; ++i)
#pragma unroll
                for (int j = 0; j < 4; ++j)
                    acc[i][j] = __builtin_amdgcn_mfma_f32_16x16x32_f16(af[i], bf[j], acc[i][j], 0, 0, 0);
        }
    }
#pragma unroll
    for (int i = 0; i < 4; ++i) {
        int gm_base = m0 + wm * 64 + i * 16 + lk * 4;
#pragma unroll
        for (int j = 0; j < 4; ++j) {
            int gn = n0 + wn * 64 + j * 16 + lrow;
#pragma unroll
            for (int r2 = 0; r2 < 4; ++r2) {
                long idx = (long)(gm_base + r2) * N + gn;
                if (F16OUT) ((f16*)Cout)[idx] = (f16)acc[i][j][r2];
                else        ((float*)Cout)[idx] = acc[i][j][r2];
            }
        }
    }
}

// ------------------------------------------------------------------
// ba = x @ w_ba   (fp32)
// ------------------------------------------------------------------
__global__ __launch_bounds__(256) void ba_gemm_kernel(const float* __restrict__ x,
                                                      const float* __restrict__ w,
                                                      float* __restrict__ ba) {
    __shared__ float xs[16][256];
    int tid = threadIdx.x;
    int t0 = blockIdx.x * 16;
    int o = tid & 63, tg = tid >> 6;
    float acc[4] = {0.f, 0.f, 0.f, 0.f};
    for (int kc = 0; kc < 2048; kc += 256) {
        __syncthreads();
#pragma unroll
        for (int i = 0; i < 16; ++i) {
            int idx = i * 256 + tid;
            int tok = idx >> 8, k = idx & 255;
            xs[tok][k] = x[(long)(t0 + tok) * 2048 + kc + k];
        }
        __syncthreads();
        for (int k = 0; k < 256; ++k) {
            float wv = w[(long)(kc + k) * 64 + o];
#pragma unroll
            for (int j = 0; j < 4; ++j) acc[j] += xs[tg * 4 + j][k] * wv;
        }
    }
#pragma unroll
    for (int j = 0; j < 4; ++j) ba[(long)(t0 + tg * 4 + j) * 64 + o] = acc[j];
}

// ------------------------------------------------------------------
// depthwise causal conv(K=4) + bias + SiLU (+ L2norm for q/k heads)
// ------------------------------------------------------------------
__global__ __launch_bounds__(256) void conv_kernel(const f16* __restrict__ qkvz,
                                                   const float* __restrict__ cw,
                                                   const float* __restrict__ cb,
                                                   f16* __restrict__ qh,
                                                   f16* __restrict__ kh,
                                                   f16* __restrict__ vh) {
    __shared__ float Lin[35 * 128];
    __shared__ float Lout[32 * 128];
    __shared__ float Lsc[32];
    int g = blockIdx.x;
    int s0 = blockIdx.y * 32;
    int b = blockIdx.z;
    int tid = threadIdx.x;
    int colbase, chbase;
    f16* outp;
    bool donorm;
    float nmul;
    if (g < 16) {
        colbase = g * 768; chbase = g * 128;
        outp = qh + (((long)b * 16 + g) * 2048 + s0) * 128;
        donorm = true; nmul = QSCALE;
    } else if (g < 32) {
        int hk = g - 16;
        colbase = hk * 768 + 128; chbase = 2048 + hk * 128;
        outp = kh + (((long)b * 16 + hk) * 2048 + s0) * 128;
        donorm = true; nmul = 1.f;
    } else {
        int hv = g - 32;
        colbase = (hv >> 1) * 768 + 256 + (hv & 1) * 128; chbase = 4096 + hv * 128;
        outp = vh + (((long)b * 32 + hv) * 2048 + s0) * 128;
        donorm = false; nmul = 1.f;
    }
    for (int idx = tid; idx < 35 * 128; idx += 256) {
        int sr = idx >> 7, c = idx & 127;
        int s = s0 + sr - 3;
        Lin[idx] = (s >= 0) ? (float)qkvz[((long)b * 2048 + s) * 12288 + colbase + c] : 0.f;
    }
    __syncthreads();
    int c = tid & 127, sg = tid >> 7;
    float w0 = cw[(chbase + c) * 4 + 0];
    float w1 = cw[(chbase + c) * 4 + 1];
    float w2 = cw[(chbase + c) * 4 + 2];
    float w3 = cw[(chbase + c) * 4 + 3];
    float bias = cb[chbase + c];
#pragma unroll
    for (int j = 0; j < 16; ++j) {
        int sl = sg * 16 + j;
        float v = w0 * Lin[sl * 128 + c] + w1 * Lin[(sl + 1) * 128 + c] +
                  w2 * Lin[(sl + 2) * 128 + c] + w3 * Lin[(sl + 3) * 128 + c] + bias;
        v = v / (1.f + expf(-v));  // SiLU
        Lout[sl * 128 + c] = v;
    }
    __syncthreads();
    if (donorm) {
        int token = tid >> 3, part = tid & 7;
        float ss = 0.f;
#pragma unroll
        for (int i = 0; i < 16; ++i) {
            float v = Lout[token * 128 + part * 16 + i];
            ss += v * v;
        }
        ss += __shfl_xor(ss, 1); ss += __shfl_xor(ss, 2); ss += __shfl_xor(ss, 4);
        if (part == 0) Lsc[token] = rsqrtf(ss + 1e-6f) * nmul;
        __syncthreads();
#pragma unroll
        for (int j = 0; j < 16; ++j) {
            int sl = sg * 16 + j;
            outp[(long)sl * 128 + c] = (f16)(Lout[sl * 128 + c] * Lsc[sl]);
        }
    } else {
#pragma unroll
        for (int j = 0; j < 16; ++j) {
            int sl = sg * 16 + j;
            outp[(long)sl * 128 + c] = (f16)Lout[sl * 128 + c];
        }
    }
}

// ------------------------------------------------------------------
// eg = exp(g), beta = sigmoid(b)
// ------------------------------------------------------------------
__global__ __launch_bounds__(256) void gb_kernel(const float* __restrict__ ba,
                                                 const float* __restrict__ a_log,
                                                 const float* __restrict__ dt_bias,
                                                 float* __restrict__ eg,
                                                 float* __restrict__ bt) {
    int idx = blockIdx.x * 256 + threadIdx.x;  // ((b*32+hv)*2048 + s)
    if (idx >= 2 * 32 * 2048) return;
    int s = idx & 2047;
    int hv = (idx >> 11) & 31;
    int b = idx >> 16;
    int gg = hv & 1, hk = hv >> 1;
    long base = ((long)b * 2048 + s) * 64 + hk * 4;
    float bv = ba[base + gg];
    float av = ba[base + 2 + gg];
    float xx = av + dt_bias[hv];
    float sp = (xx > 20.f) ? xx : log1pf(expf(xx));
    float gv = -expf(a_log[hv]) * sp;
    eg[idx] = expf(gv);
    bt[idx] = 1.f / (1.f + expf(-bv));
}

// ------------------------------------------------------------------
// 16-lane DPP row sums (constant-ctrl templated; interleaved x4 for ILP)
// ------------------------------------------------------------------
__device__ __forceinline__ float rowsum16(float x) {
    int v;
    v = __float_as_int(x);
    x += __int_as_float(__builtin_amdgcn_update_dpp(v, v, 0x121, 0xF, 0xF, false));
    v = __float_as_int(x);
    x += __int_as_float(__builtin_amdgcn_update_dpp(v, v, 0x122, 0xF, 0xF, false));
    v = __float_as_int(x);
    x += __int_as_float(__builtin_amdgcn_update_dpp(v, v, 0x124, 0xF, 0xF, false));
    v = __float_as_int(x);
    x += __int_as_float(__builtin_amdgcn_update_dpp(v, v, 0x128, 0xF, 0xF, false));
    return x;
}
template <int CTRL>
__device__ __forceinline__ void dpp_add4(float& a, float& b, float& c, float& d) {
    int va = __float_as_int(a), vb = __float_as_int(b), vc = __float_as_int(c), vd = __float_as_int(d);
    a += __int_as_float(__builtin_amdgcn_update_dpp(va, va, CTRL, 0xF, 0xF, false));
    b += __int_as_float(__builtin_amdgcn_update_dpp(vb, vb, CTRL, 0xF, 0xF, false));
    c += __int_as_float(__builtin_amdgcn_update_dpp(vc, vc, CTRL, 0xF, 0xF, false));
    d += __int_as_float(__builtin_amdgcn_update_dpp(vd, vd, CTRL, 0xF, 0xF, false));
}
__device__ __forceinline__ void rowsum16x4(float& a, float& b, float& c, float& d) {
    dpp_add4<0x121>(a, b, c, d);
    dpp_add4<0x122>(a, b, c, d);
    dpp_add4<0x124>(a, b, c, d);
    dpp_add4<0x128>(a, b, c, d);
}

// ------------------------------------------------------------------
// cross_kernel: per (b,hv,grp of 4 steps) precompute coeffs (see r6).
// ------------------------------------------------------------------
__global__ __launch_bounds__(256) void cross_kernel(const f16* __restrict__ qh,
                                                    const f16* __restrict__ kh,
                                                    const float* __restrict__ eg,
                                                    const float* __restrict__ bt,
                                                    float* __restrict__ scal) {
    __shared__ float dots[16];
    int bid = blockIdx.x;
    int grp0 = (bid & 127) * 4;
    int hv = (bid >> 7) & 31;
    int b = bid >> 12;
    int bh = b * 16 + (hv >> 1);
    int tid = threadIdx.x;
    int slot = tid >> 4, dkg = tid & 15;
    const unsigned long long AI = 0x3333222110333221ull;
    const unsigned long long BJ = 0x3210210100210100ull;
    int ii = (int)((AI >> (slot * 4)) & 15);
    int jj = (int)((BJ >> (slot * 4)) & 15);
    const f16* abase = (slot < 6) ? kh : qh;
    const float* egp = eg + ((long)b * 32 + hv) * 2048;
    const float* btp = bt + ((long)b * 32 + hv) * 2048;

    for (int gl = 0; gl < 4; ++gl) {
        int grp = grp0 + gl;
        int t0 = grp * 4;
        f16x8 av = *(const f16x8*)(abase + ((long)bh * 2048 + t0 + ii) * 128 + dkg * 8);
        f16x8 bv = *(const f16x8*)(kh + ((long)bh * 2048 + t0 + jj) * 128 + dkg * 8);
        float d = 0.f;
#pragma unroll
        for (int e = 0; e < 8; ++e) d = fmaf((float)av[e], (float)bv[e], d);
        d = rowsum16(d);
        if (dkg == 0) dots[slot] = d;
        __syncthreads();
        if (tid == 0) {
            float e0 = egp[t0], e1 = egp[t0 + 1], e2 = egp[t0 + 2], e3 = egp[t0 + 3];
            float P0 = e0, P1 = P0 * e1, P2 = P1 * e2, P3 = P2 * e3;
            float r10 = e1, r21 = e2, r32 = e3;
            float r20 = e1 * e2, r31 = e2 * e3;
            float r30 = r20 * e3;
            float* outp = scal + ((long)(b * 32 + hv) * 512 + grp) * 32;
            f32x4 o0 = {P0, P1, P2, P3};
            f32x4 o1 = {r10 * dots[0], r20 * dots[1], r21 * dots[2], r30 * dots[3]};
            f32x4 o2 = {r31 * dots[4], r32 * dots[5], dots[6], r10 * dots[7]};
            f32x4 o3 = {dots[8], r20 * dots[9], r21 * dots[10], dots[11]};
            f32x4 o4 = {r30 * dots[12], r31 * dots[13], r32 * dots[14], dots[15]};
            f32x4 o5 = {btp[t0], btp[t0 + 1], btp[t0 + 2], btp[t0 + 3]};
            f32x4 o6 = {r30, r31, r32, 0.f};  // R_j = P3/P_j
            ((f32x4*)outp)[0] = o0; ((f32x4*)outp)[1] = o1; ((f32x4*)outp)[2] = o2;
            ((f32x4*)outp)[3] = o3; ((f32x4*)outp)[4] = o4; ((f32x4*)outp)[5] = o5;
            ((f32x4*)outp)[6] = o6;
        }
        __syncthreads();
    }
}

// ------------------------------------------------------------------
// gated delta scan, 4-step blocked, f16 LDS, 2 dv-cols per thread.
// block 256 = 16 dkg x 16 colq; grid 256 = (b, hv, vs in [0,4))
// (r7 configuration — best measured: 577 us)
// ------------------------------------------------------------------
#define CH 32
#define NG 8  // groups of 4 per chunk

__global__ __launch_bounds__(256, 1) void scan_kernel(const f16* __restrict__ qh,
                                                      const f16* __restrict__ kh,
                                                      const f16* __restrict__ vh,
                                                      const float* __restrict__ scal,
                                                      f16* __restrict__ o) {
    __shared__ f16 Lk[CH * 128];
    __shared__ f16 Lq[CH * 128];
    __shared__ f16 Lv[CH * 32];

    int bid = blockIdx.x;
    int vs = bid & 3;
    int hv = (bid >> 2) & 31;
    int b = bid >> 7;
    int tid = threadIdx.x;
    int dkg = tid & 15, colq = tid >> 4;
    int c0 = vs * 32 + colq * 2;
    const f16* kp = kh + ((long)b * 16 + (hv >> 1)) * 2048 * 128;
    const f16* qp = qh + ((long)b * 16 + (hv >> 1)) * 2048 * 128;
    const f16* vp = vh + ((long)b * 32 + hv) * 2048 * 128;
    const float* scp = scal + ((long)(b * 32 + hv) * 512) * 32;
    f16* op = o + ((long)b * 2048 * 32 + hv) * 128 + c0;

    f16x8 rk0, rk1, rq0, rq1;
    f16x4 rv;
    auto issue_loads = [&](int c) {
        long base = (long)c * CH * 128;
        rk0 = *(const f16x8*)(kp + base + tid * 8);
        rk1 = *(const f16x8*)(kp + base + 2048 + tid * 8);
        rq0 = *(const f16x8*)(qp + base + tid * 8);
        rq1 = *(const f16x8*)(qp + base + 2048 + tid * 8);
        rv = *(const f16x4*)(vp + base + (tid >> 3) * 128 + vs * 32 + (tid & 7) * 4);
    };
    auto commit = [&]() {
        *(f16x8*)(Lk + tid * 8) = rk0;
        *(f16x8*)(Lk + 2048 + tid * 8) = rk1;
        *(f16x8*)(Lq + tid * 8) = rq0;
        *(f16x8*)(Lq + 2048 + tid * 8) = rq1;
        *(f16x4*)(Lv + tid * 4) = rv;
    };

    float St0[8] = {0.f, 0.f, 0.f, 0.f, 0.f, 0.f, 0.f, 0.f};
    float St1[8] = {0.f, 0.f, 0.f, 0.f, 0.f, 0.f, 0.f, 0.f};

    issue_loads(0);
    commit();
    __syncthreads();

    // scalar coeffs for group 0
    f32x4 s0, s1, s2, s3, s4, s5, s6;
    {
        const f32x4* sq = (const f32x4*)scp;
        s0 = sq[0]; s1 = sq[1]; s2 = sq[2]; s3 = sq[3]; s4 = sq[4]; s5 = sq[5]; s6 = sq[6];
    }

    for (int c = 0; c < 2048 / CH; ++c) {
        if (c + 1 < 2048 / CH) issue_loads(c + 1);
        for (int g = 0; g < NG; ++g) {
            int gg = c * NG + g;
            // prefetch next group's coeffs
            int ng = (gg + 1 < 512) ? gg + 1 : gg;
            const f32x4* nq = (const f32x4*)(scp + (long)ng * 32);
            f32x4 t0v = nq[0], t1v = nq[1], t2v = nq[2], t3v = nq[3], t4v = nq[4], t5v = nq[5], t6v = nq[6];

            int sb = g * 4;
            f16x8 hk[4], hq[4];
            f16x2 vv[4];
#pragma unroll
            for (int i = 0; i < 4; ++i) {
                hk[i] = *(const f16x8*)(Lk + (sb + i) * 128 + dkg * 8);
                hq[i] = *(const f16x8*)(Lq + (sb + i) * 128 + dkg * 8);
                vv[i] = *(const f16x2*)(Lv + (sb + i) * 32 + colq * 2);
            }
            float kf[4][8];
#pragma unroll
            for (int i = 0; i < 4; ++i)
#pragma unroll
                for (int e = 0; e < 8; ++e) kf[i][e] = (float)hk[i][e];

            float a0[4], a1[4], c0v[4], c1v[4];
#pragma unroll
            for (int i = 0; i < 4; ++i) {
                float qf[8];
#pragma unroll
                for (int e = 0; e < 8; ++e) qf[e] = (float)hq[i][e];
                float sa0 = 0.f, sa1 = 0.f, sc0 = 0.f, sc1 = 0.f;
#pragma unroll
                for (int e = 0; e < 8; ++e) {
                    sa0 = fmaf(kf[i][e], St0[e], sa0);
                    sa1 = fmaf(kf[i][e], St1[e], sa1);
                    sc0 = fmaf(qf[e], St0[e], sc0);
                    sc1 = fmaf(qf[e], St1[e], sc1);
                }
                a0[i] = sa0; a1[i] = sa1; c0v[i] = sc0; c1v[i] = sc1;
            }
            rowsum16x4(a0[0], a0[1], a0[2], a0[3]);
            rowsum16x4(a1[0], a1[1], a1[2], a1[3]);
            rowsum16x4(c0v[0], c0v[1], c0v[2], c0v[3]);
            rowsum16x4(c1v[0], c1v[1], c1v[2], c1v[3]);

            float P0 = s0[0], P1 = s0[1], P2 = s0[2], P3 = s0[3];
            float KK10 = s1[0], KK20 = s1[1], KK21 = s1[2], KK30 = s1[3];
            float KK31 = s2[0], KK32 = s2[1], QK00 = s2[2], QK10 = s2[3];
            float QK11 = s3[0], QK20 = s3[1], QK21 = s3[2], QK22 = s3[3];
            float QK30 = s4[0], QK31 = s4[1], QK32 = s4[2], QK33 = s4[3];
            float B0 = s5[0], B1 = s5[1], B2 = s5[2], B3 = s5[3];
            float R0 = s6[0], R1 = s6[1], R2 = s6[2];

            // col 0 tail
            float x0 = (float)vv[0][0], x1 = (float)vv[1][0], x2 = (float)vv[2][0], x3 = (float)vv[3][0];
            float d00 = B0 * (x0 - P0 * a0[0]);
            float d01 = B1 * (x1 - P1 * a0[1] - KK10 * d00);
            float d02 = B2 * (x2 - P2 * a0[2] - KK20 * d00 - KK21 * d01);
            float d03 = B3 * (x3 - P3 * a0[3] - KK30 * d00 - KK31 * d01 - KK32 * d02);
            float o00 = fmaf(QK00, d00, P0 * c0v[0]);
            float o01 = P1 * c0v[1] + QK10 * d00 + QK11 * d01;
            float o02 = P2 * c0v[2] + QK20 * d00 + QK21 * d01 + QK22 * d02;
            float o03 = P3 * c0v[3] + QK30 * d00 + QK31 * d01 + QK32 * d02 + QK33 * d03;
            // col 1 tail
            float y0 = (float)vv[0][1], y1 = (float)vv[1][1], y2 = (float)vv[2][1], y3 = (float)vv[3][1];
            float d10 = B0 * (y0 - P0 * a1[0]);
            float d11 = B1 * (y1 - P1 * a1[1] - KK10 * d10);
            float d12 = B2 * (y2 - P2 * a1[2] - KK20 * d10 - KK21 * d11);
            float d13 = B3 * (y3 - P3 * a1[3] - KK30 * d10 - KK31 * d11 - KK32 * d12);
            float o10 = fmaf(QK00, d10, P0 * c1v[0]);
            float o11 = P1 * c1v[1] + QK10 * d10 + QK11 * d11;
            float o12 = P2 * c1v[2] + QK20 * d10 + QK21 * d11 + QK22 * d12;
            float o13 = P3 * c1v[3] + QK30 * d10 + QK31 * d11 + QK32 * d12 + QK33 * d13;

            // state update: S = P3*S + sum_j (R_j*d_j) k_j
            float w00 = R0 * d00, w01 = R1 * d01, w02 = R2 * d02, w03 = d03;
            float w10 = R0 * d10, w11 = R1 * d11, w12 = R2 * d12, w13 = d13;
#pragma unroll
            for (int e = 0; e < 8; ++e) {
                St0[e] = fmaf(P3, St0[e],
                          fmaf(w00, kf[0][e], fmaf(w01, kf[1][e], fmaf(w02, kf[2][e], w03 * kf[3][e]))));
                St1[e] = fmaf(P3, St1[e],
                          fmaf(w10, kf[0][e], fmaf(w11, kf[1][e], fmaf(w12, kf[2][e], w13 * kf[3][e]))));
            }

            if (dkg == 0) {
                long tb = (long)(c * CH + sb) * 4096;
                f16x2 z0; z0[0] = (f16)o00; z0[1] = (f16)o10; *(f16x2*)(op + tb) = z0;
                f16x2 z1; z1[0] = (f16)o01; z1[1] = (f16)o11; *(f16x2*)(op + tb + 4096) = z1;
                f16x2 z2; z2[0] = (f16)o02; z2[1] = (f16)o12; *(f16x2*)(op + tb + 8192) = z2;
                f16x2 z3; z3[0] = (f16)o03; z3[1] = (f16)o13; *(f16x2*)(op + tb + 12288) = z3;
            }
            s0 = t0v; s1 = t1v; s2 = t2v; s3 = t3v; s4 = t4v; s5 = t5v; s6 = t6v;
        }
        __syncthreads();
        if (c + 1 < 2048 / CH) commit();
        __syncthreads();
    }
}

// ------------------------------------------------------------------
// y = rmsnorm(o * silu(z)) * norm_w  -> f16
// ------------------------------------------------------------------
__global__ __launch_bounds__(256) void gate_kernel(const f16* __restrict__ o,
                                                   const f16* __restrict__ qkvz,
                                                   const float* __restrict__ norm_w,
                                                   f16* __restrict__ y) {
    int token = blockIdx.x;  // b*2048 + s
    int tid = threadIdx.x;
    int hv = tid >> 3, part = tid & 7;
    int dv0 = part * 16;
    const f16* orow = o + ((long)token * 32 + hv) * 128 + dv0;
    long zcol = (long)(hv >> 1) * 768 + 512 + (hv & 1) * 128 + dv0;
    const f16* zrow = qkvz + (long)token * 12288 + zcol;
    float yv[16];
    float ss = 0.f;
#pragma unroll
    for (int i = 0; i < 16; ++i) {
        float ov = (float)orow[i];
        float zv = (float)zrow[i];
        float gt = zv / (1.f + expf(-zv));
        float v = ov * gt;
        yv[i] = v;
        ss += v * v;
    }
    ss += __shfl_xor(ss, 1); ss += __shfl_xor(ss, 2); ss += __shfl_xor(ss, 4);
    float scale = rsqrtf(ss * (1.f / 128.f) + 1e-6f);
    f16* yrow = y + (long)token * 4096 + hv * 128 + dv0;
#pragma unroll
    for (int i = 0; i < 16; ++i) yrow[i] = (f16)(yv[i] * scale * norm_w[dv0 + i]);
}

// ------------------------------------------------------------------
// Workspace (242 MB, time-aliased):
//   [0,96)        qkvz16           (gemm1 -> gate)
//   [96,112)      x16              (prep -> gemm1)
//   [112,160)     WT               (prep -> gemm1)
//   [96,128)      ob f16           (scan -> gate)   — over dead x16+part of WT
//   [128,132)     scal f32 4MB     (cross -> scan)  — over dead WT
//   [160,176)     WTo              (prep -> gemm2)
//   [176,240)     qh/kh/vh         (conv -> scan); [176,208) reused as y16
//   [240,242)     bab/egb/btb
// ------------------------------------------------------------------
extern "C" void kernel_launch(void* const* d_in, const int* in_sizes, int n_in,
                              void* d_out, int out_size, void* d_ws, size_t ws_size,
                              hipStream_t stream) {
    const float* x       = (const float*)d_in[0];
    const float* w_qkvz  = (const float*)d_in[1];
    const float* w_ba    = (const float*)d_in[2];
    const float* conv_w  = (const float*)d_in[3];
    const float* conv_b  = (const float*)d_in[4];
    const float* a_log   = (const float*)d_in[5];
    const float* dt_bias = (const float*)d_in[6];
    const float* norm_w  = (const float*)d_in[7];
    const float* w_o     = (const float*)d_in[8];
    float* out = (float*)d_out;

    char* ws = (char*)d_ws;
    const size_t MB = 1024 * 1024;
    f16*   qkvz16 = (f16*)ws;                      // 96 MB
    f16*   x16    = (f16*)(ws + 96 * MB);          // 16 MB
    f16*   WT     = (f16*)(ws + 112 * MB);         // 48 MB
    f16*   ob     = (f16*)(ws + 96 * MB);          // 32 MB (after gemm1)
    float* scal   = (float*)(ws + 128 * MB);       // 4 MB (after gemm1)
    f16*   WTo    = (f16*)(ws + 160 * MB);         // 16 MB
    f16*   qh     = (f16*)(ws + 176 * MB);         // 16 MB
    f16*   kh     = (f16*)(ws + 192 * MB);         // 16 MB
    f16*   vh     = (f16*)(ws + 208 * MB);         // 32 MB
    f16*   y16    = (f16*)(ws + 176 * MB);         // 32 MB (after scan)
    float* bab    = (float*)(ws + 240 * MB);       // 1 MB
    float* egb    = (float*)(ws + 241 * MB);       // 0.5 MB
    float* btb    = (float*)(ws + 241 * MB + 512 * 1024);  // 0.5 MB

    // prep
    cvt16_kernel<<<8192, 256, 0, stream>>>(x, x16, 4096 * 2048 / 4);
    transpose16_kernel<<<dim3(12288 / 64, 2048 / 64), 256, 0, stream>>>(w_qkvz, WT, 2048, 12288);
    transpose16_kernel<<<dim3(2048 / 64, 4096 / 64), 256, 0, stream>>>(w_o, WTo, 4096, 2048);

    // qkvz = x @ w_qkvz   (tiles = 32*96 = 3072)
    gemm16_kernel<1><<<3072, 256, 0, stream>>>(x16, WT, qkvz16, 4096, 12288, 2048);
    // ba = x @ w_ba
    ba_gemm_kernel<<<256, 256, 0, stream>>>(x, w_ba, bab);

    // conv + silu + l2norm
    conv_kernel<<<dim3(64, 64, 2), 256, 0, stream>>>(qkvz16, conv_w, conv_b, qh, kh, vh);
    // gate scalars
    gb_kernel<<<512, 256, 0, stream>>>(bab, a_log, dt_bias, egb, btb);
    // per-group cross coefficients
    cross_kernel<<<8192, 256, 0, stream>>>(qh, kh, egb, btb, scal);

    // 4-step blocked delta scan (r7 config: grid 256, 2 cols/thread)
    scan_kernel<<<256, 256, 0, stream>>>(qh, kh, vh, scal, ob);

    // gating + rmsnorm -> y16
    gate_kernel<<<4096, 256, 0, stream>>>(ob, qkvz16, norm_w, y16);

    // out = y @ w_o   (tiles = 32*16 = 512)
    gemm16_kernel<0><<<512, 256, 0, stream>>>(y16, WTo, out, 4096, 2048, 4096);
}

// Round 11
// 1042.372 us; speedup vs baseline: 1.1934x; 1.1576x over previous
//
#include <hip/hip_runtime.h>

typedef _Float16 f16;
typedef _Float16 f16x2 __attribute__((ext_vector_type(2)));
typedef _Float16 f16x4 __attribute__((ext_vector_type(4)));
typedef _Float16 f16x8 __attribute__((ext_vector_type(8)));
typedef float f32x4 __attribute__((ext_vector_type(4)));

#define QSCALE 0.08838834764831845f  // DK^-0.5

// ------------------------------------------------------------------
// convert fp32 -> f16 (vectorized x4)
// ------------------------------------------------------------------
__global__ __launch_bounds__(256) void cvt16_kernel(const float* __restrict__ in,
                                                    f16* __restrict__ out, int n4) {
    int i = blockIdx.x * 256 + threadIdx.x;
    if (i >= n4) return;
    f32x4 v = ((const f32x4*)in)[i];
    f16x4 h;
    h[0] = (f16)v[0]; h[1] = (f16)v[1]; h[2] = (f16)v[2]; h[3] = (f16)v[3];
    ((f16x4*)out)[i] = h;
}

// ------------------------------------------------------------------
// transpose fp32 [R][C] -> f16 [C][R]
// ------------------------------------------------------------------
__global__ __launch_bounds__(256) void transpose16_kernel(const float* __restrict__ in,
                                                          f16* __restrict__ out, int R, int C) {
    __shared__ f16 tile[64][66];
    int c0 = blockIdx.x * 64, r0 = blockIdx.y * 64;
    int tid = threadIdx.x;
#pragma unroll
    for (int i = 0; i < 16; ++i) {
        int idx = i * 256 + tid;
        int r = idx >> 6, c = idx & 63;
        tile[r][c] = (f16)in[(long)(r0 + r) * C + (c0 + c)];
    }
    __syncthreads();
#pragma unroll
    for (int i = 0; i < 16; ++i) {
        int idx = i * 256 + tid;
        int orow = idx >> 6, oc = idx & 63;
        out[(long)(c0 + orow) * R + (r0 + oc)] = tile[oc][orow];
    }
}

// ------------------------------------------------------------------
// f16 MFMA GEMM (r7 version — reg-staged, XOR-swizzled LDS; measured best)
// ------------------------------------------------------------------
template <int F16OUT>
__global__ __launch_bounds__(256) void gemm16_kernel(const f16* __restrict__ A,
                                                     const f16* __restrict__ Bt,
                                                     void* __restrict__ Cout,
                                                     int M, int N, int Kd) {
    __shared__ f16 sA[128 * 64];
    __shared__ f16 sB[128 * 64];
    const int tid = threadIdx.x;
    const int lane = tid & 63, wv = tid >> 6;
    const int wm = wv >> 1, wn = wv & 1;
    const int m0 = blockIdx.y * 128, n0 = blockIdx.x * 128;
    const int lrow = lane & 15, lk = lane >> 4;
    f32x4 acc[4][4] = {};
    for (int k0 = 0; k0 < Kd; k0 += 64) {
        __syncthreads();
#pragma unroll
        for (int j = 0; j < 4; ++j) {
            int P = (tid + j * 256) * 16;
            int row = P >> 7;
            int sw = P ^ ((row & 7) << 4);
            int koff = P & 127;
            const char* ga = (const char*)(A + (long)(m0 + row) * Kd + k0) + koff;
            *(f32x4*)((char*)sA + sw) = *(const f32x4*)ga;
            const char* gb = (const char*)(Bt + (long)(n0 + row) * Kd + k0) + koff;
            *(f32x4*)((char*)sB + sw) = *(const f32x4*)gb;
        }
        __syncthreads();
#pragma unroll
        for (int kk = 0; kk < 2; ++kk) {
            f16x8 af[4], bf[4];
#pragma unroll
            for (int i = 0; i < 4; ++i) {
                int arow = wm * 64 + i * 16 + lrow;
                int abyte = arow * 128 + kk * 64 + lk * 16;
                af[i] = *(const f16x8*)((const char*)sA + (abyte ^ ((arow & 7) << 4)));
                int brow = wn * 64 + i * 16 + lrow;
                int bbyte = brow * 128 + kk * 64 + lk * 16;
                bf[i] = *(const f16x8*)((const char*)sB + (bbyte ^ ((brow & 7) << 4)));
            }
#pragma unroll
            for (int i = 0; i < 4; ++i)
#pragma unroll
                for (int j = 0; j < 4; ++j)
                    acc[i][j] = __builtin_amdgcn_mfma_f32_16x16x32_f16(af[i], bf[j], acc[i][j], 0, 0, 0);
        }
    }
#pragma unroll
    for (int i = 0; i < 4; ++i) {
        int gm_base = m0 + wm * 64 + i * 16 + lk * 4;
#pragma unroll
        for (int j = 0; j < 4; ++j) {
            int gn = n0 + wn * 64 + j * 16 + lrow;
#pragma unroll
            for (int r = 0; r < 4; ++r) {
                long idx = (long)(gm_base + r) * N + gn;
                if (F16OUT) ((f16*)Cout)[idx] = (f16)acc[i][j][r];
                else        ((float*)Cout)[idx] = acc[i][j][r];
            }
        }
    }
}

// ------------------------------------------------------------------
// ba = x @ w_ba   (fp32)
// ------------------------------------------------------------------
__global__ __launch_bounds__(256) void ba_gemm_kernel(const float* __restrict__ x,
                                                      const float* __restrict__ w,
                                                      float* __restrict__ ba) {
    __shared__ float xs[16][256];
    int tid = threadIdx.x;
    int t0 = blockIdx.x * 16;
    int o = tid & 63, tg = tid >> 6;
    float acc[4] = {0.f, 0.f, 0.f, 0.f};
    for (int kc = 0; kc < 2048; kc += 256) {
        __syncthreads();
#pragma unroll
        for (int i = 0; i < 16; ++i) {
            int idx = i * 256 + tid;
            int tok = idx >> 8, k = idx & 255;
            xs[tok][k] = x[(long)(t0 + tok) * 2048 + kc + k];
        }
        __syncthreads();
        for (int k = 0; k < 256; ++k) {
            float wv = w[(long)(kc + k) * 64 + o];
#pragma unroll
            for (int j = 0; j < 4; ++j) acc[j] += xs[tg * 4 + j][k] * wv;
        }
    }
#pragma unroll
    for (int j = 0; j < 4; ++j) ba[(long)(t0 + tg * 4 + j) * 64 + o] = acc[j];
}

// ------------------------------------------------------------------
// depthwise causal conv(K=4) + bias + SiLU (+ L2norm for q/k heads)
// ------------------------------------------------------------------
__global__ __launch_bounds__(256) void conv_kernel(const f16* __restrict__ qkvz,
                                                   const float* __restrict__ cw,
                                                   const float* __restrict__ cb,
                                                   f16* __restrict__ qh,
                                                   f16* __restrict__ kh,
                                                   f16* __restrict__ vh) {
    __shared__ float Lin[35 * 128];
    __shared__ float Lout[32 * 128];
    __shared__ float Lsc[32];
    int g = blockIdx.x;
    int s0 = blockIdx.y * 32;
    int b = blockIdx.z;
    int tid = threadIdx.x;
    int colbase, chbase;
    f16* outp;
    bool donorm;
    float nmul;
    if (g < 16) {
        colbase = g * 768; chbase = g * 128;
        outp = qh + (((long)b * 16 + g) * 2048 + s0) * 128;
        donorm = true; nmul = QSCALE;
    } else if (g < 32) {
        int hk = g - 16;
        colbase = hk * 768 + 128; chbase = 2048 + hk * 128;
        outp = kh + (((long)b * 16 + hk) * 2048 + s0) * 128;
        donorm = true; nmul = 1.f;
    } else {
        int hv = g - 32;
        colbase = (hv >> 1) * 768 + 256 + (hv & 1) * 128; chbase = 4096 + hv * 128;
        outp = vh + (((long)b * 32 + hv) * 2048 + s0) * 128;
        donorm = false; nmul = 1.f;
    }
    for (int idx = tid; idx < 35 * 128; idx += 256) {
        int sr = idx >> 7, c = idx & 127;
        int s = s0 + sr - 3;
        Lin[idx] = (s >= 0) ? (float)qkvz[((long)b * 2048 + s) * 12288 + colbase + c] : 0.f;
    }
    __syncthreads();
    int c = tid & 127, sg = tid >> 7;
    float w0 = cw[(chbase + c) * 4 + 0];
    float w1 = cw[(chbase + c) * 4 + 1];
    float w2 = cw[(chbase + c) * 4 + 2];
    float w3 = cw[(chbase + c) * 4 + 3];
    float bias = cb[chbase + c];
#pragma unroll
    for (int j = 0; j < 16; ++j) {
        int sl = sg * 16 + j;
        float v = w0 * Lin[sl * 128 + c] + w1 * Lin[(sl + 1) * 128 + c] +
                  w2 * Lin[(sl + 2) * 128 + c] + w3 * Lin[(sl + 3) * 128 + c] + bias;
        v = v / (1.f + expf(-v));  // SiLU
        Lout[sl * 128 + c] = v;
    }
    __syncthreads();
    if (donorm) {
        int token = tid >> 3, part = tid & 7;
        float ss = 0.f;
#pragma unroll
        for (int i = 0; i < 16; ++i) {
            float v = Lout[token * 128 + part * 16 + i];
            ss += v * v;
        }
        ss += __shfl_xor(ss, 1); ss += __shfl_xor(ss, 2); ss += __shfl_xor(ss, 4);
        if (part == 0) Lsc[token] = rsqrtf(ss + 1e-6f) * nmul;
        __syncthreads();
#pragma unroll
        for (int j = 0; j < 16; ++j) {
            int sl = sg * 16 + j;
            outp[(long)sl * 128 + c] = (f16)(Lout[sl * 128 + c] * Lsc[sl]);
        }
    } else {
#pragma unroll
        for (int j = 0; j < 16; ++j) {
            int sl = sg * 16 + j;
            outp[(long)sl * 128 + c] = (f16)Lout[sl * 128 + c];
        }
    }
}

// ------------------------------------------------------------------
// g = -exp(a_log)*softplus(a+dt_bias) (RAW, not exp), beta = sigmoid(b)
// ------------------------------------------------------------------
__global__ __launch_bounds__(256) void gb_kernel(const float* __restrict__ ba,
                                                 const float* __restrict__ a_log,
                                                 const float* __restrict__ dt_bias,
                                                 float* __restrict__ gout,
                                                 float* __restrict__ bt) {
    int idx = blockIdx.x * 256 + threadIdx.x;  // ((b*32+hv)*2048 + s)
    if (idx >= 2 * 32 * 2048) return;
    int s = idx & 2047;
    int hv = (idx >> 11) & 31;
    int b = idx >> 16;
    int gg = hv & 1, hk = hv >> 1;
    long base = ((long)b * 2048 + s) * 64 + hk * 4;
    float bv = ba[base + gg];
    float av = ba[base + 2 + gg];
    float xx = av + dt_bias[hv];
    float sp = (xx > 20.f) ? xx : log1pf(expf(xx));
    gout[idx] = -expf(a_log[hv]) * sp;
    bt[idx] = 1.f / (1.f + expf(-bv));
}

// ------------------------------------------------------------------
// kh [bh][2048][128] -> khT [bh][128][2048]  (f16 transpose)
// grid 1024 = 32 bh x 32 step-blocks of 64; block 256
// tile padded to 136 f16/row (272B = 16-aligned) for f16x8 LDS stores
// ------------------------------------------------------------------
__global__ __launch_bounds__(256) void kT_kernel(const f16* __restrict__ kh,
                                                 f16* __restrict__ khT) {
    __shared__ f16 t[64][136];
    int bh = blockIdx.x >> 5;
    int s0 = (blockIdx.x & 31) * 64;
    int tid = threadIdx.x;
#pragma unroll
    for (int it = 0; it < 4; ++it) {
        int P = (tid + it * 256) * 8;
        int r = P >> 7, col = P & 127;
        *(f16x8*)&t[r][col] = *(const f16x8*)(kh + ((long)bh * 2048 + s0 + r) * 128 + col);
    }
    __syncthreads();
#pragma unroll
    for (int it = 0; it < 4; ++it) {
        int Q = (tid + it * 256) * 8;
        int dk = Q >> 6, sc = Q & 63;
        f16x8 v;
#pragma unroll
        for (int e = 0; e < 8; ++e) v[e] = t[sc + e][dk];
        *(f16x8*)(khT + ((long)bh * 128 + dk) * 2048 + s0 + sc) = v;
    }
}

// ------------------------------------------------------------------
// chunk_pre: per (b,hv,chunk of 32) — one wave.
// Computes per chunk-head: W (32x32 f16), T2n (32x32 f16),
// D0 = T@(beta*V) stored [dv][step] f16, pv = [P(32f32) | kws(32f32)].
// ------------------------------------------------------------------
__global__ __launch_bounds__(64) void chunk_pre_kernel(const f16* __restrict__ qh,
                                                       const f16* __restrict__ kh,
                                                       const f16* __restrict__ vh,
                                                       const float* __restrict__ gb,
                                                       const float* __restrict__ bt,
                                                       f16* __restrict__ Wg,
                                                       f16* __restrict__ T2ng,
                                                       f16* __restrict__ d0g,
                                                       float* __restrict__ pvg) {
    __shared__ f16 Kl[32 * 128];     // [step][dk], swz ^((step&7)<<4)
    __shared__ f16 Ql[32 * 128];
    __shared__ f16 VTl[128 * 32];    // beta*V as [dv][step], swz ^((dv&3)<<4)
    __shared__ float KKl[32 * 32];   // [i][j]
    __shared__ float RL[32 * 32];    // exp(cum_i - cum_j), j<=i
    __shared__ float Tf[32 * 33];    // T f32 work
    __shared__ f16 Tl[32 * 64];      // T f16 [i][j] padded rows (64 halfs), swz ^((i&3)<<4)
    __shared__ float cuml[32], bl[32], pl[32];

    int bid = blockIdx.x;
    int chunk = bid & 63;
    int hv = (bid >> 6) & 31;
    int b = bid >> 11;
    int bh = b * 16 + (hv >> 1);
    int l = threadIdx.x;
    int h = l >> 4, c = l & 15;
    long chid = bid;  // chunk-head id == bid by construction

    const f16* kbase = kh + ((long)bh * 2048 + chunk * 32) * 128;
    const f16* qbase = qh + ((long)bh * 2048 + chunk * 32) * 128;
    const f16* vbase = vh + (((long)b * 32 + hv) * 2048 + chunk * 32) * 128;
    const float* gp = gb + ((long)b * 32 + hv) * 2048 + chunk * 32;
    const float* bp = bt + ((long)b * 32 + hv) * 2048 + chunk * 32;

    // ---- scalars: inclusive scan of g over lanes 0..31
    float gv = (l < 32) ? gp[l] : 0.f;
#pragma unroll
    for (int d = 1; d < 32; d <<= 1) {
        float t2 = __shfl_up(gv, d);
        if (l >= d) gv += t2;
    }
    if (l < 32) { cuml[l] = gv; bl[l] = bp[l]; pl[l] = expf(gv); }

    // ---- stage K,Q
#pragma unroll
    for (int it = 0; it < 8; ++it) {
        int P = (l + it * 64) * 16;
        int row = P >> 8;
        int sw = P ^ ((row & 7) << 4);
        *(f16x8*)((char*)Kl + sw) = *(const f16x8*)((const char*)kbase + (long)row * 256 + (P & 255));
        *(f16x8*)((char*)Ql + sw) = *(const f16x8*)((const char*)qbase + (long)row * 256 + (P & 255));
    }
    __syncthreads();

    // ---- stage beta*V transposed, build RL
#pragma unroll
    for (int it = 0; it < 8; ++it) {
        int idx = (l + it * 64) * 8;
        int row = idx >> 7, col = idx & 127;
        f16x8 v = *(const f16x8*)(vbase + (long)row * 128 + col);
        float be = bl[row];
#pragma unroll
        for (int e = 0; e < 8; ++e) {
            int dv = col + e;
            int byte = (dv * 64 + row * 2) ^ ((dv & 3) << 4);
            *(f16*)((char*)VTl + byte) = (f16)((float)v[e] * be);
        }
    }
#pragma unroll
    for (int it = 0; it < 16; ++it) {
        int e = l * 16 + it;
        int i = e >> 5, j = e & 31;
        RL[e] = (j <= i) ? expf(cuml[i] - cuml[j]) : 0.f;
    }
    __syncthreads();

    // ---- frag readers
    auto fragKQ = [&](const f16* base, int ti, int kk) {
        int row = c + 16 * ti;
        int byte = row * 256 + ((kk * 64 + h * 16) ^ ((row & 7) << 4));
        return *(const f16x8*)((const char*)base + byte);
    };

    // ---- KK = K @ K^T
    {
        f32x4 acc[2][2] = {};
#pragma unroll
        for (int kk = 0; kk < 4; ++kk) {
            f16x8 fa0 = fragKQ(Kl, 0, kk), fa1 = fragKQ(Kl, 1, kk);
            acc[0][0] = __builtin_amdgcn_mfma_f32_16x16x32_f16(fa0, fa0, acc[0][0], 0, 0, 0);
            acc[0][1] = __builtin_amdgcn_mfma_f32_16x16x32_f16(fa0, fa1, acc[0][1], 0, 0, 0);
            acc[1][0] = __builtin_amdgcn_mfma_f32_16x16x32_f16(fa1, fa0, acc[1][0], 0, 0, 0);
            acc[1][1] = __builtin_amdgcn_mfma_f32_16x16x32_f16(fa1, fa1, acc[1][1], 0, 0, 0);
        }
#pragma unroll
        for (int ti = 0; ti < 2; ++ti)
#pragma unroll
            for (int tj = 0; tj < 2; ++tj)
#pragma unroll
                for (int r = 0; r < 4; ++r)
                    KKl[(h * 4 + r + 16 * ti) * 32 + c + 16 * tj] = acc[ti][tj][r];
    }
    // ---- QK = Q @ K^T -> W
    {
        f32x4 acc[2][2] = {};
#pragma unroll
        for (int kk = 0; kk < 4; ++kk) {
            f16x8 fq0 = fragKQ(Ql, 0, kk), fq1 = fragKQ(Ql, 1, kk);
            f16x8 fk0 = fragKQ(Kl, 0, kk), fk1 = fragKQ(Kl, 1, kk);
            acc[0][0] = __builtin_amdgcn_mfma_f32_16x16x32_f16(fq0, fk0, acc[0][0], 0, 0, 0);
            acc[0][1] = __builtin_amdgcn_mfma_f32_16x16x32_f16(fq0, fk1, acc[0][1], 0, 0, 0);
            acc[1][0] = __builtin_amdgcn_mfma_f32_16x16x32_f16(fq1, fk0, acc[1][0], 0, 0, 0);
            acc[1][1] = __builtin_amdgcn_mfma_f32_16x16x32_f16(fq1, fk1, acc[1][1], 0, 0, 0);
        }
        __syncthreads();
#pragma unroll
        for (int ti = 0; ti < 2; ++ti)
#pragma unroll
            for (int tj = 0; tj < 2; ++tj)
#pragma unroll
                for (int r = 0; r < 4; ++r) {
                    int i = h * 4 + r + 16 * ti, j = c + 16 * tj;
                    Wg[chid * 1024 + i * 32 + j] = (f16)(acc[ti][tj][r] * RL[i * 32 + j]);
                }
    }

    // ---- T inversion (forward substitution), lane j owns column j
    if (l < 32) {
        int j = l;
        for (int i = 0; i < 32; ++i) {
            float s = (i == j) ? 1.f : 0.f;
            float bi = bl[i];
            for (int ll = j; ll < i; ++ll)
                s -= bi * KKl[i * 32 + ll] * RL[i * 32 + ll] * Tf[ll * 33 + j];
            Tf[i * 33 + j] = s;
        }
        float bpj = bl[j] * pl[j];
        for (int i = 0; i < 32; ++i) {
            float tv = (i >= j) ? Tf[i * 33 + j] : 0.f;
            int byte = (i * 128 + j * 2) ^ ((i & 3) << 4);
            *(f16*)((char*)Tl + byte) = (f16)tv;
            T2ng[chid * 1024 + i * 32 + j] = (f16)(-tv * bpj);
        }
        pvg[chid * 64 + j] = pl[j];
        pvg[chid * 64 + 32 + j] = expf(cuml[31] - cuml[j]);
    }
    __syncthreads();

    // ---- D0 = T @ (beta*V): M=32 N=128 K=32
    {
        f16x8 fT[2];
#pragma unroll
        for (int ti = 0; ti < 2; ++ti) {
            int row = c + 16 * ti;
            fT[ti] = *(const f16x8*)((const char*)Tl + ((row * 128 + h * 16) ^ ((row & 3) << 4)));
        }
#pragma unroll
        for (int nj = 0; nj < 8; ++nj) {
            int dv = c + 16 * nj;
            f16x8 fv = *(const f16x8*)((const char*)VTl + ((dv * 64 + h * 16) ^ ((dv & 3) << 4)));
            f32x4 a0 = {}, a1 = {};
            a0 = __builtin_amdgcn_mfma_f32_16x16x32_f16(fT[0], fv, a0, 0, 0, 0);
            a1 = __builtin_amdgcn_mfma_f32_16x16x32_f16(fT[1], fv, a1, 0, 0, 0);
            f16x4 s0, s1;
#pragma unroll
            for (int r = 0; r < 4; ++r) { s0[r] = (f16)a0[r]; s1[r] = (f16)a1[r]; }
            *(f16x4*)(d0g + chid * 4096 + (long)dv * 32 + 4 * h) = s0;
            *(f16x4*)(d0g + chid * 4096 + (long)dv * 32 + 16 + 4 * h) = s1;
        }
    }
}

// ------------------------------------------------------------------
// sequential chunked scan: grid 256 = (b,hv,vs of 32 dv); 1 wave.
// S (f16, [dv][dk] in LDS, double-buffered). 56 MFMAs/chunk.
// ------------------------------------------------------------------
__global__ __launch_bounds__(64) void scan_kernel(const f16* __restrict__ qh,
                                                  const f16* __restrict__ kh,
                                                  const f16* __restrict__ khT,
                                                  const f16* __restrict__ Wg,
                                                  const f16* __restrict__ T2ng,
                                                  const f16* __restrict__ d0g,
                                                  const float* __restrict__ pvg,
                                                  f16* __restrict__ ob) {
    __shared__ f16 Sl[2][32 * 128];  // [dv][dk], swz ^((dv&7)<<4)
    __shared__ f16 AKl[32 * 32];     // [dv][step], swz ^((dv&3)<<4)
    __shared__ f16 Dl[32 * 32];

    int bid = blockIdx.x;
    int vs = bid & 3;
    int hv = (bid >> 2) & 31;
    int b = bid >> 7;
    int bh32 = b * 32 + hv;
    int bh = b * 16 + (hv >> 1);
    int l = threadIdx.x, h = l >> 4, c = l & 15;

    const f16* kb = kh + (long)bh * 2048 * 128;
    const f16* qb = qh + (long)bh * 2048 * 128;
    const f16* ktb = khT + (long)bh * 128 * 2048;

    f16x8 z = {};
#pragma unroll
    for (int it = 0; it < 8; ++it) *(f16x8*)((char*)Sl[0] + (l + it * 64) * 16) = z;
    __syncthreads();

    int cur = 0;
    for (int ch = 0; ch < 64; ++ch) {
        long chid = (long)bh32 * 64 + ch;
        f16x8 fk[2][4], fq[2][4], fkt[8], fT[2], fW[2];
#pragma unroll
        for (int ti = 0; ti < 2; ++ti) {
            long row = ch * 32 + c + 16 * ti;
#pragma unroll
            for (int kk = 0; kk < 4; ++kk) {
                fk[ti][kk] = *(const f16x8*)(kb + row * 128 + kk * 32 + h * 8);
                fq[ti][kk] = *(const f16x8*)(qb + row * 128 + kk * 32 + h * 8);
            }
            fT[ti] = *(const f16x8*)(T2ng + chid * 1024 + (c + 16 * ti) * 32 + h * 8);
            fW[ti] = *(const f16x8*)(Wg + chid * 1024 + (c + 16 * ti) * 32 + h * 8);
        }
#pragma unroll
        for (int ti = 0; ti < 8; ++ti)
            fkt[ti] = *(const f16x8*)(ktb + (long)(c + 16 * ti) * 2048 + ch * 32 + h * 8);
        f16x4 fd0[2][2];
#pragma unroll
        for (int ti = 0; ti < 2; ++ti)
#pragma unroll
            for (int tj = 0; tj < 2; ++tj)
                fd0[ti][tj] = *(const f16x4*)(d0g + chid * 4096 +
                                              (long)(vs * 32 + c + 16 * tj) * 32 + 16 * ti + 4 * h);
        f32x4 pva = *(const f32x4*)(pvg + chid * 64 + 4 * h);
        f32x4 pvb = *(const f32x4*)(pvg + chid * 64 + 16 + 4 * h);
        float pc = pvg[chid * 64 + 31];
        f32x4 kwa = *(const f32x4*)(pvg + chid * 64 + 32 + h * 8);
        f32x4 kwb = *(const f32x4*)(pvg + chid * 64 + 36 + h * 8);

        f16x8 fS[2][4];
#pragma unroll
        for (int nj = 0; nj < 2; ++nj) {
            int dv = c + 16 * nj;
#pragma unroll
            for (int kk = 0; kk < 4; ++kk)
                fS[nj][kk] = *(const f16x8*)((char*)Sl[cur] +
                                             (dv * 256 + ((kk * 64 + h * 16) ^ ((dv & 7) << 4))));
        }
        f32x4 AK[2][2] = {}, AQ[2][2] = {};
#pragma unroll
        for (int ti = 0; ti < 2; ++ti)
#pragma unroll
            for (int nj = 0; nj < 2; ++nj)
#pragma unroll
                for (int kk = 0; kk < 4; ++kk) {
                    AK[ti][nj] = __builtin_amdgcn_mfma_f32_16x16x32_f16(fk[ti][kk], fS[nj][kk], AK[ti][nj], 0, 0, 0);
                    AQ[ti][nj] = __builtin_amdgcn_mfma_f32_16x16x32_f16(fq[ti][kk], fS[nj][kk], AQ[ti][nj], 0, 0, 0);
                }
#pragma unroll
        for (int ti = 0; ti < 2; ++ti)
#pragma unroll
            for (int nj = 0; nj < 2; ++nj) {
                int dv = c + 16 * nj;
                f16x4 t;
#pragma unroll
                for (int r = 0; r < 4; ++r) t[r] = (f16)AK[ti][nj][r];
                *(f16x4*)((char*)AKl + ((dv * 64 + 32 * ti + 8 * h) ^ ((dv & 3) << 4))) = t;
            }
        f32x4 Dv[2][2];
#pragma unroll
        for (int ti = 0; ti < 2; ++ti)
#pragma unroll
            for (int tj = 0; tj < 2; ++tj)
#pragma unroll
                for (int r = 0; r < 4; ++r) Dv[ti][tj][r] = (float)fd0[ti][tj][r];
        {
            f16x8 fak[2];
#pragma unroll
            for (int tj = 0; tj < 2; ++tj) {
                int dv = c + 16 * tj;
                fak[tj] = *(const f16x8*)((char*)AKl + ((dv * 64 + h * 16) ^ ((dv & 3) << 4)));
            }
#pragma unroll
            for (int ti = 0; ti < 2; ++ti)
#pragma unroll
                for (int tj = 0; tj < 2; ++tj)
                    Dv[ti][tj] = __builtin_amdgcn_mfma_f32_16x16x32_f16(fT[ti], fak[tj], Dv[ti][tj], 0, 0, 0);
        }
#pragma unroll
        for (int ti = 0; ti < 2; ++ti)
#pragma unroll
            for (int tj = 0; tj < 2; ++tj) {
                int dv = c + 16 * tj;
                f16x4 t;
#pragma unroll
                for (int r = 0; r < 4; ++r) t[r] = (f16)Dv[ti][tj][r];
                *(f16x4*)((char*)Dl + ((dv * 64 + 32 * ti + 8 * h) ^ ((dv & 3) << 4))) = t;
            }
        f16x8 fdl[2];
#pragma unroll
        for (int tj = 0; tj < 2; ++tj) {
            int dv = c + 16 * tj;
            fdl[tj] = *(const f16x8*)((char*)Dl + ((dv * 64 + h * 16) ^ ((dv & 3) << 4)));
        }
        f32x4 Ov[2][2];
#pragma unroll
        for (int ti = 0; ti < 2; ++ti)
#pragma unroll
            for (int tj = 0; tj < 2; ++tj)
#pragma unroll
                for (int r = 0; r < 4; ++r)
                    Ov[ti][tj][r] = AQ[ti][tj][r] * (ti ? pvb[r] : pva[r]);
#pragma unroll
        for (int ti = 0; ti < 2; ++ti)
#pragma unroll
            for (int tj = 0; tj < 2; ++tj)
                Ov[ti][tj] = __builtin_amdgcn_mfma_f32_16x16x32_f16(fW[ti], fdl[tj], Ov[ti][tj], 0, 0, 0);
#pragma unroll
        for (int ti = 0; ti < 2; ++ti)
#pragma unroll
            for (int tj = 0; tj < 2; ++tj)
#pragma unroll
                for (int r = 0; r < 4; ++r) {
                    long tok = (long)b * 2048 + ch * 32 + 16 * ti + 4 * h + r;
                    ob[tok * 4096 + hv * 128 + vs * 32 + c + 16 * tj] = (f16)Ov[ti][tj][r];
                }
#pragma unroll
        for (int ti = 0; ti < 8; ++ti) {
            f16x8 fa;
#pragma unroll
            for (int e = 0; e < 8; ++e)
                fa[e] = (f16)((float)fkt[ti][e] * (e < 4 ? kwa[e] : kwb[e - 4]));
#pragma unroll
            for (int tj = 0; tj < 2; ++tj) {
                int dv = c + 16 * tj;
                int sbyte = (dv * 256 + (32 * ti + 8 * h)) ^ ((dv & 7) << 4);
                f16x4 sold = *(const f16x4*)((char*)Sl[cur] + sbyte);
                f32x4 acc;
#pragma unroll
                for (int r = 0; r < 4; ++r) acc[r] = pc * (float)sold[r];
                acc = __builtin_amdgcn_mfma_f32_16x16x32_f16(fa, fdl[tj], acc, 0, 0, 0);
                f16x4 snew;
#pragma unroll
                for (int r = 0; r < 4; ++r) snew[r] = (f16)acc[r];
                *(f16x4*)((char*)Sl[cur ^ 1] + sbyte) = snew;
            }
        }
        cur ^= 1;
        __syncthreads();
    }
}

// ------------------------------------------------------------------
// y = rmsnorm(o * silu(z)) * norm_w  -> f16
// ------------------------------------------------------------------
__global__ __launch_bounds__(256) void gate_kernel(const f16* __restrict__ o,
                                                   const f16* __restrict__ qkvz,
                                                   const float* __restrict__ norm_w,
                                                   f16* __restrict__ y) {
    int token = blockIdx.x;  // b*2048 + s
    int tid = threadIdx.x;
    int hv = tid >> 3, part = tid & 7;
    int dv0 = part * 16;
    const f16* orow = o + ((long)token * 32 + hv) * 128 + dv0;
    long zcol = (long)(hv >> 1) * 768 + 512 + (hv & 1) * 128 + dv0;
    const f16* zrow = qkvz + (long)token * 12288 + zcol;
    float yv[16];
    float ss = 0.f;
#pragma unroll
    for (int i = 0; i < 16; ++i) {
        float ov = (float)orow[i];
        float zv = (float)zrow[i];
        float gt = zv / (1.f + expf(-zv));
        float v = ov * gt;
        yv[i] = v;
        ss += v * v;
    }
    ss += __shfl_xor(ss, 1); ss += __shfl_xor(ss, 2); ss += __shfl_xor(ss, 4);
    float scale = rsqrtf(ss * (1.f / 128.f) + 1e-6f);
    f16* yrow = y + (long)token * 4096 + hv * 128 + dv0;
#pragma unroll
    for (int i = 0; i < 16; ++i) yrow[i] = (f16)(yv[i] * scale * norm_w[dv0 + i]);
}

// ------------------------------------------------------------------
// Workspace (242 MB, time-aliased) — lifetime-audited:
//   [0,96)    qkvz16  (gemm1 -> gate)
//   [96,97)   bab     (ba_gemm -> gb; over dead x16)  [FIX: was 239, inside vh]
//   [96,112)  x16 (cvt -> gemm1)
//   [112,160) WT (transpose -> gemm1)
//   [96,128)  d0g (chunk_pre -> scan; overwrites bab AFTER gb consumed it)
//   [128,136) Wg ; [136,144) T2ng ; [144,160) khT  (post-gemm1)
//   [160,176) WTo (transpose -> gemm2)
//   [176,208) qh,kh (conv -> scan); y16 over it after scan (gate -> gemm2)
//   [208,240) vh (conv -> chunk_pre); ob over it (scan -> gate)
//   [240,240.5) gbuf ; [240.5,241) btb ; [241,242) pvg
// ------------------------------------------------------------------
extern "C" void kernel_launch(void* const* d_in, const int* in_sizes, int n_in,
                              void* d_out, int out_size, void* d_ws, size_t ws_size,
                              hipStream_t stream) {
    const float* x       = (const float*)d_in[0];
    const float* w_qkvz  = (const float*)d_in[1];
    const float* w_ba    = (const float*)d_in[2];
    const float* conv_w  = (const float*)d_in[3];
    const float* conv_b  = (const float*)d_in[4];
    const float* a_log   = (const float*)d_in[5];
    const float* dt_bias = (const float*)d_in[6];
    const float* norm_w  = (const float*)d_in[7];
    const float* w_o     = (const float*)d_in[8];
    float* out = (float*)d_out;

    char* ws = (char*)d_ws;
    const size_t MB = 1024 * 1024;
    f16*   qkvz16 = (f16*)ws;
    f16*   x16    = (f16*)(ws + 96 * MB);
    f16*   WT     = (f16*)(ws + 112 * MB);
    float* bab    = (float*)(ws + 96 * MB);   // over dead x16; consumed before d0g
    f16*   d0g    = (f16*)(ws + 96 * MB);
    f16*   Wg     = (f16*)(ws + 128 * MB);
    f16*   T2ng   = (f16*)(ws + 136 * MB);
    f16*   khT    = (f16*)(ws + 144 * MB);
    f16*   WTo    = (f16*)(ws + 160 * MB);
    f16*   qh     = (f16*)(ws + 176 * MB);
    f16*   kh     = (f16*)(ws + 192 * MB);
    f16*   vh     = (f16*)(ws + 208 * MB);
    f16*   ob     = (f16*)(ws + 208 * MB);
    f16*   y16    = (f16*)(ws + 176 * MB);
    float* gbuf   = (float*)(ws + 240 * MB);
    float* btb    = (float*)(ws + 240 * MB + 512 * 1024);
    float* pvg    = (float*)(ws + 241 * MB);

    // prep
    cvt16_kernel<<<8192, 256, 0, stream>>>(x, x16, 4096 * 2048 / 4);
    transpose16_kernel<<<dim3(12288 / 64, 2048 / 64), 256, 0, stream>>>(w_qkvz, WT, 2048, 12288);
    transpose16_kernel<<<dim3(2048 / 64, 4096 / 64), 256, 0, stream>>>(w_o, WTo, 4096, 2048);

    // qkvz = x @ w_qkvz
    gemm16_kernel<1><<<dim3(12288 / 128, 4096 / 128), 256, 0, stream>>>(x16, WT, qkvz16, 4096, 12288, 2048);
    // ba = x @ w_ba  (writes over dead x16)
    ba_gemm_kernel<<<256, 256, 0, stream>>>(x, w_ba, bab);

    // conv + silu + l2norm
    conv_kernel<<<dim3(64, 64, 2), 256, 0, stream>>>(qkvz16, conv_w, conv_b, qh, kh, vh);
    // g, beta
    gb_kernel<<<512, 256, 0, stream>>>(bab, a_log, dt_bias, gbuf, btb);
    // k transpose
    kT_kernel<<<1024, 256, 0, stream>>>(kh, khT);
    // per-chunk UT-transform precompute (overwrites bab region AFTER gb)
    chunk_pre_kernel<<<4096, 64, 0, stream>>>(qh, kh, vh, gbuf, btb, Wg, T2ng, d0g, pvg);
    // sequential chunked MFMA scan
    scan_kernel<<<256, 64, 0, stream>>>(qh, kh, khT, Wg, T2ng, d0g, pvg, ob);

    // gating + rmsnorm -> y16
    gate_kernel<<<4096, 256, 0, stream>>>(ob, qkvz16, norm_w, y16);

    // out = y @ w_o
    gemm16_kernel<0><<<dim3(2048 / 128, 4096 / 128), 256, 0, stream>>>(y16, WTo, out, 4096, 2048, 4096);
}

// Round 12
// 1031.830 us; speedup vs baseline: 1.2055x; 1.0102x over previous
//
#include <hip/hip_runtime.h>

typedef _Float16 f16;
typedef _Float16 f16x2 __attribute__((ext_vector_type(2)));
typedef _Float16 f16x4 __attribute__((ext_vector_type(4)));
typedef _Float16 f16x8 __attribute__((ext_vector_type(8)));
typedef float f32x4 __attribute__((ext_vector_type(4)));

#define QSCALE 0.08838834764831845f  // DK^-0.5

// ------------------------------------------------------------------
// convert fp32 -> f16 (vectorized x4)
// ------------------------------------------------------------------
__global__ __launch_bounds__(256) void cvt16_kernel(const float* __restrict__ in,
                                                    f16* __restrict__ out, int n4) {
    int i = blockIdx.x * 256 + threadIdx.x;
    if (i >= n4) return;
    f32x4 v = ((const f32x4*)in)[i];
    f16x4 h;
    h[0] = (f16)v[0]; h[1] = (f16)v[1]; h[2] = (f16)v[2]; h[3] = (f16)v[3];
    ((f16x4*)out)[i] = h;
}

// ------------------------------------------------------------------
// transpose fp32 [R][C] -> f16 [C][R]
// ------------------------------------------------------------------
__global__ __launch_bounds__(256) void transpose16_kernel(const float* __restrict__ in,
                                                          f16* __restrict__ out, int R, int C) {
    __shared__ f16 tile[64][66];
    int c0 = blockIdx.x * 64, r0 = blockIdx.y * 64;
    int tid = threadIdx.x;
#pragma unroll
    for (int i = 0; i < 16; ++i) {
        int idx = i * 256 + tid;
        int r = idx >> 6, c = idx & 63;
        tile[r][c] = (f16)in[(long)(r0 + r) * C + (c0 + c)];
    }
    __syncthreads();
#pragma unroll
    for (int i = 0; i < 16; ++i) {
        int idx = i * 256 + tid;
        int orow = idx >> 6, oc = idx & 63;
        out[(long)(c0 + orow) * R + (r0 + oc)] = tile[oc][orow];
    }
}

// ------------------------------------------------------------------
// f16 MFMA GEMM (r7 body — reg-staged, XOR-swizzled LDS; measured best)
// + bijective XCD tile swizzle (T1/m204; grid must be 1D, %8==0)
// ------------------------------------------------------------------
template <int F16OUT>
__global__ __launch_bounds__(256) void gemm16_kernel(const f16* __restrict__ A,
                                                     const f16* __restrict__ Bt,
                                                     void* __restrict__ Cout,
                                                     int M, int N, int Kd) {
    __shared__ f16 sA[128 * 64];
    __shared__ f16 sB[128 * 64];
    const int tid = threadIdx.x;
    const int lane = tid & 63, wv = tid >> 6;
    const int wm = wv >> 1, wn = wv & 1;
    // XCD-aware bijective swizzle of the tile index
    const int nbx = N >> 7;
    const int nwg = (M >> 7) * nbx;
    int bid = blockIdx.x;
    int q = nwg >> 3, r = nwg & 7;
    int xcd = bid & 7, rest = bid >> 3;
    int wgid = (xcd < r ? xcd * (q + 1) : r * (q + 1) + (xcd - r) * q) + rest;
    const int m0 = (wgid / nbx) * 128, n0 = (wgid % nbx) * 128;
    const int lrow = lane & 15, lk = lane >> 4;
    f32x4 acc[4][4] = {};
    for (int k0 = 0; k0 < Kd; k0 += 64) {
        __syncthreads();
#pragma unroll
        for (int j = 0; j < 4; ++j) {
            int P = (tid + j * 256) * 16;
            int row = P >> 7;
            int sw = P ^ ((row & 7) << 4);
            int koff = P & 127;
            const char* ga = (const char*)(A + (long)(m0 + row) * Kd + k0) + koff;
            *(f32x4*)((char*)sA + sw) = *(const f32x4*)ga;
            const char* gb = (const char*)(Bt + (long)(n0 + row) * Kd + k0) + koff;
            *(f32x4*)((char*)sB + sw) = *(const f32x4*)gb;
        }
        __syncthreads();
#pragma unroll
        for (int kk = 0; kk < 2; ++kk) {
            f16x8 af[4], bf[4];
#pragma unroll
            for (int i = 0; i < 4; ++i) {
                int arow = wm * 64 + i * 16 + lrow;
                int abyte = arow * 128 + kk * 64 + lk * 16;
                af[i] = *(const f16x8*)((const char*)sA + (abyte ^ ((arow & 7) << 4)));
                int brow = wn * 64 + i * 16 + lrow;
                int bbyte = brow * 128 + kk * 64 + lk * 16;
                bf[i] = *(const f16x8*)((const char*)sB + (bbyte ^ ((brow & 7) << 4)));
            }
#pragma unroll
            for (int i = 0; i < 4; ++i)
#pragma unroll
                for (int j = 0; j < 4; ++j)
                    acc[i][j] = __builtin_amdgcn_mfma_f32_16x16x32_f16(af[i], bf[j], acc[i][j], 0, 0, 0);
        }
    }
#pragma unroll
    for (int i = 0; i < 4; ++i) {
        int gm_base = m0 + wm * 64 + i * 16 + lk * 4;
#pragma unroll
        for (int j = 0; j < 4; ++j) {
            int gn = n0 + wn * 64 + j * 16 + lrow;
#pragma unroll
            for (int r2 = 0; r2 < 4; ++r2) {
                long idx = (long)(gm_base + r2) * N + gn;
                if (F16OUT) ((f16*)Cout)[idx] = (f16)acc[i][j][r2];
                else        ((float*)Cout)[idx] = acc[i][j][r2];
            }
        }
    }
}

// ------------------------------------------------------------------
// ba = x @ w_ba   (fp32)
// ------------------------------------------------------------------
__global__ __launch_bounds__(256) void ba_gemm_kernel(const float* __restrict__ x,
                                                      const float* __restrict__ w,
                                                      float* __restrict__ ba) {
    __shared__ float xs[16][256];
    int tid = threadIdx.x;
    int t0 = blockIdx.x * 16;
    int o = tid & 63, tg = tid >> 6;
    float acc[4] = {0.f, 0.f, 0.f, 0.f};
    for (int kc = 0; kc < 2048; kc += 256) {
        __syncthreads();
#pragma unroll
        for (int i = 0; i < 16; ++i) {
            int idx = i * 256 + tid;
            int tok = idx >> 8, k = idx & 255;
            xs[tok][k] = x[(long)(t0 + tok) * 2048 + kc + k];
        }
        __syncthreads();
        for (int k = 0; k < 256; ++k) {
            float wv = w[(long)(kc + k) * 64 + o];
#pragma unroll
            for (int j = 0; j < 4; ++j) acc[j] += xs[tg * 4 + j][k] * wv;
        }
    }
#pragma unroll
    for (int j = 0; j < 4; ++j) ba[(long)(t0 + tg * 4 + j) * 64 + o] = acc[j];
}

// ------------------------------------------------------------------
// depthwise causal conv(K=4) + bias + SiLU (+ L2norm for q/k heads)
// ------------------------------------------------------------------
__global__ __launch_bounds__(256) void conv_kernel(const f16* __restrict__ qkvz,
                                                   const float* __restrict__ cw,
                                                   const float* __restrict__ cb,
                                                   f16* __restrict__ qh,
                                                   f16* __restrict__ kh,
                                                   f16* __restrict__ vh) {
    __shared__ float Lin[35 * 128];
    __shared__ float Lout[32 * 128];
    __shared__ float Lsc[32];
    int g = blockIdx.x;
    int s0 = blockIdx.y * 32;
    int b = blockIdx.z;
    int tid = threadIdx.x;
    int colbase, chbase;
    f16* outp;
    bool donorm;
    float nmul;
    if (g < 16) {
        colbase = g * 768; chbase = g * 128;
        outp = qh + (((long)b * 16 + g) * 2048 + s0) * 128;
        donorm = true; nmul = QSCALE;
    } else if (g < 32) {
        int hk = g - 16;
        colbase = hk * 768 + 128; chbase = 2048 + hk * 128;
        outp = kh + (((long)b * 16 + hk) * 2048 + s0) * 128;
        donorm = true; nmul = 1.f;
    } else {
        int hv = g - 32;
        colbase = (hv >> 1) * 768 + 256 + (hv & 1) * 128; chbase = 4096 + hv * 128;
        outp = vh + (((long)b * 32 + hv) * 2048 + s0) * 128;
        donorm = false; nmul = 1.f;
    }
    for (int idx = tid; idx < 35 * 128; idx += 256) {
        int sr = idx >> 7, c = idx & 127;
        int s = s0 + sr - 3;
        Lin[idx] = (s >= 0) ? (float)qkvz[((long)b * 2048 + s) * 12288 + colbase + c] : 0.f;
    }
    __syncthreads();
    int c = tid & 127, sg = tid >> 7;
    float w0 = cw[(chbase + c) * 4 + 0];
    float w1 = cw[(chbase + c) * 4 + 1];
    float w2 = cw[(chbase + c) * 4 + 2];
    float w3 = cw[(chbase + c) * 4 + 3];
    float bias = cb[chbase + c];
#pragma unroll
    for (int j = 0; j < 16; ++j) {
        int sl = sg * 16 + j;
        float v = w0 * Lin[sl * 128 + c] + w1 * Lin[(sl + 1) * 128 + c] +
                  w2 * Lin[(sl + 2) * 128 + c] + w3 * Lin[(sl + 3) * 128 + c] + bias;
        v = v / (1.f + expf(-v));  // SiLU
        Lout[sl * 128 + c] = v;
    }
    __syncthreads();
    if (donorm) {
        int token = tid >> 3, part = tid & 7;
        float ss = 0.f;
#pragma unroll
        for (int i = 0; i < 16; ++i) {
            float v = Lout[token * 128 + part * 16 + i];
            ss += v * v;
        }
        ss += __shfl_xor(ss, 1); ss += __shfl_xor(ss, 2); ss += __shfl_xor(ss, 4);
        if (part == 0) Lsc[token] = rsqrtf(ss + 1e-6f) * nmul;
        __syncthreads();
#pragma unroll
        for (int j = 0; j < 16; ++j) {
            int sl = sg * 16 + j;
            outp[(long)sl * 128 + c] = (f16)(Lout[sl * 128 + c] * Lsc[sl]);
        }
    } else {
#pragma unroll
        for (int j = 0; j < 16; ++j) {
            int sl = sg * 16 + j;
            outp[(long)sl * 128 + c] = (f16)Lout[sl * 128 + c];
        }
    }
}

// ------------------------------------------------------------------
// g = -exp(a_log)*softplus(a+dt_bias) (RAW, not exp), beta = sigmoid(b)
// ------------------------------------------------------------------
__global__ __launch_bounds__(256) void gb_kernel(const float* __restrict__ ba,
                                                 const float* __restrict__ a_log,
                                                 const float* __restrict__ dt_bias,
                                                 float* __restrict__ gout,
                                                 float* __restrict__ bt) {
    int idx = blockIdx.x * 256 + threadIdx.x;  // ((b*32+hv)*2048 + s)
    if (idx >= 2 * 32 * 2048) return;
    int s = idx & 2047;
    int hv = (idx >> 11) & 31;
    int b = idx >> 16;
    int gg = hv & 1, hk = hv >> 1;
    long base = ((long)b * 2048 + s) * 64 + hk * 4;
    float bv = ba[base + gg];
    float av = ba[base + 2 + gg];
    float xx = av + dt_bias[hv];
    float sp = (xx > 20.f) ? xx : log1pf(expf(xx));
    gout[idx] = -expf(a_log[hv]) * sp;
    bt[idx] = 1.f / (1.f + expf(-bv));
}

// ------------------------------------------------------------------
// kh [bh][2048][128] -> khT [bh][128][2048]  (f16 transpose)
// ------------------------------------------------------------------
__global__ __launch_bounds__(256) void kT_kernel(const f16* __restrict__ kh,
                                                 f16* __restrict__ khT) {
    __shared__ f16 t[64][136];
    int bh = blockIdx.x >> 5;
    int s0 = (blockIdx.x & 31) * 64;
    int tid = threadIdx.x;
#pragma unroll
    for (int it = 0; it < 4; ++it) {
        int P = (tid + it * 256) * 8;
        int r = P >> 7, col = P & 127;
        *(f16x8*)&t[r][col] = *(const f16x8*)(kh + ((long)bh * 2048 + s0 + r) * 128 + col);
    }
    __syncthreads();
#pragma unroll
    for (int it = 0; it < 4; ++it) {
        int Q = (tid + it * 256) * 8;
        int dk = Q >> 6, sc = Q & 63;
        f16x8 v;
#pragma unroll
        for (int e = 0; e < 8; ++e) v[e] = t[sc + e][dk];
        *(f16x8*)(khT + ((long)bh * 128 + dk) * 2048 + s0 + sc) = v;
    }
}

// ------------------------------------------------------------------
// chunk_pre: per (b,hv,chunk of 32) — one wave.
// ------------------------------------------------------------------
__global__ __launch_bounds__(64) void chunk_pre_kernel(const f16* __restrict__ qh,
                                                       const f16* __restrict__ kh,
                                                       const f16* __restrict__ vh,
                                                       const float* __restrict__ gb,
                                                       const float* __restrict__ bt,
                                                       f16* __restrict__ Wg,
                                                       f16* __restrict__ T2ng,
                                                       f16* __restrict__ d0g,
                                                       float* __restrict__ pvg) {
    __shared__ f16 Kl[32 * 128];
    __shared__ f16 Ql[32 * 128];
    __shared__ f16 VTl[128 * 32];
    __shared__ float KKl[32 * 32];
    __shared__ float RL[32 * 32];
    __shared__ float Tf[32 * 33];
    __shared__ f16 Tl[32 * 64];
    __shared__ float cuml[32], bl[32], pl[32];

    int bid = blockIdx.x;
    int chunk = bid & 63;
    int hv = (bid >> 6) & 31;
    int b = bid >> 11;
    int bh = b * 16 + (hv >> 1);
    int l = threadIdx.x;
    int h = l >> 4, c = l & 15;
    long chid = bid;

    const f16* kbase = kh + ((long)bh * 2048 + chunk * 32) * 128;
    const f16* qbase = qh + ((long)bh * 2048 + chunk * 32) * 128;
    const f16* vbase = vh + (((long)b * 32 + hv) * 2048 + chunk * 32) * 128;
    const float* gp = gb + ((long)b * 32 + hv) * 2048 + chunk * 32;
    const float* bp = bt + ((long)b * 32 + hv) * 2048 + chunk * 32;

    float gv = (l < 32) ? gp[l] : 0.f;
#pragma unroll
    for (int d = 1; d < 32; d <<= 1) {
        float t2 = __shfl_up(gv, d);
        if (l >= d) gv += t2;
    }
    if (l < 32) { cuml[l] = gv; bl[l] = bp[l]; pl[l] = expf(gv); }

#pragma unroll
    for (int it = 0; it < 8; ++it) {
        int P = (l + it * 64) * 16;
        int row = P >> 8;
        int sw = P ^ ((row & 7) << 4);
        *(f16x8*)((char*)Kl + sw) = *(const f16x8*)((const char*)kbase + (long)row * 256 + (P & 255));
        *(f16x8*)((char*)Ql + sw) = *(const f16x8*)((const char*)qbase + (long)row * 256 + (P & 255));
    }
    __syncthreads();

#pragma unroll
    for (int it = 0; it < 8; ++it) {
        int idx = (l + it * 64) * 8;
        int row = idx >> 7, col = idx & 127;
        f16x8 v = *(const f16x8*)(vbase + (long)row * 128 + col);
        float be = bl[row];
#pragma unroll
        for (int e = 0; e < 8; ++e) {
            int dv = col + e;
            int byte = (dv * 64 + row * 2) ^ ((dv & 3) << 4);
            *(f16*)((char*)VTl + byte) = (f16)((float)v[e] * be);
        }
    }
#pragma unroll
    for (int it = 0; it < 16; ++it) {
        int e = l * 16 + it;
        int i = e >> 5, j = e & 31;
        RL[e] = (j <= i) ? expf(cuml[i] - cuml[j]) : 0.f;
    }
    __syncthreads();

    auto fragKQ = [&](const f16* base, int ti, int kk) {
        int row = c + 16 * ti;
        int byte = row * 256 + ((kk * 64 + h * 16) ^ ((row & 7) << 4));
        return *(const f16x8*)((const char*)base + byte);
    };

    {
        f32x4 acc[2][2] = {};
#pragma unroll
        for (int kk = 0; kk < 4; ++kk) {
            f16x8 fa0 = fragKQ(Kl, 0, kk), fa1 = fragKQ(Kl, 1, kk);
            acc[0][0] = __builtin_amdgcn_mfma_f32_16x16x32_f16(fa0, fa0, acc[0][0], 0, 0, 0);
            acc[0][1] = __builtin_amdgcn_mfma_f32_16x16x32_f16(fa0, fa1, acc[0][1], 0, 0, 0);
            acc[1][0] = __builtin_amdgcn_mfma_f32_16x16x32_f16(fa1, fa0, acc[1][0], 0, 0, 0);
            acc[1][1] = __builtin_amdgcn_mfma_f32_16x16x32_f16(fa1, fa1, acc[1][1], 0, 0, 0);
        }
#pragma unroll
        for (int ti = 0; ti < 2; ++ti)
#pragma unroll
            for (int tj = 0; tj < 2; ++tj)
#pragma unroll
                for (int r = 0; r < 4; ++r)
                    KKl[(h * 4 + r + 16 * ti) * 32 + c + 16 * tj] = acc[ti][tj][r];
    }
    {
        f32x4 acc[2][2] = {};
#pragma unroll
        for (int kk = 0; kk < 4; ++kk) {
            f16x8 fq0 = fragKQ(Ql, 0, kk), fq1 = fragKQ(Ql, 1, kk);
            f16x8 fk0 = fragKQ(Kl, 0, kk), fk1 = fragKQ(Kl, 1, kk);
            acc[0][0] = __builtin_amdgcn_mfma_f32_16x16x32_f16(fq0, fk0, acc[0][0], 0, 0, 0);
            acc[0][1] = __builtin_amdgcn_mfma_f32_16x16x32_f16(fq0, fk1, acc[0][1], 0, 0, 0);
            acc[1][0] = __builtin_amdgcn_mfma_f32_16x16x32_f16(fq1, fk0, acc[1][0], 0, 0, 0);
            acc[1][1] = __builtin_amdgcn_mfma_f32_16x16x32_f16(fq1, fk1, acc[1][1], 0, 0, 0);
        }
        __syncthreads();
#pragma unroll
        for (int ti = 0; ti < 2; ++ti)
#pragma unroll
            for (int tj = 0; tj < 2; ++tj)
#pragma unroll
                for (int r = 0; r < 4; ++r) {
                    int i = h * 4 + r + 16 * ti, j = c + 16 * tj;
                    Wg[chid * 1024 + i * 32 + j] = (f16)(acc[ti][tj][r] * RL[i * 32 + j]);
                }
    }

    if (l < 32) {
        int j = l;
        for (int i = 0; i < 32; ++i) {
            float s = (i == j) ? 1.f : 0.f;
            float bi = bl[i];
            for (int ll = j; ll < i; ++ll)
                s -= bi * KKl[i * 32 + ll] * RL[i * 32 + ll] * Tf[ll * 33 + j];
            Tf[i * 33 + j] = s;
        }
        float bpj = bl[j] * pl[j];
        for (int i = 0; i < 32; ++i) {
            float tv = (i >= j) ? Tf[i * 33 + j] : 0.f;
            int byte = (i * 128 + j * 2) ^ ((i & 3) << 4);
            *(f16*)((char*)Tl + byte) = (f16)tv;
            T2ng[chid * 1024 + i * 32 + j] = (f16)(-tv * bpj);
        }
        pvg[chid * 64 + j] = pl[j];
        pvg[chid * 64 + 32 + j] = expf(cuml[31] - cuml[j]);
    }
    __syncthreads();

    {
        f16x8 fT[2];
#pragma unroll
        for (int ti = 0; ti < 2; ++ti) {
            int row = c + 16 * ti;
            fT[ti] = *(const f16x8*)((const char*)Tl + ((row * 128 + h * 16) ^ ((row & 3) << 4)));
        }
#pragma unroll
        for (int nj = 0; nj < 8; ++nj) {
            int dv = c + 16 * nj;
            f16x8 fv = *(const f16x8*)((const char*)VTl + ((dv * 64 + h * 16) ^ ((dv & 3) << 4)));
            f32x4 a0 = {}, a1 = {};
            a0 = __builtin_amdgcn_mfma_f32_16x16x32_f16(fT[0], fv, a0, 0, 0, 0);
            a1 = __builtin_amdgcn_mfma_f32_16x16x32_f16(fT[1], fv, a1, 0, 0, 0);
            f16x4 s0, s1;
#pragma unroll
            for (int r = 0; r < 4; ++r) { s0[r] = (f16)a0[r]; s1[r] = (f16)a1[r]; }
            *(f16x4*)(d0g + chid * 4096 + (long)dv * 32 + 4 * h) = s0;
            *(f16x4*)(d0g + chid * 4096 + (long)dv * 32 + 16 + 4 * h) = s1;
        }
    }
}

// ------------------------------------------------------------------
// sequential chunked scan: grid 512 = (b,hv,vs of 16 dv); 1 wave.
// XCD-grouped bid swizzle keeps all 8 dv-siblings on one XCD L2.
// S (f16, [dv][dk] in LDS, double-buffered). 28 MFMAs/chunk.
// ------------------------------------------------------------------
__global__ __launch_bounds__(64) void scan_kernel(const f16* __restrict__ qh,
                                                  const f16* __restrict__ kh,
                                                  const f16* __restrict__ khT,
                                                  const f16* __restrict__ Wg,
                                                  const f16* __restrict__ T2ng,
                                                  const f16* __restrict__ d0g,
                                                  const float* __restrict__ pvg,
                                                  f16* __restrict__ ob) {
    __shared__ f16 Sl[2][16 * 128];  // [dv][dk], swz ^((dv&7)<<4)
    __shared__ f16 AKl[16 * 32];     // [dv][step], swz ^((dv&3)<<4)
    __shared__ f16 Dl[16 * 32];

    int pbid = blockIdx.x;
    int bid = (pbid & 7) * 64 + (pbid >> 3);  // XCD-grouping (512 %8==0, bijective)
    int vs = bid & 7;
    int hv = (bid >> 3) & 31;
    int b = bid >> 8;
    int bh32 = b * 32 + hv;
    int bh = b * 16 + (hv >> 1);
    int l = threadIdx.x, h = l >> 4, c = l & 15;

    const f16* kb = kh + (long)bh * 2048 * 128;
    const f16* qb = qh + (long)bh * 2048 * 128;
    const f16* ktb = khT + (long)bh * 128 * 2048;

    f16x8 z = {};
#pragma unroll
    for (int it = 0; it < 4; ++it) *(f16x8*)((char*)Sl[0] + (l + it * 64) * 16) = z;
    __syncthreads();

    int cur = 0;
    for (int ch = 0; ch < 64; ++ch) {
        long chid = (long)bh32 * 64 + ch;
        f16x8 fk[2][4], fq[2][4], fkt[8], fT[2], fW[2];
#pragma unroll
        for (int ti = 0; ti < 2; ++ti) {
            long row = ch * 32 + c + 16 * ti;
#pragma unroll
            for (int kk = 0; kk < 4; ++kk) {
                fk[ti][kk] = *(const f16x8*)(kb + row * 128 + kk * 32 + h * 8);
                fq[ti][kk] = *(const f16x8*)(qb + row * 128 + kk * 32 + h * 8);
            }
            fT[ti] = *(const f16x8*)(T2ng + chid * 1024 + (c + 16 * ti) * 32 + h * 8);
            fW[ti] = *(const f16x8*)(Wg + chid * 1024 + (c + 16 * ti) * 32 + h * 8);
        }
#pragma unroll
        for (int ti = 0; ti < 8; ++ti)
            fkt[ti] = *(const f16x8*)(ktb + (long)(c + 16 * ti) * 2048 + ch * 32 + h * 8);
        f16x4 fd0[2];
#pragma unroll
        for (int ti = 0; ti < 2; ++ti)
            fd0[ti] = *(const f16x4*)(d0g + chid * 4096 +
                                      (long)(vs * 16 + c) * 32 + 16 * ti + 4 * h);
        f32x4 pva = *(const f32x4*)(pvg + chid * 64 + 4 * h);
        f32x4 pvb = *(const f32x4*)(pvg + chid * 64 + 16 + 4 * h);
        float pc = pvg[chid * 64 + 31];
        f32x4 kwa = *(const f32x4*)(pvg + chid * 64 + 32 + h * 8);
        f32x4 kwb = *(const f32x4*)(pvg + chid * 64 + 36 + h * 8);

        const int dv = c;  // this block's dv column within its 16-slice
        f16x8 fS[4];
#pragma unroll
        for (int kk = 0; kk < 4; ++kk)
            fS[kk] = *(const f16x8*)((char*)Sl[cur] +
                                     (dv * 256 + ((kk * 64 + h * 16) ^ ((dv & 7) << 4))));
        f32x4 AK[2] = {}, AQ[2] = {};
#pragma unroll
        for (int ti = 0; ti < 2; ++ti)
#pragma unroll
            for (int kk = 0; kk < 4; ++kk) {
                AK[ti] = __builtin_amdgcn_mfma_f32_16x16x32_f16(fk[ti][kk], fS[kk], AK[ti], 0, 0, 0);
                AQ[ti] = __builtin_amdgcn_mfma_f32_16x16x32_f16(fq[ti][kk], fS[kk], AQ[ti], 0, 0, 0);
            }
#pragma unroll
        for (int ti = 0; ti < 2; ++ti) {
            f16x4 t;
#pragma unroll
            for (int r = 0; r < 4; ++r) t[r] = (f16)AK[ti][r];
            *(f16x4*)((char*)AKl + ((dv * 64 + 32 * ti + 8 * h) ^ ((dv & 3) << 4))) = t;
        }
        f32x4 Dv[2];
#pragma unroll
        for (int ti = 0; ti < 2; ++ti)
#pragma unroll
            for (int r = 0; r < 4; ++r) Dv[ti][r] = (float)fd0[ti][r];
        {
            f16x8 fak = *(const f16x8*)((char*)AKl + ((dv * 64 + h * 16) ^ ((dv & 3) << 4)));
#pragma unroll
            for (int ti = 0; ti < 2; ++ti)
                Dv[ti] = __builtin_amdgcn_mfma_f32_16x16x32_f16(fT[ti], fak, Dv[ti], 0, 0, 0);
        }
#pragma unroll
        for (int ti = 0; ti < 2; ++ti) {
            f16x4 t;
#pragma unroll
            for (int r = 0; r < 4; ++r) t[r] = (f16)Dv[ti][r];
            *(f16x4*)((char*)Dl + ((dv * 64 + 32 * ti + 8 * h) ^ ((dv & 3) << 4))) = t;
        }
        f16x8 fdl = *(const f16x8*)((char*)Dl + ((dv * 64 + h * 16) ^ ((dv & 3) << 4)));
        f32x4 Ov[2];
#pragma unroll
        for (int ti = 0; ti < 2; ++ti)
#pragma unroll
            for (int r = 0; r < 4; ++r)
                Ov[ti][r] = AQ[ti][r] * (ti ? pvb[r] : pva[r]);
#pragma unroll
        for (int ti = 0; ti < 2; ++ti)
            Ov[ti] = __builtin_amdgcn_mfma_f32_16x16x32_f16(fW[ti], fdl, Ov[ti], 0, 0, 0);
#pragma unroll
        for (int ti = 0; ti < 2; ++ti)
#pragma unroll
            for (int r = 0; r < 4; ++r) {
                long tok = (long)b * 2048 + ch * 32 + 16 * ti + 4 * h + r;
                ob[tok * 4096 + hv * 128 + vs * 16 + c] = (f16)Ov[ti][r];
            }
#pragma unroll
        for (int ti = 0; ti < 8; ++ti) {
            f16x8 fa;
#pragma unroll
            for (int e = 0; e < 8; ++e)
                fa[e] = (f16)((float)fkt[ti][e] * (e < 4 ? kwa[e] : kwb[e - 4]));
            int sbyte = (dv * 256 + (32 * ti + 8 * h)) ^ ((dv & 7) << 4);
            f16x4 sold = *(const f16x4*)((char*)Sl[cur] + sbyte);
            f32x4 acc;
#pragma unroll
            for (int r = 0; r < 4; ++r) acc[r] = pc * (float)sold[r];
            acc = __builtin_amdgcn_mfma_f32_16x16x32_f16(fa, fdl, acc, 0, 0, 0);
            f16x4 snew;
#pragma unroll
            for (int r = 0; r < 4; ++r) snew[r] = (f16)acc[r];
            *(f16x4*)((char*)Sl[cur ^ 1] + sbyte) = snew;
        }
        cur ^= 1;
        __syncthreads();
    }
}

// ------------------------------------------------------------------
// y = rmsnorm(o * silu(z)) * norm_w  -> f16
// ------------------------------------------------------------------
__global__ __launch_bounds__(256) void gate_kernel(const f16* __restrict__ o,
                                                   const f16* __restrict__ qkvz,
                                                   const float* __restrict__ norm_w,
                                                   f16* __restrict__ y) {
    int token = blockIdx.x;  // b*2048 + s
    int tid = threadIdx.x;
    int hv = tid >> 3, part = tid & 7;
    int dv0 = part * 16;
    const f16* orow = o + ((long)token * 32 + hv) * 128 + dv0;
    long zcol = (long)(hv >> 1) * 768 + 512 + (hv & 1) * 128 + dv0;
    const f16* zrow = qkvz + (long)token * 12288 + zcol;
    float yv[16];
    float ss = 0.f;
#pragma unroll
    for (int i = 0; i < 16; ++i) {
        float ov = (float)orow[i];
        float zv = (float)zrow[i];
        float gt = zv / (1.f + expf(-zv));
        float v = ov * gt;
        yv[i] = v;
        ss += v * v;
    }
    ss += __shfl_xor(ss, 1); ss += __shfl_xor(ss, 2); ss += __shfl_xor(ss, 4);
    float scale = rsqrtf(ss * (1.f / 128.f) + 1e-6f);
    f16* yrow = y + (long)token * 4096 + hv * 128 + dv0;
#pragma unroll
    for (int i = 0; i < 16; ++i) yrow[i] = (f16)(yv[i] * scale * norm_w[dv0 + i]);
}

// ------------------------------------------------------------------
// Workspace (242 MB, time-aliased) — lifetime-audited (r11 layout):
//   [0,96)    qkvz16  (gemm1 -> gate)
//   [96,97)   bab     (ba_gemm -> gb; over dead x16)
//   [96,112)  x16 (cvt -> gemm1)
//   [112,160) WT (transpose -> gemm1)
//   [96,128)  d0g (chunk_pre -> scan; overwrites bab AFTER gb consumed it)
//   [128,136) Wg ; [136,144) T2ng ; [144,160) khT  (post-gemm1)
//   [160,176) WTo (transpose -> gemm2)
//   [176,208) qh,kh (conv -> scan); y16 over it after scan
//   [208,240) vh (conv -> chunk_pre); ob over it (scan -> gate)
//   [240,240.5) gbuf ; [240.5,241) btb ; [241,242) pvg
// ------------------------------------------------------------------
extern "C" void kernel_launch(void* const* d_in, const int* in_sizes, int n_in,
                              void* d_out, int out_size, void* d_ws, size_t ws_size,
                              hipStream_t stream) {
    const float* x       = (const float*)d_in[0];
    const float* w_qkvz  = (const float*)d_in[1];
    const float* w_ba    = (const float*)d_in[2];
    const float* conv_w  = (const float*)d_in[3];
    const float* conv_b  = (const float*)d_in[4];
    const float* a_log   = (const float*)d_in[5];
    const float* dt_bias = (const float*)d_in[6];
    const float* norm_w  = (const float*)d_in[7];
    const float* w_o     = (const float*)d_in[8];
    float* out = (float*)d_out;

    char* ws = (char*)d_ws;
    const size_t MB = 1024 * 1024;
    f16*   qkvz16 = (f16*)ws;
    f16*   x16    = (f16*)(ws + 96 * MB);
    f16*   WT     = (f16*)(ws + 112 * MB);
    float* bab    = (float*)(ws + 96 * MB);   // over dead x16; consumed before d0g
    f16*   d0g    = (f16*)(ws + 96 * MB);
    f16*   Wg     = (f16*)(ws + 128 * MB);
    f16*   T2ng   = (f16*)(ws + 136 * MB);
    f16*   khT    = (f16*)(ws + 144 * MB);
    f16*   WTo    = (f16*)(ws + 160 * MB);
    f16*   qh     = (f16*)(ws + 176 * MB);
    f16*   kh     = (f16*)(ws + 192 * MB);
    f16*   vh     = (f16*)(ws + 208 * MB);
    f16*   ob     = (f16*)(ws + 208 * MB);
    f16*   y16    = (f16*)(ws + 176 * MB);
    float* gbuf   = (float*)(ws + 240 * MB);
    float* btb    = (float*)(ws + 240 * MB + 512 * 1024);
    float* pvg    = (float*)(ws + 241 * MB);

    // prep
    cvt16_kernel<<<8192, 256, 0, stream>>>(x, x16, 4096 * 2048 / 4);
    transpose16_kernel<<<dim3(12288 / 64, 2048 / 64), 256, 0, stream>>>(w_qkvz, WT, 2048, 12288);
    transpose16_kernel<<<dim3(2048 / 64, 4096 / 64), 256, 0, stream>>>(w_o, WTo, 4096, 2048);

    // qkvz = x @ w_qkvz  (1D grid 3072 tiles, XCD swizzle)
    gemm16_kernel<1><<<3072, 256, 0, stream>>>(x16, WT, qkvz16, 4096, 12288, 2048);
    // ba = x @ w_ba  (writes over dead x16)
    ba_gemm_kernel<<<256, 256, 0, stream>>>(x, w_ba, bab);

    // conv + silu + l2norm
    conv_kernel<<<dim3(64, 64, 2), 256, 0, stream>>>(qkvz16, conv_w, conv_b, qh, kh, vh);
    // g, beta
    gb_kernel<<<512, 256, 0, stream>>>(bab, a_log, dt_bias, gbuf, btb);
    // k transpose
    kT_kernel<<<1024, 256, 0, stream>>>(kh, khT);
    // per-chunk UT-transform precompute
    chunk_pre_kernel<<<4096, 64, 0, stream>>>(qh, kh, vh, gbuf, btb, Wg, T2ng, d0g, pvg);
    // sequential chunked MFMA scan (512 blocks of 16 dv, 2/CU)
    scan_kernel<<<512, 64, 0, stream>>>(qh, kh, khT, Wg, T2ng, d0g, pvg, ob);

    // gating + rmsnorm -> y16
    gate_kernel<<<4096, 256, 0, stream>>>(ob, qkvz16, norm_w, y16);

    // out = y @ w_o  (1D grid 512 tiles, XCD swizzle)
    gemm16_kernel<0><<<512, 256, 0, stream>>>(y16, WTo, out, 4096, 2048, 4096);
}

// Round 13
// 921.205 us; speedup vs baseline: 1.3503x; 1.1201x over previous
//
#include <hip/hip_runtime.h>

typedef _Float16 f16;
typedef _Float16 f16x2 __attribute__((ext_vector_type(2)));
typedef _Float16 f16x4 __attribute__((ext_vector_type(4)));
typedef _Float16 f16x8 __attribute__((ext_vector_type(8)));
typedef float f32x4 __attribute__((ext_vector_type(4)));

#define QSCALE 0.08838834764831845f  // DK^-0.5

#define RAW_BARRIER() do { \
    asm volatile("s_waitcnt lgkmcnt(0)" ::: "memory"); \
    __builtin_amdgcn_s_barrier(); \
    __builtin_amdgcn_sched_barrier(0); \
} while (0)

// ------------------------------------------------------------------
// convert fp32 -> f16 (vectorized x4)
// ------------------------------------------------------------------
__global__ __launch_bounds__(256) void cvt16_kernel(const float* __restrict__ in,
                                                    f16* __restrict__ out, int n4) {
    int i = blockIdx.x * 256 + threadIdx.x;
    if (i >= n4) return;
    f32x4 v = ((const f32x4*)in)[i];
    f16x4 h;
    h[0] = (f16)v[0]; h[1] = (f16)v[1]; h[2] = (f16)v[2]; h[3] = (f16)v[3];
    ((f16x4*)out)[i] = h;
}

// ------------------------------------------------------------------
// transpose fp32 [R][C] -> f16 [C][R]
// ------------------------------------------------------------------
__global__ __launch_bounds__(256) void transpose16_kernel(const float* __restrict__ in,
                                                          f16* __restrict__ out, int R, int C) {
    __shared__ f16 tile[64][66];
    int c0 = blockIdx.x * 64, r0 = blockIdx.y * 64;
    int tid = threadIdx.x;
#pragma unroll
    for (int i = 0; i < 16; ++i) {
        int idx = i * 256 + tid;
        int r = idx >> 6, c = idx & 63;
        tile[r][c] = (f16)in[(long)(r0 + r) * C + (c0 + c)];
    }
    __syncthreads();
#pragma unroll
    for (int i = 0; i < 16; ++i) {
        int idx = i * 256 + tid;
        int orow = idx >> 6, oc = idx & 63;
        out[(long)(c0 + orow) * R + (r0 + oc)] = tile[oc][orow];
    }
}

// ------------------------------------------------------------------
// 256x256 deep-pipelined f16 MFMA GEMM (gemm1).
// 8 waves (2x4), BK=64, 128KB dbuf LDS, reg-staged 2-ahead prefetch,
// raw s_barrier + lgkmcnt(0) only (global loads stay in flight).
// ------------------------------------------------------------------
__global__ __launch_bounds__(512, 1) void gemm256_kernel(const f16* __restrict__ A,
                                                         const f16* __restrict__ Bt,
                                                         f16* __restrict__ Cout,
                                                         int M, int N, int Kd) {
    __shared__ f16 sA[2][256 * 64];
    __shared__ f16 sB[2][256 * 64];
    const int tid = threadIdx.x;
    const int lane = tid & 63, wv = tid >> 6;
    const int wm = wv >> 2, wn = wv & 3;      // 2 x 4 wave grid
    const int m0 = blockIdx.y * 256, n0 = blockIdx.x * 256;
    const int lrow = lane & 15, lk = lane >> 4;
    const int nK = Kd >> 6;

    f32x4 acc[8][4] = {};
    f32x4 ra[4], rb[4];

    auto issue = [&](int k0) {
#pragma unroll
        for (int j = 0; j < 4; ++j) {
            int P = (tid + j * 512) * 16;       // linear byte in 32KB tile
            int row = P >> 7;
            int koff = (P & 127) >> 1;          // f16 elems
            ra[j] = *(const f32x4*)(A + (long)(m0 + row) * Kd + k0 + koff);
            rb[j] = *(const f32x4*)(Bt + (long)(n0 + row) * Kd + k0 + koff);
        }
    };
    auto commit = [&](int buf) {
#pragma unroll
        for (int j = 0; j < 4; ++j) {
            int P = (tid + j * 512) * 16;
            int row = P >> 7;
            int sw = P ^ ((row & 7) << 4);
            *(f32x4*)((char*)&sA[buf][0] + sw) = ra[j];
            *(f32x4*)((char*)&sB[buf][0] + sw) = rb[j];
        }
    };

    // prologue: tile0 into buf0; tile1 loads in flight
    issue(0);
    commit(0);
    if (nK > 1) issue(64);
    RAW_BARRIER();

    int cur = 0;
    for (int t = 0; t < nK; ++t) {
        if (t + 1 < nK) commit(cur ^ 1);        // waits (hidden) vmcnt for t+1 loads
        if (t + 2 < nK) issue((t + 2) * 64);    // stays in flight across barrier
        const char* bA = (const char*)&sA[cur][0];
        const char* bB = (const char*)&sB[cur][0];
#pragma unroll
        for (int kk = 0; kk < 2; ++kk) {
            f16x8 bf[4];
#pragma unroll
            for (int j = 0; j < 4; ++j) {
                int brow = wn * 64 + j * 16 + lrow;
                int bbyte = brow * 128 + kk * 64 + lk * 16;
                bf[j] = *(const f16x8*)(bB + (bbyte ^ ((brow & 7) << 4)));
            }
#pragma unroll
            for (int i = 0; i < 8; ++i) {
                int arow = wm * 128 + i * 16 + lrow;
                int abyte = arow * 128 + kk * 64 + lk * 16;
                f16x8 af = *(const f16x8*)(bA + (abyte ^ ((arow & 7) << 4)));
#pragma unroll
                for (int j = 0; j < 4; ++j)
                    acc[i][j] = __builtin_amdgcn_mfma_f32_16x16x32_f16(af, bf[j], acc[i][j], 0, 0, 0);
            }
        }
        RAW_BARRIER();
        cur ^= 1;
    }

#pragma unroll
    for (int i = 0; i < 8; ++i) {
        int gm_base = m0 + wm * 128 + i * 16 + lk * 4;
#pragma unroll
        for (int j = 0; j < 4; ++j) {
            int gn = n0 + wn * 64 + j * 16 + lrow;
#pragma unroll
            for (int r = 0; r < 4; ++r)
                Cout[(long)(gm_base + r) * N + gn] = (f16)acc[i][j][r];
        }
    }
}

// ------------------------------------------------------------------
// f16 MFMA GEMM (r7/r11 proven 128² version — gemm2)
// ------------------------------------------------------------------
template <int F16OUT>
__global__ __launch_bounds__(256) void gemm16_kernel(const f16* __restrict__ A,
                                                     const f16* __restrict__ Bt,
                                                     void* __restrict__ Cout,
                                                     int M, int N, int Kd) {
    __shared__ f16 sA[128 * 64];
    __shared__ f16 sB[128 * 64];
    const int tid = threadIdx.x;
    const int lane = tid & 63, wv = tid >> 6;
    const int wm = wv >> 1, wn = wv & 1;
    const int m0 = blockIdx.y * 128, n0 = blockIdx.x * 128;
    const int lrow = lane & 15, lk = lane >> 4;
    f32x4 acc[4][4] = {};
    for (int k0 = 0; k0 < Kd; k0 += 64) {
        __syncthreads();
#pragma unroll
        for (int j = 0; j < 4; ++j) {
            int P = (tid + j * 256) * 16;
            int row = P >> 7;
            int sw = P ^ ((row & 7) << 4);
            int koff = P & 127;
            const char* ga = (const char*)(A + (long)(m0 + row) * Kd + k0) + koff;
            *(f32x4*)((char*)sA + sw) = *(const f32x4*)ga;
            const char* gb = (const char*)(Bt + (long)(n0 + row) * Kd + k0) + koff;
            *(f32x4*)((char*)sB + sw) = *(const f32x4*)gb;
        }
        __syncthreads();
#pragma unroll
        for (int kk = 0; kk < 2; ++kk) {
            f16x8 af[4], bf[4];
#pragma unroll
            for (int i = 0; i < 4; ++i) {
                int arow = wm * 64 + i * 16 + lrow;
                int abyte = arow * 128 + kk * 64 + lk * 16;
                af[i] = *(const f16x8*)((const char*)sA + (abyte ^ ((arow & 7) << 4)));
                int brow = wn * 64 + i * 16 + lrow;
                int bbyte = brow * 128 + kk * 64 + lk * 16;
                bf[i] = *(const f16x8*)((const char*)sB + (bbyte ^ ((brow & 7) << 4)));
            }
#pragma unroll
            for (int i = 0; i < 4; ++i)
#pragma unroll
                for (int j = 0; j < 4; ++j)
                    acc[i][j] = __builtin_amdgcn_mfma_f32_16x16x32_f16(af[i], bf[j], acc[i][j], 0, 0, 0);
        }
    }
#pragma unroll
    for (int i = 0; i < 4; ++i) {
        int gm_base = m0 + wm * 64 + i * 16 + lk * 4;
#pragma unroll
        for (int j = 0; j < 4; ++j) {
            int gn = n0 + wn * 64 + j * 16 + lrow;
#pragma unroll
            for (int r = 0; r < 4; ++r) {
                long idx = (long)(gm_base + r) * N + gn;
                if (F16OUT) ((f16*)Cout)[idx] = (f16)acc[i][j][r];
                else        ((float*)Cout)[idx] = acc[i][j][r];
            }
        }
    }
}

// ------------------------------------------------------------------
// ba = x @ w_ba   (fp32)
// ------------------------------------------------------------------
__global__ __launch_bounds__(256) void ba_gemm_kernel(const float* __restrict__ x,
                                                      const float* __restrict__ w,
                                                      float* __restrict__ ba) {
    __shared__ float xs[16][256];
    int tid = threadIdx.x;
    int t0 = blockIdx.x * 16;
    int o = tid & 63, tg = tid >> 6;
    float acc[4] = {0.f, 0.f, 0.f, 0.f};
    for (int kc = 0; kc < 2048; kc += 256) {
        __syncthreads();
#pragma unroll
        for (int i = 0; i < 16; ++i) {
            int idx = i * 256 + tid;
            int tok = idx >> 8, k = idx & 255;
            xs[tok][k] = x[(long)(t0 + tok) * 2048 + kc + k];
        }
        __syncthreads();
        for (int k = 0; k < 256; ++k) {
            float wv = w[(long)(kc + k) * 64 + o];
#pragma unroll
            for (int j = 0; j < 4; ++j) acc[j] += xs[tg * 4 + j][k] * wv;
        }
    }
#pragma unroll
    for (int j = 0; j < 4; ++j) ba[(long)(t0 + tg * 4 + j) * 64 + o] = acc[j];
}

// ------------------------------------------------------------------
// depthwise causal conv(K=4) + bias + SiLU (+ L2norm for q/k heads)
// vectorized f16x8 staging (G13)
// ------------------------------------------------------------------
__global__ __launch_bounds__(256) void conv_kernel(const f16* __restrict__ qkvz,
                                                   const float* __restrict__ cw,
                                                   const float* __restrict__ cb,
                                                   f16* __restrict__ qh,
                                                   f16* __restrict__ kh,
                                                   f16* __restrict__ vh) {
    __shared__ float Lin[35 * 128];
    __shared__ float Lout[32 * 128];
    __shared__ float Lsc[32];
    int g = blockIdx.x;
    int s0 = blockIdx.y * 32;
    int b = blockIdx.z;
    int tid = threadIdx.x;
    int colbase, chbase;
    f16* outp;
    bool donorm;
    float nmul;
    if (g < 16) {
        colbase = g * 768; chbase = g * 128;
        outp = qh + (((long)b * 16 + g) * 2048 + s0) * 128;
        donorm = true; nmul = QSCALE;
    } else if (g < 32) {
        int hk = g - 16;
        colbase = hk * 768 + 128; chbase = 2048 + hk * 128;
        outp = kh + (((long)b * 16 + hk) * 2048 + s0) * 128;
        donorm = true; nmul = 1.f;
    } else {
        int hv = g - 32;
        colbase = (hv >> 1) * 768 + 256 + (hv & 1) * 128; chbase = 4096 + hv * 128;
        outp = vh + (((long)b * 32 + hv) * 2048 + s0) * 128;
        donorm = false; nmul = 1.f;
    }
    for (int ci = tid; ci < 35 * 16; ci += 256) {
        int sr = ci >> 4, cc = (ci & 15) * 8;
        int s = s0 + sr - 3;
        f32x4 lo = {}, hi = {};
        if (s >= 0) {
            f16x8 v = *(const f16x8*)(qkvz + ((long)b * 2048 + s) * 12288 + colbase + cc);
#pragma unroll
            for (int e = 0; e < 4; ++e) { lo[e] = (float)v[e]; hi[e] = (float)v[4 + e]; }
        }
        *(f32x4*)&Lin[sr * 128 + cc] = lo;
        *(f32x4*)&Lin[sr * 128 + cc + 4] = hi;
    }
    __syncthreads();
    int c = tid & 127, sg = tid >> 7;
    float w0 = cw[(chbase + c) * 4 + 0];
    float w1 = cw[(chbase + c) * 4 + 1];
    float w2 = cw[(chbase + c) * 4 + 2];
    float w3 = cw[(chbase + c) * 4 + 3];
    float bias = cb[chbase + c];
#pragma unroll
    for (int j = 0; j < 16; ++j) {
        int sl = sg * 16 + j;
        float v = w0 * Lin[sl * 128 + c] + w1 * Lin[(sl + 1) * 128 + c] +
                  w2 * Lin[(sl + 2) * 128 + c] + w3 * Lin[(sl + 3) * 128 + c] + bias;
        v = v / (1.f + expf(-v));  // SiLU
        Lout[sl * 128 + c] = v;
    }
    __syncthreads();
    if (donorm) {
        int token = tid >> 3, part = tid & 7;
        float ss = 0.f;
#pragma unroll
        for (int i = 0; i < 16; ++i) {
            float v = Lout[token * 128 + part * 16 + i];
            ss += v * v;
        }
        ss += __shfl_xor(ss, 1); ss += __shfl_xor(ss, 2); ss += __shfl_xor(ss, 4);
        if (part == 0) Lsc[token] = rsqrtf(ss + 1e-6f) * nmul;
        __syncthreads();
#pragma unroll
        for (int j = 0; j < 16; ++j) {
            int sl = sg * 16 + j;
            outp[(long)sl * 128 + c] = (f16)(Lout[sl * 128 + c] * Lsc[sl]);
        }
    } else {
#pragma unroll
        for (int j = 0; j < 16; ++j) {
            int sl = sg * 16 + j;
            outp[(long)sl * 128 + c] = (f16)Lout[sl * 128 + c];
        }
    }
}

// ------------------------------------------------------------------
// g = -exp(a_log)*softplus(a+dt_bias) (RAW), beta = sigmoid(b)
// ------------------------------------------------------------------
__global__ __launch_bounds__(256) void gb_kernel(const float* __restrict__ ba,
                                                 const float* __restrict__ a_log,
                                                 const float* __restrict__ dt_bias,
                                                 float* __restrict__ gout,
                                                 float* __restrict__ bt) {
    int idx = blockIdx.x * 256 + threadIdx.x;  // ((b*32+hv)*2048 + s)
    if (idx >= 2 * 32 * 2048) return;
    int s = idx & 2047;
    int hv = (idx >> 11) & 31;
    int b = idx >> 16;
    int gg = hv & 1, hk = hv >> 1;
    long base = ((long)b * 2048 + s) * 64 + hk * 4;
    float bv = ba[base + gg];
    float av = ba[base + 2 + gg];
    float xx = av + dt_bias[hv];
    float sp = (xx > 20.f) ? xx : log1pf(expf(xx));
    gout[idx] = -expf(a_log[hv]) * sp;
    bt[idx] = 1.f / (1.f + expf(-bv));
}

// ------------------------------------------------------------------
// kh [bh][2048][128] -> khT [bh][128][2048]  (f16 transpose)
// ------------------------------------------------------------------
__global__ __launch_bounds__(256) void kT_kernel(const f16* __restrict__ kh,
                                                 f16* __restrict__ khT) {
    __shared__ f16 t[64][136];
    int bh = blockIdx.x >> 5;
    int s0 = (blockIdx.x & 31) * 64;
    int tid = threadIdx.x;
#pragma unroll
    for (int it = 0; it < 4; ++it) {
        int P = (tid + it * 256) * 8;
        int r = P >> 7, col = P & 127;
        *(f16x8*)&t[r][col] = *(const f16x8*)(kh + ((long)bh * 2048 + s0 + r) * 128 + col);
    }
    __syncthreads();
#pragma unroll
    for (int it = 0; it < 4; ++it) {
        int Q = (tid + it * 256) * 8;
        int dk = Q >> 6, sc = Q & 63;
        f16x8 v;
#pragma unroll
        for (int e = 0; e < 8; ++e) v[e] = t[sc + e][dk];
        *(f16x8*)(khT + ((long)bh * 128 + dk) * 2048 + s0 + sc) = v;
    }
}

// ------------------------------------------------------------------
// chunk_pre: per (b,hv,chunk of 32) — one wave.
// ------------------------------------------------------------------
__global__ __launch_bounds__(64) void chunk_pre_kernel(const f16* __restrict__ qh,
                                                       const f16* __restrict__ kh,
                                                       const f16* __restrict__ vh,
                                                       const float* __restrict__ gb,
                                                       const float* __restrict__ bt,
                                                       f16* __restrict__ Wg,
                                                       f16* __restrict__ T2ng,
                                                       f16* __restrict__ d0g,
                                                       float* __restrict__ pvg) {
    __shared__ f16 Kl[32 * 128];
    __shared__ f16 Ql[32 * 128];
    __shared__ f16 VTl[128 * 32];
    __shared__ float KKl[32 * 32];
    __shared__ float RL[32 * 32];
    __shared__ float Tf[32 * 33];
    __shared__ f16 Tl[32 * 64];
    __shared__ float cuml[32], bl[32], pl[32];

    int bid = blockIdx.x;
    int chunk = bid & 63;
    int hv = (bid >> 6) & 31;
    int b = bid >> 11;
    int bh = b * 16 + (hv >> 1);
    int l = threadIdx.x;
    int h = l >> 4, c = l & 15;
    long chid = bid;

    const f16* kbase = kh + ((long)bh * 2048 + chunk * 32) * 128;
    const f16* qbase = qh + ((long)bh * 2048 + chunk * 32) * 128;
    const f16* vbase = vh + (((long)b * 32 + hv) * 2048 + chunk * 32) * 128;
    const float* gp = gb + ((long)b * 32 + hv) * 2048 + chunk * 32;
    const float* bp = bt + ((long)b * 32 + hv) * 2048 + chunk * 32;

    float gv = (l < 32) ? gp[l] : 0.f;
#pragma unroll
    for (int d = 1; d < 32; d <<= 1) {
        float t2 = __shfl_up(gv, d);
        if (l >= d) gv += t2;
    }
    if (l < 32) { cuml[l] = gv; bl[l] = bp[l]; pl[l] = expf(gv); }

#pragma unroll
    for (int it = 0; it < 8; ++it) {
        int P = (l + it * 64) * 16;
        int row = P >> 8;
        int sw = P ^ ((row & 7) << 4);
        *(f16x8*)((char*)Kl + sw) = *(const f16x8*)((const char*)kbase + (long)row * 256 + (P & 255));
        *(f16x8*)((char*)Ql + sw) = *(const f16x8*)((const char*)qbase + (long)row * 256 + (P & 255));
    }
    __syncthreads();

#pragma unroll
    for (int it = 0; it < 8; ++it) {
        int idx = (l + it * 64) * 8;
        int row = idx >> 7, col = idx & 127;
        f16x8 v = *(const f16x8*)(vbase + (long)row * 128 + col);
        float be = bl[row];
#pragma unroll
        for (int e = 0; e < 8; ++e) {
            int dv = col + e;
            int byte = (dv * 64 + row * 2) ^ ((dv & 3) << 4);
            *(f16*)((char*)VTl + byte) = (f16)((float)v[e] * be);
        }
    }
#pragma unroll
    for (int it = 0; it < 16; ++it) {
        int e = l * 16 + it;
        int i = e >> 5, j = e & 31;
        RL[e] = (j <= i) ? expf(cuml[i] - cuml[j]) : 0.f;
    }
    __syncthreads();

    auto fragKQ = [&](const f16* base, int ti, int kk) {
        int row = c + 16 * ti;
        int byte = row * 256 + ((kk * 64 + h * 16) ^ ((row & 7) << 4));
        return *(const f16x8*)((const char*)base + byte);
    };

    {
        f32x4 acc[2][2] = {};
#pragma unroll
        for (int kk = 0; kk < 4; ++kk) {
            f16x8 fa0 = fragKQ(Kl, 0, kk), fa1 = fragKQ(Kl, 1, kk);
            acc[0][0] = __builtin_amdgcn_mfma_f32_16x16x32_f16(fa0, fa0, acc[0][0], 0, 0, 0);
            acc[0][1] = __builtin_amdgcn_mfma_f32_16x16x32_f16(fa0, fa1, acc[0][1], 0, 0, 0);
            acc[1][0] = __builtin_amdgcn_mfma_f32_16x16x32_f16(fa1, fa0, acc[1][0], 0, 0, 0);
            acc[1][1] = __builtin_amdgcn_mfma_f32_16x16x32_f16(fa1, fa1, acc[1][1], 0, 0, 0);
        }
#pragma unroll
        for (int ti = 0; ti < 2; ++ti)
#pragma unroll
            for (int tj = 0; tj < 2; ++tj)
#pragma unroll
                for (int r = 0; r < 4; ++r)
                    KKl[(h * 4 + r + 16 * ti) * 32 + c + 16 * tj] = acc[ti][tj][r];
    }
    {
        f32x4 acc[2][2] = {};
#pragma unroll
        for (int kk = 0; kk < 4; ++kk) {
            f16x8 fq0 = fragKQ(Ql, 0, kk), fq1 = fragKQ(Ql, 1, kk);
            f16x8 fk0 = fragKQ(Kl, 0, kk), fk1 = fragKQ(Kl, 1, kk);
            acc[0][0] = __builtin_amdgcn_mfma_f32_16x16x32_f16(fq0, fk0, acc[0][0], 0, 0, 0);
            acc[0][1] = __builtin_amdgcn_mfma_f32_16x16x32_f16(fq0, fk1, acc[0][1], 0, 0, 0);
            acc[1][0] = __builtin_amdgcn_mfma_f32_16x16x32_f16(fq1, fk0, acc[1][0], 0, 0, 0);
            acc[1][1] = __builtin_amdgcn_mfma_f32_16x16x32_f16(fq1, fk1, acc[1][1], 0, 0, 0);
        }
        __syncthreads();
#pragma unroll
        for (int ti = 0; ti < 2; ++ti)
#pragma unroll
            for (int tj = 0; tj < 2; ++tj)
#pragma unroll
                for (int r = 0; r < 4; ++r) {
                    int i = h * 4 + r + 16 * ti, j = c + 16 * tj;
                    Wg[chid * 1024 + i * 32 + j] = (f16)(acc[ti][tj][r] * RL[i * 32 + j]);
                }
    }

    if (l < 32) {
        int j = l;
        for (int i = 0; i < 32; ++i) {
            float s = (i == j) ? 1.f : 0.f;
            float bi = bl[i];
            for (int ll = j; ll < i; ++ll)
                s -= bi * KKl[i * 32 + ll] * RL[i * 32 + ll] * Tf[ll * 33 + j];
            Tf[i * 33 + j] = s;
        }
        float bpj = bl[j] * pl[j];
        for (int i = 0; i < 32; ++i) {
            float tv = (i >= j) ? Tf[i * 33 + j] : 0.f;
            int byte = (i * 128 + j * 2) ^ ((i & 3) << 4);
            *(f16*)((char*)Tl + byte) = (f16)tv;
            T2ng[chid * 1024 + i * 32 + j] = (f16)(-tv * bpj);
        }
        pvg[chid * 64 + j] = pl[j];
        pvg[chid * 64 + 32 + j] = expf(cuml[31] - cuml[j]);
    }
    __syncthreads();

    {
        f16x8 fT[2];
#pragma unroll
        for (int ti = 0; ti < 2; ++ti) {
            int row = c + 16 * ti;
            fT[ti] = *(const f16x8*)((const char*)Tl + ((row * 128 + h * 16) ^ ((row & 3) << 4)));
        }
#pragma unroll
        for (int nj = 0; nj < 8; ++nj) {
            int dv = c + 16 * nj;
            f16x8 fv = *(const f16x8*)((const char*)VTl + ((dv * 64 + h * 16) ^ ((dv & 3) << 4)));
            f32x4 a0 = {}, a1 = {};
            a0 = __builtin_amdgcn_mfma_f32_16x16x32_f16(fT[0], fv, a0, 0, 0, 0);
            a1 = __builtin_amdgcn_mfma_f32_16x16x32_f16(fT[1], fv, a1, 0, 0, 0);
            f16x4 s0, s1;
#pragma unroll
            for (int r = 0; r < 4; ++r) { s0[r] = (f16)a0[r]; s1[r] = (f16)a1[r]; }
            *(f16x4*)(d0g + chid * 4096 + (long)dv * 32 + 4 * h) = s0;
            *(f16x4*)(d0g + chid * 4096 + (long)dv * 32 + 16 + 4 * h) = s1;
        }
    }
}

// ------------------------------------------------------------------
// sequential chunked scan: grid 512 = (b,hv,vs of 16 dv); 1 wave.
// ------------------------------------------------------------------
__global__ __launch_bounds__(64) void scan_kernel(const f16* __restrict__ qh,
                                                  const f16* __restrict__ kh,
                                                  const f16* __restrict__ khT,
                                                  const f16* __restrict__ Wg,
                                                  const f16* __restrict__ T2ng,
                                                  const f16* __restrict__ d0g,
                                                  const float* __restrict__ pvg,
                                                  f16* __restrict__ ob) {
    __shared__ f16 Sl[2][16 * 128];
    __shared__ f16 AKl[16 * 32];
    __shared__ f16 Dl[16 * 32];

    int pbid = blockIdx.x;
    int bid = (pbid & 7) * 64 + (pbid >> 3);
    int vs = bid & 7;
    int hv = (bid >> 3) & 31;
    int b = bid >> 8;
    int bh32 = b * 32 + hv;
    int bh = b * 16 + (hv >> 1);
    int l = threadIdx.x, h = l >> 4, c = l & 15;

    const f16* kb = kh + (long)bh * 2048 * 128;
    const f16* qb = qh + (long)bh * 2048 * 128;
    const f16* ktb = khT + (long)bh * 128 * 2048;

    f16x8 z = {};
#pragma unroll
    for (int it = 0; it < 4; ++it) *(f16x8*)((char*)Sl[0] + (l + it * 64) * 16) = z;
    __syncthreads();

    int cur = 0;
    for (int ch = 0; ch < 64; ++ch) {
        long chid = (long)bh32 * 64 + ch;
        f16x8 fk[2][4], fq[2][4], fkt[8], fT[2], fW[2];
#pragma unroll
        for (int ti = 0; ti < 2; ++ti) {
            long row = ch * 32 + c + 16 * ti;
#pragma unroll
            for (int kk = 0; kk < 4; ++kk) {
                fk[ti][kk] = *(const f16x8*)(kb + row * 128 + kk * 32 + h * 8);
                fq[ti][kk] = *(const f16x8*)(qb + row * 128 + kk * 32 + h * 8);
            }
            fT[ti] = *(const f16x8*)(T2ng + chid * 1024 + (c + 16 * ti) * 32 + h * 8);
            fW[ti] = *(const f16x8*)(Wg + chid * 1024 + (c + 16 * ti) * 32 + h * 8);
        }
#pragma unroll
        for (int ti = 0; ti < 8; ++ti)
            fkt[ti] = *(const f16x8*)(ktb + (long)(c + 16 * ti) * 2048 + ch * 32 + h * 8);
        f16x4 fd0[2];
#pragma unroll
        for (int ti = 0; ti < 2; ++ti)
            fd0[ti] = *(const f16x4*)(d0g + chid * 4096 +
                                      (long)(vs * 16 + c) * 32 + 16 * ti + 4 * h);
        f32x4 pva = *(const f32x4*)(pvg + chid * 64 + 4 * h);
        f32x4 pvb = *(const f32x4*)(pvg + chid * 64 + 16 + 4 * h);
        float pc = pvg[chid * 64 + 31];
        f32x4 kwa = *(const f32x4*)(pvg + chid * 64 + 32 + h * 8);
        f32x4 kwb = *(const f32x4*)(pvg + chid * 64 + 36 + h * 8);

        const int dv = c;
        f16x8 fS[4];
#pragma unroll
        for (int kk = 0; kk < 4; ++kk)
            fS[kk] = *(const f16x8*)((char*)Sl[cur] +
                                     (dv * 256 + ((kk * 64 + h * 16) ^ ((dv & 7) << 4))));
        f32x4 AK[2] = {}, AQ[2] = {};
#pragma unroll
        for (int ti = 0; ti < 2; ++ti)
#pragma unroll
            for (int kk = 0; kk < 4; ++kk) {
                AK[ti] = __builtin_amdgcn_mfma_f32_16x16x32_f16(fk[ti][kk], fS[kk], AK[ti], 0, 0, 0);
                AQ[ti] = __builtin_amdgcn_mfma_f32_16x16x32_f16(fq[ti][kk], fS[kk], AQ[ti], 0, 0, 0);
            }
#pragma unroll
        for (int ti = 0; ti < 2; ++ti) {
            f16x4 t;
#pragma unroll
            for (int r = 0; r < 4; ++r) t[r] = (f16)AK[ti][r];
            *(f16x4*)((char*)AKl + ((dv * 64 + 32 * ti + 8 * h) ^ ((dv & 3) << 4))) = t;
        }
        f32x4 Dv[2];
#pragma unroll
        for (int ti = 0; ti < 2; ++ti)
#pragma unroll
            for (int r = 0; r < 4; ++r) Dv[ti][r] = (float)fd0[ti][r];
        {
            f16x8 fak = *(const f16x8*)((char*)AKl + ((dv * 64 + h * 16) ^ ((dv & 3) << 4)));
#pragma unroll
            for (int ti = 0; ti < 2; ++ti)
                Dv[ti] = __builtin_amdgcn_mfma_f32_16x16x32_f16(fT[ti], fak, Dv[ti], 0, 0, 0);
        }
#pragma unroll
        for (int ti = 0; ti < 2; ++ti) {
            f16x4 t;
#pragma unroll
            for (int r = 0; r < 4; ++r) t[r] = (f16)Dv[ti][r];
            *(f16x4*)((char*)Dl + ((dv * 64 + 32 * ti + 8 * h) ^ ((dv & 3) << 4))) = t;
        }
        f16x8 fdl = *(const f16x8*)((char*)Dl + ((dv * 64 + h * 16) ^ ((dv & 3) << 4)));
        f32x4 Ov[2];
#pragma unroll
        for (int ti = 0; ti < 2; ++ti)
#pragma unroll
            for (int r = 0; r < 4; ++r)
                Ov[ti][r] = AQ[ti][r] * (ti ? pvb[r] : pva[r]);
#pragma unroll
        for (int ti = 0; ti < 2; ++ti)
            Ov[ti] = __builtin_amdgcn_mfma_f32_16x16x32_f16(fW[ti], fdl, Ov[ti], 0, 0, 0);
#pragma unroll
        for (int ti = 0; ti < 2; ++ti)
#pragma unroll
            for (int r = 0; r < 4; ++r) {
                long tok = (long)b * 2048 + ch * 32 + 16 * ti + 4 * h + r;
                ob[tok * 4096 + hv * 128 + vs * 16 + c] = (f16)Ov[ti][r];
            }
#pragma unroll
        for (int ti = 0; ti < 8; ++ti) {
            f16x8 fa;
#pragma unroll
            for (int e = 0; e < 8; ++e)
                fa[e] = (f16)((float)fkt[ti][e] * (e < 4 ? kwa[e] : kwb[e - 4]));
            int sbyte = (dv * 256 + (32 * ti + 8 * h)) ^ ((dv & 7) << 4);
            f16x4 sold = *(const f16x4*)((char*)Sl[cur] + sbyte);
            f32x4 acc;
#pragma unroll
            for (int r = 0; r < 4; ++r) acc[r] = pc * (float)sold[r];
            acc = __builtin_amdgcn_mfma_f32_16x16x32_f16(fa, fdl, acc, 0, 0, 0);
            f16x4 snew;
#pragma unroll
            for (int r = 0; r < 4; ++r) snew[r] = (f16)acc[r];
            *(f16x4*)((char*)Sl[cur ^ 1] + sbyte) = snew;
        }
        cur ^= 1;
        __syncthreads();
    }
}

// ------------------------------------------------------------------
// y = rmsnorm(o * silu(z)) * norm_w  -> f16  (vectorized f16x8)
// ------------------------------------------------------------------
__global__ __launch_bounds__(256) void gate_kernel(const f16* __restrict__ o,
                                                   const f16* __restrict__ qkvz,
                                                   const float* __restrict__ norm_w,
                                                   f16* __restrict__ y) {
    int token = blockIdx.x;  // b*2048 + s
    int tid = threadIdx.x;
    int hv = tid >> 3, part = tid & 7;
    int dv0 = part * 16;
    const f16* orow = o + ((long)token * 32 + hv) * 128 + dv0;
    long zcol = (long)(hv >> 1) * 768 + 512 + (hv & 1) * 128 + dv0;
    const f16* zrow = qkvz + (long)token * 12288 + zcol;
    f16x8 ov0 = *(const f16x8*)orow, ov1 = *(const f16x8*)(orow + 8);
    f16x8 zv0 = *(const f16x8*)zrow, zv1 = *(const f16x8*)(zrow + 8);
    float yv[16];
    float ss = 0.f;
#pragma unroll
    for (int i = 0; i < 16; ++i) {
        float ovf = (float)(i < 8 ? ov0[i] : ov1[i - 8]);
        float zvf = (float)(i < 8 ? zv0[i] : zv1[i - 8]);
        float gt = zvf / (1.f + expf(-zvf));
        float v = ovf * gt;
        yv[i] = v;
        ss += v * v;
    }
    ss += __shfl_xor(ss, 1); ss += __shfl_xor(ss, 2); ss += __shfl_xor(ss, 4);
    float scale = rsqrtf(ss * (1.f / 128.f) + 1e-6f);
    f16* yrow = y + (long)token * 4096 + hv * 128 + dv0;
    f16x8 y0, y1;
#pragma unroll
    for (int i = 0; i < 8; ++i) {
        y0[i] = (f16)(yv[i] * scale * norm_w[dv0 + i]);
        y1[i] = (f16)(yv[8 + i] * scale * norm_w[dv0 + 8 + i]);
    }
    *(f16x8*)yrow = y0;
    *(f16x8*)(yrow + 8) = y1;
}

// ------------------------------------------------------------------
// Workspace (242 MB, time-aliased) — r11 lifetime-audited layout.
// ------------------------------------------------------------------
extern "C" void kernel_launch(void* const* d_in, const int* in_sizes, int n_in,
                              void* d_out, int out_size, void* d_ws, size_t ws_size,
                              hipStream_t stream) {
    const float* x       = (const float*)d_in[0];
    const float* w_qkvz  = (const float*)d_in[1];
    const float* w_ba    = (const float*)d_in[2];
    const float* conv_w  = (const float*)d_in[3];
    const float* conv_b  = (const float*)d_in[4];
    const float* a_log   = (const float*)d_in[5];
    const float* dt_bias = (const float*)d_in[6];
    const float* norm_w  = (const float*)d_in[7];
    const float* w_o     = (const float*)d_in[8];
    float* out = (float*)d_out;

    char* ws = (char*)d_ws;
    const size_t MB = 1024 * 1024;
    f16*   qkvz16 = (f16*)ws;
    f16*   x16    = (f16*)(ws + 96 * MB);
    f16*   WT     = (f16*)(ws + 112 * MB);
    float* bab    = (float*)(ws + 96 * MB);   // over dead x16; consumed before d0g
    f16*   d0g    = (f16*)(ws + 96 * MB);
    f16*   Wg     = (f16*)(ws + 128 * MB);
    f16*   T2ng   = (f16*)(ws + 136 * MB);
    f16*   khT    = (f16*)(ws + 144 * MB);
    f16*   WTo    = (f16*)(ws + 160 * MB);
    f16*   qh     = (f16*)(ws + 176 * MB);
    f16*   kh     = (f16*)(ws + 192 * MB);
    f16*   vh     = (f16*)(ws + 208 * MB);
    f16*   ob     = (f16*)(ws + 208 * MB);
    f16*   y16    = (f16*)(ws + 176 * MB);
    float* gbuf   = (float*)(ws + 240 * MB);
    float* btb    = (float*)(ws + 240 * MB + 512 * 1024);
    float* pvg    = (float*)(ws + 241 * MB);

    // prep
    cvt16_kernel<<<8192, 256, 0, stream>>>(x, x16, 4096 * 2048 / 4);
    transpose16_kernel<<<dim3(12288 / 64, 2048 / 64), 256, 0, stream>>>(w_qkvz, WT, 2048, 12288);
    transpose16_kernel<<<dim3(2048 / 64, 4096 / 64), 256, 0, stream>>>(w_o, WTo, 4096, 2048);

    // qkvz = x @ w_qkvz  (256² deep-pipelined, 8 waves)
    gemm256_kernel<<<dim3(12288 / 256, 4096 / 256), 512, 0, stream>>>(x16, WT, qkvz16, 4096, 12288, 2048);
    // ba = x @ w_ba
    ba_gemm_kernel<<<256, 256, 0, stream>>>(x, w_ba, bab);

    // conv + silu + l2norm
    conv_kernel<<<dim3(64, 64, 2), 256, 0, stream>>>(qkvz16, conv_w, conv_b, qh, kh, vh);
    // g, beta
    gb_kernel<<<512, 256, 0, stream>>>(bab, a_log, dt_bias, gbuf, btb);
    // k transpose
    kT_kernel<<<1024, 256, 0, stream>>>(kh, khT);
    // per-chunk UT-transform precompute
    chunk_pre_kernel<<<4096, 64, 0, stream>>>(qh, kh, vh, gbuf, btb, Wg, T2ng, d0g, pvg);
    // sequential chunked MFMA scan
    scan_kernel<<<512, 64, 0, stream>>>(qh, kh, khT, Wg, T2ng, d0g, pvg, ob);

    // gating + rmsnorm -> y16
    gate_kernel<<<4096, 256, 0, stream>>>(ob, qkvz16, norm_w, y16);

    // out = y @ w_o  (proven 128² kernel, 2D grid)
    gemm16_kernel<0><<<dim3(2048 / 128, 4096 / 128), 256, 0, stream>>>(y16, WTo, out, 4096, 2048, 4096);
}

// Round 14
// 905.346 us; speedup vs baseline: 1.3740x; 1.0175x over previous
//
#include <hip/hip_runtime.h>

typedef _Float16 f16;
typedef _Float16 f16x2 __attribute__((ext_vector_type(2)));
typedef _Float16 f16x4 __attribute__((ext_vector_type(4)));
typedef _Float16 f16x8 __attribute__((ext_vector_type(8)));
typedef float f32x4 __attribute__((ext_vector_type(4)));

#define QSCALE 0.08838834764831845f  // DK^-0.5

#define RAW_BARRIER() do { \
    asm volatile("s_waitcnt lgkmcnt(0)" ::: "memory"); \
    __builtin_amdgcn_s_barrier(); \
    __builtin_amdgcn_sched_barrier(0); \
} while (0)

// ------------------------------------------------------------------
// convert fp32 -> f16 (vectorized x4)
// ------------------------------------------------------------------
__global__ __launch_bounds__(256) void cvt16_kernel(const float* __restrict__ in,
                                                    f16* __restrict__ out, int n4) {
    int i = blockIdx.x * 256 + threadIdx.x;
    if (i >= n4) return;
    f32x4 v = ((const f32x4*)in)[i];
    f16x4 h;
    h[0] = (f16)v[0]; h[1] = (f16)v[1]; h[2] = (f16)v[2]; h[3] = (f16)v[3];
    ((f16x4*)out)[i] = h;
}

// ------------------------------------------------------------------
// transpose fp32 [R][C] -> f16 [C][R]
// ------------------------------------------------------------------
__global__ __launch_bounds__(256) void transpose16_kernel(const float* __restrict__ in,
                                                          f16* __restrict__ out, int R, int C) {
    __shared__ f16 tile[64][66];
    int c0 = blockIdx.x * 64, r0 = blockIdx.y * 64;
    int tid = threadIdx.x;
#pragma unroll
    for (int i = 0; i < 16; ++i) {
        int idx = i * 256 + tid;
        int r = idx >> 6, c = idx & 63;
        tile[r][c] = (f16)in[(long)(r0 + r) * C + (c0 + c)];
    }
    __syncthreads();
#pragma unroll
    for (int i = 0; i < 16; ++i) {
        int idx = i * 256 + tid;
        int orow = idx >> 6, oc = idx & 63;
        out[(long)(c0 + orow) * R + (r0 + oc)] = tile[oc][orow];
    }
}

// ------------------------------------------------------------------
// 256xBN deep-pipelined f16 MFMA GEMM. BN = 64*NJ (NJ=4 -> 256, NJ=2 -> 128).
// 8 waves (2x4), BK=64, dbuf LDS, reg-staged 2-ahead prefetch,
// raw s_barrier + lgkmcnt(0) only (global loads stay in flight).
// T5: setprio around the compute phase.
// ------------------------------------------------------------------
template <int NJ, int F16OUT>
__global__ __launch_bounds__(512, 1) void gemm256_kernel(const f16* __restrict__ A,
                                                         const f16* __restrict__ Bt,
                                                         void* __restrict__ Cout,
                                                         int M, int N, int Kd) {
    constexpr int BN = 64 * NJ;
    constexpr int BNW = 16 * NJ;           // per-wave B width
    __shared__ f16 sA[2][256 * 64];
    __shared__ f16 sB[2][BN * 64];
    const int tid = threadIdx.x;
    const int lane = tid & 63, wv = tid >> 6;
    const int wm = wv >> 2, wn = wv & 3;   // 2 x 4 wave grid
    const int m0 = blockIdx.y * 256, n0 = blockIdx.x * BN;
    const int lrow = lane & 15, lk = lane >> 4;
    const int nK = Kd >> 6;

    f32x4 acc[8][NJ] = {};
    f32x4 ra[4], rb[NJ];

    auto issue = [&](int k0) {
#pragma unroll
        for (int j = 0; j < 4; ++j) {
            int P = (tid + j * 512) * 16;
            int row = P >> 7;
            int koff = (P & 127) >> 1;
            ra[j] = *(const f32x4*)(A + (long)(m0 + row) * Kd + k0 + koff);
        }
#pragma unroll
        for (int j = 0; j < NJ; ++j) {
            int P = (tid + j * 512) * 16;
            int row = P >> 7;
            int koff = (P & 127) >> 1;
            rb[j] = *(const f32x4*)(Bt + (long)(n0 + row) * Kd + k0 + koff);
        }
    };
    auto commit = [&](int buf) {
#pragma unroll
        for (int j = 0; j < 4; ++j) {
            int P = (tid + j * 512) * 16;
            int row = P >> 7;
            int sw = P ^ ((row & 7) << 4);
            *(f32x4*)((char*)&sA[buf][0] + sw) = ra[j];
        }
#pragma unroll
        for (int j = 0; j < NJ; ++j) {
            int P = (tid + j * 512) * 16;
            int row = P >> 7;
            int sw = P ^ ((row & 7) << 4);
            *(f32x4*)((char*)&sB[buf][0] + sw) = rb[j];
        }
    };

    issue(0);
    commit(0);
    if (nK > 1) issue(64);
    RAW_BARRIER();

    int cur = 0;
    for (int t = 0; t < nK; ++t) {
        if (t + 1 < nK) commit(cur ^ 1);
        if (t + 2 < nK) issue((t + 2) * 64);
        const char* bA = (const char*)&sA[cur][0];
        const char* bB = (const char*)&sB[cur][0];
        __builtin_amdgcn_s_setprio(1);
#pragma unroll
        for (int kk = 0; kk < 2; ++kk) {
            f16x8 bf[NJ];
#pragma unroll
            for (int j = 0; j < NJ; ++j) {
                int brow = wn * BNW + j * 16 + lrow;
                int bbyte = brow * 128 + kk * 64 + lk * 16;
                bf[j] = *(const f16x8*)(bB + (bbyte ^ ((brow & 7) << 4)));
            }
#pragma unroll
            for (int i = 0; i < 8; ++i) {
                int arow = wm * 128 + i * 16 + lrow;
                int abyte = arow * 128 + kk * 64 + lk * 16;
                f16x8 af = *(const f16x8*)(bA + (abyte ^ ((arow & 7) << 4)));
#pragma unroll
                for (int j = 0; j < NJ; ++j)
                    acc[i][j] = __builtin_amdgcn_mfma_f32_16x16x32_f16(af, bf[j], acc[i][j], 0, 0, 0);
            }
        }
        __builtin_amdgcn_s_setprio(0);
        RAW_BARRIER();
        cur ^= 1;
    }

#pragma unroll
    for (int i = 0; i < 8; ++i) {
        int gm_base = m0 + wm * 128 + i * 16 + lk * 4;
#pragma unroll
        for (int j = 0; j < NJ; ++j) {
            int gn = n0 + wn * BNW + j * 16 + lrow;
#pragma unroll
            for (int r = 0; r < 4; ++r) {
                long idx = (long)(gm_base + r) * N + gn;
                if (F16OUT) ((f16*)Cout)[idx] = (f16)acc[i][j][r];
                else        ((float*)Cout)[idx] = acc[i][j][r];
            }
        }
    }
}

// ------------------------------------------------------------------
// ba = x @ w_ba   (fp32)
// ------------------------------------------------------------------
__global__ __launch_bounds__(256) void ba_gemm_kernel(const float* __restrict__ x,
                                                      const float* __restrict__ w,
                                                      float* __restrict__ ba) {
    __shared__ float xs[16][256];
    int tid = threadIdx.x;
    int t0 = blockIdx.x * 16;
    int o = tid & 63, tg = tid >> 6;
    float acc[4] = {0.f, 0.f, 0.f, 0.f};
    for (int kc = 0; kc < 2048; kc += 256) {
        __syncthreads();
#pragma unroll
        for (int i = 0; i < 16; ++i) {
            int idx = i * 256 + tid;
            int tok = idx >> 8, k = idx & 255;
            xs[tok][k] = x[(long)(t0 + tok) * 2048 + kc + k];
        }
        __syncthreads();
        for (int k = 0; k < 256; ++k) {
            float wv = w[(long)(kc + k) * 64 + o];
#pragma unroll
            for (int j = 0; j < 4; ++j) acc[j] += xs[tg * 4 + j][k] * wv;
        }
    }
#pragma unroll
    for (int j = 0; j < 4; ++j) ba[(long)(t0 + tg * 4 + j) * 64 + o] = acc[j];
}

// ------------------------------------------------------------------
// depthwise causal conv(K=4) + bias + SiLU (+ L2norm for q/k heads)
// ------------------------------------------------------------------
__global__ __launch_bounds__(256) void conv_kernel(const f16* __restrict__ qkvz,
                                                   const float* __restrict__ cw,
                                                   const float* __restrict__ cb,
                                                   f16* __restrict__ qh,
                                                   f16* __restrict__ kh,
                                                   f16* __restrict__ vh) {
    __shared__ float Lin[35 * 128];
    __shared__ float Lout[32 * 128];
    __shared__ float Lsc[32];
    int g = blockIdx.x;
    int s0 = blockIdx.y * 32;
    int b = blockIdx.z;
    int tid = threadIdx.x;
    int colbase, chbase;
    f16* outp;
    bool donorm;
    float nmul;
    if (g < 16) {
        colbase = g * 768; chbase = g * 128;
        outp = qh + (((long)b * 16 + g) * 2048 + s0) * 128;
        donorm = true; nmul = QSCALE;
    } else if (g < 32) {
        int hk = g - 16;
        colbase = hk * 768 + 128; chbase = 2048 + hk * 128;
        outp = kh + (((long)b * 16 + hk) * 2048 + s0) * 128;
        donorm = true; nmul = 1.f;
    } else {
        int hv = g - 32;
        colbase = (hv >> 1) * 768 + 256 + (hv & 1) * 128; chbase = 4096 + hv * 128;
        outp = vh + (((long)b * 32 + hv) * 2048 + s0) * 128;
        donorm = false; nmul = 1.f;
    }
    for (int ci = tid; ci < 35 * 16; ci += 256) {
        int sr = ci >> 4, cc = (ci & 15) * 8;
        int s = s0 + sr - 3;
        f32x4 lo = {}, hi = {};
        if (s >= 0) {
            f16x8 v = *(const f16x8*)(qkvz + ((long)b * 2048 + s) * 12288 + colbase + cc);
#pragma unroll
            for (int e = 0; e < 4; ++e) { lo[e] = (float)v[e]; hi[e] = (float)v[4 + e]; }
        }
        *(f32x4*)&Lin[sr * 128 + cc] = lo;
        *(f32x4*)&Lin[sr * 128 + cc + 4] = hi;
    }
    __syncthreads();
    int c = tid & 127, sg = tid >> 7;
    float w0 = cw[(chbase + c) * 4 + 0];
    float w1 = cw[(chbase + c) * 4 + 1];
    float w2 = cw[(chbase + c) * 4 + 2];
    float w3 = cw[(chbase + c) * 4 + 3];
    float bias = cb[chbase + c];
#pragma unroll
    for (int j = 0; j < 16; ++j) {
        int sl = sg * 16 + j;
        float v = w0 * Lin[sl * 128 + c] + w1 * Lin[(sl + 1) * 128 + c] +
                  w2 * Lin[(sl + 2) * 128 + c] + w3 * Lin[(sl + 3) * 128 + c] + bias;
        v = v / (1.f + expf(-v));  // SiLU
        Lout[sl * 128 + c] = v;
    }
    __syncthreads();
    if (donorm) {
        int token = tid >> 3, part = tid & 7;
        float ss = 0.f;
#pragma unroll
        for (int i = 0; i < 16; ++i) {
            float v = Lout[token * 128 + part * 16 + i];
            ss += v * v;
        }
        ss += __shfl_xor(ss, 1); ss += __shfl_xor(ss, 2); ss += __shfl_xor(ss, 4);
        if (part == 0) Lsc[token] = rsqrtf(ss + 1e-6f) * nmul;
        __syncthreads();
#pragma unroll
        for (int j = 0; j < 16; ++j) {
            int sl = sg * 16 + j;
            outp[(long)sl * 128 + c] = (f16)(Lout[sl * 128 + c] * Lsc[sl]);
        }
    } else {
#pragma unroll
        for (int j = 0; j < 16; ++j) {
            int sl = sg * 16 + j;
            outp[(long)sl * 128 + c] = (f16)Lout[sl * 128 + c];
        }
    }
}

// ------------------------------------------------------------------
// g = -exp(a_log)*softplus(a+dt_bias) (RAW), beta = sigmoid(b)
// ------------------------------------------------------------------
__global__ __launch_bounds__(256) void gb_kernel(const float* __restrict__ ba,
                                                 const float* __restrict__ a_log,
                                                 const float* __restrict__ dt_bias,
                                                 float* __restrict__ gout,
                                                 float* __restrict__ bt) {
    int idx = blockIdx.x * 256 + threadIdx.x;  // ((b*32+hv)*2048 + s)
    if (idx >= 2 * 32 * 2048) return;
    int s = idx & 2047;
    int hv = (idx >> 11) & 31;
    int b = idx >> 16;
    int gg = hv & 1, hk = hv >> 1;
    long base = ((long)b * 2048 + s) * 64 + hk * 4;
    float bv = ba[base + gg];
    float av = ba[base + 2 + gg];
    float xx = av + dt_bias[hv];
    float sp = (xx > 20.f) ? xx : log1pf(expf(xx));
    gout[idx] = -expf(a_log[hv]) * sp;
    bt[idx] = 1.f / (1.f + expf(-bv));
}

// ------------------------------------------------------------------
// kh [bh][2048][128] -> khT [bh][128][2048]  (f16 transpose)
// ------------------------------------------------------------------
__global__ __launch_bounds__(256) void kT_kernel(const f16* __restrict__ kh,
                                                 f16* __restrict__ khT) {
    __shared__ f16 t[64][136];
    int bh = blockIdx.x >> 5;
    int s0 = (blockIdx.x & 31) * 64;
    int tid = threadIdx.x;
#pragma unroll
    for (int it = 0; it < 4; ++it) {
        int P = (tid + it * 256) * 8;
        int r = P >> 7, col = P & 127;
        *(f16x8*)&t[r][col] = *(const f16x8*)(kh + ((long)bh * 2048 + s0 + r) * 128 + col);
    }
    __syncthreads();
#pragma unroll
    for (int it = 0; it < 4; ++it) {
        int Q = (tid + it * 256) * 8;
        int dk = Q >> 6, sc = Q & 63;
        f16x8 v;
#pragma unroll
        for (int e = 0; e < 8; ++e) v[e] = t[sc + e][dk];
        *(f16x8*)(khT + ((long)bh * 128 + dk) * 2048 + s0 + sc) = v;
    }
}

// ------------------------------------------------------------------
// chunk_pre: per (b,hv,chunk of 32) — one wave.
// ------------------------------------------------------------------
__global__ __launch_bounds__(64) void chunk_pre_kernel(const f16* __restrict__ qh,
                                                       const f16* __restrict__ kh,
                                                       const f16* __restrict__ vh,
                                                       const float* __restrict__ gb,
                                                       const float* __restrict__ bt,
                                                       f16* __restrict__ Wg,
                                                       f16* __restrict__ T2ng,
                                                       f16* __restrict__ d0g,
                                                       float* __restrict__ pvg) {
    __shared__ f16 Kl[32 * 128];
    __shared__ f16 Ql[32 * 128];
    __shared__ f16 VTl[128 * 32];
    __shared__ float KKl[32 * 32];
    __shared__ float RL[32 * 32];
    __shared__ float Tf[32 * 33];
    __shared__ f16 Tl[32 * 64];
    __shared__ float cuml[32], bl[32], pl[32];

    int bid = blockIdx.x;
    int chunk = bid & 63;
    int hv = (bid >> 6) & 31;
    int b = bid >> 11;
    int bh = b * 16 + (hv >> 1);
    int l = threadIdx.x;
    int h = l >> 4, c = l & 15;
    long chid = bid;

    const f16* kbase = kh + ((long)bh * 2048 + chunk * 32) * 128;
    const f16* qbase = qh + ((long)bh * 2048 + chunk * 32) * 128;
    const f16* vbase = vh + (((long)b * 32 + hv) * 2048 + chunk * 32) * 128;
    const float* gp = gb + ((long)b * 32 + hv) * 2048 + chunk * 32;
    const float* bp = bt + ((long)b * 32 + hv) * 2048 + chunk * 32;

    float gv = (l < 32) ? gp[l] : 0.f;
#pragma unroll
    for (int d = 1; d < 32; d <<= 1) {
        float t2 = __shfl_up(gv, d);
        if (l >= d) gv += t2;
    }
    if (l < 32) { cuml[l] = gv; bl[l] = bp[l]; pl[l] = expf(gv); }

#pragma unroll
    for (int it = 0; it < 8; ++it) {
        int P = (l + it * 64) * 16;
        int row = P >> 8;
        int sw = P ^ ((row & 7) << 4);
        *(f16x8*)((char*)Kl + sw) = *(const f16x8*)((const char*)kbase + (long)row * 256 + (P & 255));
        *(f16x8*)((char*)Ql + sw) = *(const f16x8*)((const char*)qbase + (long)row * 256 + (P & 255));
    }
    __syncthreads();

#pragma unroll
    for (int it = 0; it < 8; ++it) {
        int idx = (l + it * 64) * 8;
        int row = idx >> 7, col = idx & 127;
        f16x8 v = *(const f16x8*)(vbase + (long)row * 128 + col);
        float be = bl[row];
#pragma unroll
        for (int e = 0; e < 8; ++e) {
            int dv = col + e;
            int byte = (dv * 64 + row * 2) ^ ((dv & 3) << 4);
            *(f16*)((char*)VTl + byte) = (f16)((float)v[e] * be);
        }
    }
#pragma unroll
    for (int it = 0; it < 16; ++it) {
        int e = l * 16 + it;
        int i = e >> 5, j = e & 31;
        RL[e] = (j <= i) ? expf(cuml[i] - cuml[j]) : 0.f;
    }
    __syncthreads();

    auto fragKQ = [&](const f16* base, int ti, int kk) {
        int row = c + 16 * ti;
        int byte = row * 256 + ((kk * 64 + h * 16) ^ ((row & 7) << 4));
        return *(const f16x8*)((const char*)base + byte);
    };

    {
        f32x4 acc[2][2] = {};
#pragma unroll
        for (int kk = 0; kk < 4; ++kk) {
            f16x8 fa0 = fragKQ(Kl, 0, kk), fa1 = fragKQ(Kl, 1, kk);
            acc[0][0] = __builtin_amdgcn_mfma_f32_16x16x32_f16(fa0, fa0, acc[0][0], 0, 0, 0);
            acc[0][1] = __builtin_amdgcn_mfma_f32_16x16x32_f16(fa0, fa1, acc[0][1], 0, 0, 0);
            acc[1][0] = __builtin_amdgcn_mfma_f32_16x16x32_f16(fa1, fa0, acc[1][0], 0, 0, 0);
            acc[1][1] = __builtin_amdgcn_mfma_f32_16x16x32_f16(fa1, fa1, acc[1][1], 0, 0, 0);
        }
#pragma unroll
        for (int ti = 0; ti < 2; ++ti)
#pragma unroll
            for (int tj = 0; tj < 2; ++tj)
#pragma unroll
                for (int r = 0; r < 4; ++r)
                    KKl[(h * 4 + r + 16 * ti) * 32 + c + 16 * tj] = acc[ti][tj][r];
    }
    {
        f32x4 acc[2][2] = {};
#pragma unroll
        for (int kk = 0; kk < 4; ++kk) {
            f16x8 fq0 = fragKQ(Ql, 0, kk), fq1 = fragKQ(Ql, 1, kk);
            f16x8 fk0 = fragKQ(Kl, 0, kk), fk1 = fragKQ(Kl, 1, kk);
            acc[0][0] = __builtin_amdgcn_mfma_f32_16x16x32_f16(fq0, fk0, acc[0][0], 0, 0, 0);
            acc[0][1] = __builtin_amdgcn_mfma_f32_16x16x32_f16(fq0, fk1, acc[0][1], 0, 0, 0);
            acc[1][0] = __builtin_amdgcn_mfma_f32_16x16x32_f16(fq1, fk0, acc[1][0], 0, 0, 0);
            acc[1][1] = __builtin_amdgcn_mfma_f32_16x16x32_f16(fq1, fk1, acc[1][1], 0, 0, 0);
        }
        __syncthreads();
#pragma unroll
        for (int ti = 0; ti < 2; ++ti)
#pragma unroll
            for (int tj = 0; tj < 2; ++tj)
#pragma unroll
                for (int r = 0; r < 4; ++r) {
                    int i = h * 4 + r + 16 * ti, j = c + 16 * tj;
                    Wg[chid * 1024 + i * 32 + j] = (f16)(acc[ti][tj][r] * RL[i * 32 + j]);
                }
    }

    if (l < 32) {
        int j = l;
        for (int i = 0; i < 32; ++i) {
            float s = (i == j) ? 1.f : 0.f;
            float bi = bl[i];
            for (int ll = j; ll < i; ++ll)
                s -= bi * KKl[i * 32 + ll] * RL[i * 32 + ll] * Tf[ll * 33 + j];
            Tf[i * 33 + j] = s;
        }
        float bpj = bl[j] * pl[j];
        for (int i = 0; i < 32; ++i) {
            float tv = (i >= j) ? Tf[i * 33 + j] : 0.f;
            int byte = (i * 128 + j * 2) ^ ((i & 3) << 4);
            *(f16*)((char*)Tl + byte) = (f16)tv;
            T2ng[chid * 1024 + i * 32 + j] = (f16)(-tv * bpj);
        }
        pvg[chid * 64 + j] = pl[j];
        pvg[chid * 64 + 32 + j] = expf(cuml[31] - cuml[j]);
    }
    __syncthreads();

    {
        f16x8 fT[2];
#pragma unroll
        for (int ti = 0; ti < 2; ++ti) {
            int row = c + 16 * ti;
            fT[ti] = *(const f16x8*)((const char*)Tl + ((row * 128 + h * 16) ^ ((row & 3) << 4)));
        }
#pragma unroll
        for (int nj = 0; nj < 8; ++nj) {
            int dv = c + 16 * nj;
            f16x8 fv = *(const f16x8*)((const char*)VTl + ((dv * 64 + h * 16) ^ ((dv & 3) << 4)));
            f32x4 a0 = {}, a1 = {};
            a0 = __builtin_amdgcn_mfma_f32_16x16x32_f16(fT[0], fv, a0, 0, 0, 0);
            a1 = __builtin_amdgcn_mfma_f32_16x16x32_f16(fT[1], fv, a1, 0, 0, 0);
            f16x4 s0, s1;
#pragma unroll
            for (int r = 0; r < 4; ++r) { s0[r] = (f16)a0[r]; s1[r] = (f16)a1[r]; }
            *(f16x4*)(d0g + chid * 4096 + (long)dv * 32 + 4 * h) = s0;
            *(f16x4*)(d0g + chid * 4096 + (long)dv * 32 + 16 + 4 * h) = s1;
        }
    }
}

// ------------------------------------------------------------------
// sequential chunked scan: grid 512 = (b,hv,vs of 16 dv); 1 wave.
// ------------------------------------------------------------------
__global__ __launch_bounds__(64) void scan_kernel(const f16* __restrict__ qh,
                                                  const f16* __restrict__ kh,
                                                  const f16* __restrict__ khT,
                                                  const f16* __restrict__ Wg,
                                                  const f16* __restrict__ T2ng,
                                                  const f16* __restrict__ d0g,
                                                  const float* __restrict__ pvg,
                                                  f16* __restrict__ ob) {
    __shared__ f16 Sl[2][16 * 128];
    __shared__ f16 AKl[16 * 32];
    __shared__ f16 Dl[16 * 32];

    int pbid = blockIdx.x;
    int bid = (pbid & 7) * 64 + (pbid >> 3);
    int vs = bid & 7;
    int hv = (bid >> 3) & 31;
    int b = bid >> 8;
    int bh32 = b * 32 + hv;
    int bh = b * 16 + (hv >> 1);
    int l = threadIdx.x, h = l >> 4, c = l & 15;

    const f16* kb = kh + (long)bh * 2048 * 128;
    const f16* qb = qh + (long)bh * 2048 * 128;
    const f16* ktb = khT + (long)bh * 128 * 2048;

    f16x8 z = {};
#pragma unroll
    for (int it = 0; it < 4; ++it) *(f16x8*)((char*)Sl[0] + (l + it * 64) * 16) = z;
    __syncthreads();

    int cur = 0;
    for (int ch = 0; ch < 64; ++ch) {
        long chid = (long)bh32 * 64 + ch;
        f16x8 fk[2][4], fq[2][4], fkt[8], fT[2], fW[2];
#pragma unroll
        for (int ti = 0; ti < 2; ++ti) {
            long row = ch * 32 + c + 16 * ti;
#pragma unroll
            for (int kk = 0; kk < 4; ++kk) {
                fk[ti][kk] = *(const f16x8*)(kb + row * 128 + kk * 32 + h * 8);
                fq[ti][kk] = *(const f16x8*)(qb + row * 128 + kk * 32 + h * 8);
            }
            fT[ti] = *(const f16x8*)(T2ng + chid * 1024 + (c + 16 * ti) * 32 + h * 8);
            fW[ti] = *(const f16x8*)(Wg + chid * 1024 + (c + 16 * ti) * 32 + h * 8);
        }
#pragma unroll
        for (int ti = 0; ti < 8; ++ti)
            fkt[ti] = *(const f16x8*)(ktb + (long)(c + 16 * ti) * 2048 + ch * 32 + h * 8);
        f16x4 fd0[2];
#pragma unroll
        for (int ti = 0; ti < 2; ++ti)
            fd0[ti] = *(const f16x4*)(d0g + chid * 4096 +
                                      (long)(vs * 16 + c) * 32 + 16 * ti + 4 * h);
        f32x4 pva = *(const f32x4*)(pvg + chid * 64 + 4 * h);
        f32x4 pvb = *(const f32x4*)(pvg + chid * 64 + 16 + 4 * h);
        float pc = pvg[chid * 64 + 31];
        f32x4 kwa = *(const f32x4*)(pvg + chid * 64 + 32 + h * 8);
        f32x4 kwb = *(const f32x4*)(pvg + chid * 64 + 36 + h * 8);

        const int dv = c;
        f16x8 fS[4];
#pragma unroll
        for (int kk = 0; kk < 4; ++kk)
            fS[kk] = *(const f16x8*)((char*)Sl[cur] +
                                     (dv * 256 + ((kk * 64 + h * 16) ^ ((dv & 7) << 4))));
        f32x4 AK[2] = {}, AQ[2] = {};
#pragma unroll
        for (int ti = 0; ti < 2; ++ti)
#pragma unroll
            for (int kk = 0; kk < 4; ++kk) {
                AK[ti] = __builtin_amdgcn_mfma_f32_16x16x32_f16(fk[ti][kk], fS[kk], AK[ti], 0, 0, 0);
                AQ[ti] = __builtin_amdgcn_mfma_f32_16x16x32_f16(fq[ti][kk], fS[kk], AQ[ti], 0, 0, 0);
            }
#pragma unroll
        for (int ti = 0; ti < 2; ++ti) {
            f16x4 t;
#pragma unroll
            for (int r = 0; r < 4; ++r) t[r] = (f16)AK[ti][r];
            *(f16x4*)((char*)AKl + ((dv * 64 + 32 * ti + 8 * h) ^ ((dv & 3) << 4))) = t;
        }
        f32x4 Dv[2];
#pragma unroll
        for (int ti = 0; ti < 2; ++ti)
#pragma unroll
            for (int r = 0; r < 4; ++r) Dv[ti][r] = (float)fd0[ti][r];
        {
            f16x8 fak = *(const f16x8*)((char*)AKl + ((dv * 64 + h * 16) ^ ((dv & 3) << 4)));
#pragma unroll
            for (int ti = 0; ti < 2; ++ti)
                Dv[ti] = __builtin_amdgcn_mfma_f32_16x16x32_f16(fT[ti], fak, Dv[ti], 0, 0, 0);
        }
#pragma unroll
        for (int ti = 0; ti < 2; ++ti) {
            f16x4 t;
#pragma unroll
            for (int r = 0; r < 4; ++r) t[r] = (f16)Dv[ti][r];
            *(f16x4*)((char*)Dl + ((dv * 64 + 32 * ti + 8 * h) ^ ((dv & 3) << 4))) = t;
        }
        f16x8 fdl = *(const f16x8*)((char*)Dl + ((dv * 64 + h * 16) ^ ((dv & 3) << 4)));
        f32x4 Ov[2];
#pragma unroll
        for (int ti = 0; ti < 2; ++ti)
#pragma unroll
            for (int r = 0; r < 4; ++r)
                Ov[ti][r] = AQ[ti][r] * (ti ? pvb[r] : pva[r]);
#pragma unroll
        for (int ti = 0; ti < 2; ++ti)
            Ov[ti] = __builtin_amdgcn_mfma_f32_16x16x32_f16(fW[ti], fdl, Ov[ti], 0, 0, 0);
#pragma unroll
        for (int ti = 0; ti < 2; ++ti)
#pragma unroll
            for (int r = 0; r < 4; ++r) {
                long tok = (long)b * 2048 + ch * 32 + 16 * ti + 4 * h + r;
                ob[tok * 4096 + hv * 128 + vs * 16 + c] = (f16)Ov[ti][r];
            }
#pragma unroll
        for (int ti = 0; ti < 8; ++ti) {
            f16x8 fa;
#pragma unroll
            for (int e = 0; e < 8; ++e)
                fa[e] = (f16)((float)fkt[ti][e] * (e < 4 ? kwa[e] : kwb[e - 4]));
            int sbyte = (dv * 256 + (32 * ti + 8 * h)) ^ ((dv & 7) << 4);
            f16x4 sold = *(const f16x4*)((char*)Sl[cur] + sbyte);
            f32x4 acc;
#pragma unroll
            for (int r = 0; r < 4; ++r) acc[r] = pc * (float)sold[r];
            acc = __builtin_amdgcn_mfma_f32_16x16x32_f16(fa, fdl, acc, 0, 0, 0);
            f16x4 snew;
#pragma unroll
            for (int r = 0; r < 4; ++r) snew[r] = (f16)acc[r];
            *(f16x4*)((char*)Sl[cur ^ 1] + sbyte) = snew;
        }
        cur ^= 1;
        __syncthreads();
    }
}

// ------------------------------------------------------------------
// y = rmsnorm(o * silu(z)) * norm_w  -> f16  (vectorized f16x8)
// ------------------------------------------------------------------
__global__ __launch_bounds__(256) void gate_kernel(const f16* __restrict__ o,
                                                   const f16* __restrict__ qkvz,
                                                   const float* __restrict__ norm_w,
                                                   f16* __restrict__ y) {
    int token = blockIdx.x;  // b*2048 + s
    int tid = threadIdx.x;
    int hv = tid >> 3, part = tid & 7;
    int dv0 = part * 16;
    const f16* orow = o + ((long)token * 32 + hv) * 128 + dv0;
    long zcol = (long)(hv >> 1) * 768 + 512 + (hv & 1) * 128 + dv0;
    const f16* zrow = qkvz + (long)token * 12288 + zcol;
    f16x8 ov0 = *(const f16x8*)orow, ov1 = *(const f16x8*)(orow + 8);
    f16x8 zv0 = *(const f16x8*)zrow, zv1 = *(const f16x8*)(zrow + 8);
    float yv[16];
    float ss = 0.f;
#pragma unroll
    for (int i = 0; i < 16; ++i) {
        float ovf = (float)(i < 8 ? ov0[i] : ov1[i - 8]);
        float zvf = (float)(i < 8 ? zv0[i] : zv1[i - 8]);
        float gt = zvf / (1.f + expf(-zvf));
        float v = ovf * gt;
        yv[i] = v;
        ss += v * v;
    }
    ss += __shfl_xor(ss, 1); ss += __shfl_xor(ss, 2); ss += __shfl_xor(ss, 4);
    float scale = rsqrtf(ss * (1.f / 128.f) + 1e-6f);
    f16* yrow = y + (long)token * 4096 + hv * 128 + dv0;
    f16x8 y0, y1;
#pragma unroll
    for (int i = 0; i < 8; ++i) {
        y0[i] = (f16)(yv[i] * scale * norm_w[dv0 + i]);
        y1[i] = (f16)(yv[8 + i] * scale * norm_w[dv0 + 8 + i]);
    }
    *(f16x8*)yrow = y0;
    *(f16x8*)(yrow + 8) = y1;
}

// ------------------------------------------------------------------
// Workspace (242 MB, time-aliased) — r11 lifetime-audited layout.
// ------------------------------------------------------------------
extern "C" void kernel_launch(void* const* d_in, const int* in_sizes, int n_in,
                              void* d_out, int out_size, void* d_ws, size_t ws_size,
                              hipStream_t stream) {
    const float* x       = (const float*)d_in[0];
    const float* w_qkvz  = (const float*)d_in[1];
    const float* w_ba    = (const float*)d_in[2];
    const float* conv_w  = (const float*)d_in[3];
    const float* conv_b  = (const float*)d_in[4];
    const float* a_log   = (const float*)d_in[5];
    const float* dt_bias = (const float*)d_in[6];
    const float* norm_w  = (const float*)d_in[7];
    const float* w_o     = (const float*)d_in[8];
    float* out = (float*)d_out;

    char* ws = (char*)d_ws;
    const size_t MB = 1024 * 1024;
    f16*   qkvz16 = (f16*)ws;
    f16*   x16    = (f16*)(ws + 96 * MB);
    f16*   WT     = (f16*)(ws + 112 * MB);
    float* bab    = (float*)(ws + 96 * MB);   // over dead x16; consumed before d0g
    f16*   d0g    = (f16*)(ws + 96 * MB);
    f16*   Wg     = (f16*)(ws + 128 * MB);
    f16*   T2ng   = (f16*)(ws + 136 * MB);
    f16*   khT    = (f16*)(ws + 144 * MB);
    f16*   WTo    = (f16*)(ws + 160 * MB);
    f16*   qh     = (f16*)(ws + 176 * MB);
    f16*   kh     = (f16*)(ws + 192 * MB);
    f16*   vh     = (f16*)(ws + 208 * MB);
    f16*   ob     = (f16*)(ws + 208 * MB);
    f16*   y16    = (f16*)(ws + 176 * MB);
    float* gbuf   = (float*)(ws + 240 * MB);
    float* btb    = (float*)(ws + 240 * MB + 512 * 1024);
    float* pvg    = (float*)(ws + 241 * MB);

    // prep
    cvt16_kernel<<<8192, 256, 0, stream>>>(x, x16, 4096 * 2048 / 4);
    transpose16_kernel<<<dim3(12288 / 64, 2048 / 64), 256, 0, stream>>>(w_qkvz, WT, 2048, 12288);
    transpose16_kernel<<<dim3(2048 / 64, 4096 / 64), 256, 0, stream>>>(w_o, WTo, 4096, 2048);

    // qkvz = x @ w_qkvz  (256x256 deep-pipelined, 8 waves, setprio)
    gemm256_kernel<4, 1><<<dim3(12288 / 256, 4096 / 256), 512, 0, stream>>>(x16, WT, qkvz16, 4096, 12288, 2048);
    // ba = x @ w_ba
    ba_gemm_kernel<<<256, 256, 0, stream>>>(x, w_ba, bab);

    // conv + silu + l2norm
    conv_kernel<<<dim3(64, 64, 2), 256, 0, stream>>>(qkvz16, conv_w, conv_b, qh, kh, vh);
    // g, beta
    gb_kernel<<<512, 256, 0, stream>>>(bab, a_log, dt_bias, gbuf, btb);
    // k transpose
    kT_kernel<<<1024, 256, 0, stream>>>(kh, khT);
    // per-chunk UT-transform precompute
    chunk_pre_kernel<<<4096, 64, 0, stream>>>(qh, kh, vh, gbuf, btb, Wg, T2ng, d0g, pvg);
    // sequential chunked MFMA scan
    scan_kernel<<<512, 64, 0, stream>>>(qh, kh, khT, Wg, T2ng, d0g, pvg, ob);

    // gating + rmsnorm -> y16
    gate_kernel<<<4096, 256, 0, stream>>>(ob, qkvz16, norm_w, y16);

    // out = y @ w_o  (256x128 deep-pipelined, grid 256 = 1/CU, f32 out)
    gemm256_kernel<2, 0><<<dim3(2048 / 128, 4096 / 256), 512, 0, stream>>>(y16, WTo, out, 4096, 2048, 4096);
}

// Round 15
// 820.858 us; speedup vs baseline: 1.5154x; 1.1029x over previous
//
#include <hip/hip_runtime.h>

typedef _Float16 f16;
typedef _Float16 f16x2 __attribute__((ext_vector_type(2)));
typedef _Float16 f16x4 __attribute__((ext_vector_type(4)));
typedef _Float16 f16x8 __attribute__((ext_vector_type(8)));
typedef float f32x4 __attribute__((ext_vector_type(4)));

#define QSCALE 0.08838834764831845f  // DK^-0.5

#define RAW_BARRIER() do { \
    asm volatile("s_waitcnt lgkmcnt(0)" ::: "memory"); \
    __builtin_amdgcn_s_barrier(); \
    __builtin_amdgcn_sched_barrier(0); \
} while (0)

// ------------------------------------------------------------------
// convert fp32 -> f16 (vectorized x4)
// ------------------------------------------------------------------
__global__ __launch_bounds__(256) void cvt16_kernel(const float* __restrict__ in,
                                                    f16* __restrict__ out, int n4) {
    int i = blockIdx.x * 256 + threadIdx.x;
    if (i >= n4) return;
    f32x4 v = ((const f32x4*)in)[i];
    f16x4 h;
    h[0] = (f16)v[0]; h[1] = (f16)v[1]; h[2] = (f16)v[2]; h[3] = (f16)v[3];
    ((f16x4*)out)[i] = h;
}

// ------------------------------------------------------------------
// transpose fp32 [R][C] -> f16 [C][R]
// ------------------------------------------------------------------
__global__ __launch_bounds__(256) void transpose16_kernel(const float* __restrict__ in,
                                                          f16* __restrict__ out, int R, int C) {
    __shared__ f16 tile[64][66];
    int c0 = blockIdx.x * 64, r0 = blockIdx.y * 64;
    int tid = threadIdx.x;
#pragma unroll
    for (int i = 0; i < 16; ++i) {
        int idx = i * 256 + tid;
        int r = idx >> 6, c = idx & 63;
        tile[r][c] = (f16)in[(long)(r0 + r) * C + (c0 + c)];
    }
    __syncthreads();
#pragma unroll
    for (int i = 0; i < 16; ++i) {
        int idx = i * 256 + tid;
        int orow = idx >> 6, oc = idx & 63;
        out[(long)(c0 + orow) * R + (r0 + oc)] = tile[oc][orow];
    }
}

// ------------------------------------------------------------------
// 256xBN deep-pipelined f16 MFMA GEMM. BN = 64*NJ.
// ------------------------------------------------------------------
template <int NJ, int F16OUT>
__global__ __launch_bounds__(512, 1) void gemm256_kernel(const f16* __restrict__ A,
                                                         const f16* __restrict__ Bt,
                                                         void* __restrict__ Cout,
                                                         int M, int N, int Kd) {
    constexpr int BN = 64 * NJ;
    constexpr int BNW = 16 * NJ;
    __shared__ f16 sA[2][256 * 64];
    __shared__ f16 sB[2][BN * 64];
    const int tid = threadIdx.x;
    const int lane = tid & 63, wv = tid >> 6;
    const int wm = wv >> 2, wn = wv & 3;
    const int m0 = blockIdx.y * 256, n0 = blockIdx.x * BN;
    const int lrow = lane & 15, lk = lane >> 4;
    const int nK = Kd >> 6;

    f32x4 acc[8][NJ] = {};
    f32x4 ra[4], rb[NJ];

    auto issue = [&](int k0) {
#pragma unroll
        for (int j = 0; j < 4; ++j) {
            int P = (tid + j * 512) * 16;
            int row = P >> 7;
            int koff = (P & 127) >> 1;
            ra[j] = *(const f32x4*)(A + (long)(m0 + row) * Kd + k0 + koff);
        }
#pragma unroll
        for (int j = 0; j < NJ; ++j) {
            int P = (tid + j * 512) * 16;
            int row = P >> 7;
            int koff = (P & 127) >> 1;
            rb[j] = *(const f32x4*)(Bt + (long)(n0 + row) * Kd + k0 + koff);
        }
    };
    auto commit = [&](int buf) {
#pragma unroll
        for (int j = 0; j < 4; ++j) {
            int P = (tid + j * 512) * 16;
            int row = P >> 7;
            int sw = P ^ ((row & 7) << 4);
            *(f32x4*)((char*)&sA[buf][0] + sw) = ra[j];
        }
#pragma unroll
        for (int j = 0; j < NJ; ++j) {
            int P = (tid + j * 512) * 16;
            int row = P >> 7;
            int sw = P ^ ((row & 7) << 4);
            *(f32x4*)((char*)&sB[buf][0] + sw) = rb[j];
        }
    };

    issue(0);
    commit(0);
    if (nK > 1) issue(64);
    RAW_BARRIER();

    int cur = 0;
    for (int t = 0; t < nK; ++t) {
        if (t + 1 < nK) commit(cur ^ 1);
        if (t + 2 < nK) issue((t + 2) * 64);
        const char* bA = (const char*)&sA[cur][0];
        const char* bB = (const char*)&sB[cur][0];
        __builtin_amdgcn_s_setprio(1);
#pragma unroll
        for (int kk = 0; kk < 2; ++kk) {
            f16x8 bf[NJ];
#pragma unroll
            for (int j = 0; j < NJ; ++j) {
                int brow = wn * BNW + j * 16 + lrow;
                int bbyte = brow * 128 + kk * 64 + lk * 16;
                bf[j] = *(const f16x8*)(bB + (bbyte ^ ((brow & 7) << 4)));
            }
#pragma unroll
            for (int i = 0; i < 8; ++i) {
                int arow = wm * 128 + i * 16 + lrow;
                int abyte = arow * 128 + kk * 64 + lk * 16;
                f16x8 af = *(const f16x8*)(bA + (abyte ^ ((arow & 7) << 4)));
#pragma unroll
                for (int j = 0; j < NJ; ++j)
                    acc[i][j] = __builtin_amdgcn_mfma_f32_16x16x32_f16(af, bf[j], acc[i][j], 0, 0, 0);
            }
        }
        __builtin_amdgcn_s_setprio(0);
        RAW_BARRIER();
        cur ^= 1;
    }

#pragma unroll
    for (int i = 0; i < 8; ++i) {
        int gm_base = m0 + wm * 128 + i * 16 + lk * 4;
#pragma unroll
        for (int j = 0; j < NJ; ++j) {
            int gn = n0 + wn * BNW + j * 16 + lrow;
#pragma unroll
            for (int r = 0; r < 4; ++r) {
                long idx = (long)(gm_base + r) * N + gn;
                if (F16OUT) ((f16*)Cout)[idx] = (f16)acc[i][j][r];
                else        ((float*)Cout)[idx] = acc[i][j][r];
            }
        }
    }
}

// ------------------------------------------------------------------
// ba = x @ w_ba, FUSED epilogue: g/beta directly (kills gb kernel).
// thread (o, tok): o = hk*4 + {gg | 2+gg} -> hv = (o>>2)*2 + (o&1)
// ------------------------------------------------------------------
__global__ __launch_bounds__(256) void ba_gemm_kernel(const float* __restrict__ x,
                                                      const float* __restrict__ w,
                                                      const float* __restrict__ a_log,
                                                      const float* __restrict__ dt_bias,
                                                      float* __restrict__ gout,
                                                      float* __restrict__ bt) {
    __shared__ float xs[16][256];
    int tid = threadIdx.x;
    int t0 = blockIdx.x * 16;
    int o = tid & 63, tg = tid >> 6;
    float acc[4] = {0.f, 0.f, 0.f, 0.f};
    for (int kc = 0; kc < 2048; kc += 256) {
        __syncthreads();
#pragma unroll
        for (int i = 0; i < 16; ++i) {
            int idx = i * 256 + tid;
            int tok = idx >> 8, k = idx & 255;
            xs[tok][k] = x[(long)(t0 + tok) * 2048 + kc + k];
        }
        __syncthreads();
        for (int k = 0; k < 256; ++k) {
            float wv = w[(long)(kc + k) * 64 + o];
#pragma unroll
            for (int j = 0; j < 4; ++j) acc[j] += xs[tg * 4 + j][k] * wv;
        }
    }
    int hv = ((o >> 2) << 1) | (o & 1);
    bool isB = (o & 2) == 0;
    float al = expf(a_log[hv]);
    float db = dt_bias[hv];
#pragma unroll
    for (int j = 0; j < 4; ++j) {
        int tok = t0 + tg * 4 + j;
        int b = tok >> 11, s = tok & 2047;
        long oidx = ((long)b * 32 + hv) * 2048 + s;
        if (isB) {
            bt[oidx] = 1.f / (1.f + expf(-acc[j]));
        } else {
            float xx = acc[j] + db;
            float sp = (xx > 20.f) ? xx : log1pf(expf(xx));
            gout[oidx] = -al * sp;
        }
    }
}

// ------------------------------------------------------------------
// depthwise causal conv(K=4) + bias + SiLU (+ L2norm for q/k heads)
// ------------------------------------------------------------------
__global__ __launch_bounds__(256) void conv_kernel(const f16* __restrict__ qkvz,
                                                   const float* __restrict__ cw,
                                                   const float* __restrict__ cb,
                                                   f16* __restrict__ qh,
                                                   f16* __restrict__ kh,
                                                   f16* __restrict__ vh) {
    __shared__ float Lin[35 * 128];
    __shared__ float Lout[32 * 128];
    __shared__ float Lsc[32];
    int g = blockIdx.x;
    int s0 = blockIdx.y * 32;
    int b = blockIdx.z;
    int tid = threadIdx.x;
    int colbase, chbase;
    f16* outp;
    bool donorm;
    float nmul;
    if (g < 16) {
        colbase = g * 768; chbase = g * 128;
        outp = qh + (((long)b * 16 + g) * 2048 + s0) * 128;
        donorm = true; nmul = QSCALE;
    } else if (g < 32) {
        int hk = g - 16;
        colbase = hk * 768 + 128; chbase = 2048 + hk * 128;
        outp = kh + (((long)b * 16 + hk) * 2048 + s0) * 128;
        donorm = true; nmul = 1.f;
    } else {
        int hv = g - 32;
        colbase = (hv >> 1) * 768 + 256 + (hv & 1) * 128; chbase = 4096 + hv * 128;
        outp = vh + (((long)b * 32 + hv) * 2048 + s0) * 128;
        donorm = false; nmul = 1.f;
    }
    for (int ci = tid; ci < 35 * 16; ci += 256) {
        int sr = ci >> 4, cc = (ci & 15) * 8;
        int s = s0 + sr - 3;
        f32x4 lo = {}, hi = {};
        if (s >= 0) {
            f16x8 v = *(const f16x8*)(qkvz + ((long)b * 2048 + s) * 12288 + colbase + cc);
#pragma unroll
            for (int e = 0; e < 4; ++e) { lo[e] = (float)v[e]; hi[e] = (float)v[4 + e]; }
        }
        *(f32x4*)&Lin[sr * 128 + cc] = lo;
        *(f32x4*)&Lin[sr * 128 + cc + 4] = hi;
    }
    __syncthreads();
    int c = tid & 127, sg = tid >> 7;
    float w0 = cw[(chbase + c) * 4 + 0];
    float w1 = cw[(chbase + c) * 4 + 1];
    float w2 = cw[(chbase + c) * 4 + 2];
    float w3 = cw[(chbase + c) * 4 + 3];
    float bias = cb[chbase + c];
#pragma unroll
    for (int j = 0; j < 16; ++j) {
        int sl = sg * 16 + j;
        float v = w0 * Lin[sl * 128 + c] + w1 * Lin[(sl + 1) * 128 + c] +
                  w2 * Lin[(sl + 2) * 128 + c] + w3 * Lin[(sl + 3) * 128 + c] + bias;
        v = v / (1.f + expf(-v));  // SiLU
        Lout[sl * 128 + c] = v;
    }
    __syncthreads();
    if (donorm) {
        int token = tid >> 3, part = tid & 7;
        float ss = 0.f;
#pragma unroll
        for (int i = 0; i < 16; ++i) {
            float v = Lout[token * 128 + part * 16 + i];
            ss += v * v;
        }
        ss += __shfl_xor(ss, 1); ss += __shfl_xor(ss, 2); ss += __shfl_xor(ss, 4);
        if (part == 0) Lsc[token] = rsqrtf(ss + 1e-6f) * nmul;
        __syncthreads();
#pragma unroll
        for (int j = 0; j < 16; ++j) {
            int sl = sg * 16 + j;
            outp[(long)sl * 128 + c] = (f16)(Lout[sl * 128 + c] * Lsc[sl]);
        }
    } else {
#pragma unroll
        for (int j = 0; j < 16; ++j) {
            int sl = sg * 16 + j;
            outp[(long)sl * 128 + c] = (f16)Lout[sl * 128 + c];
        }
    }
}

// ------------------------------------------------------------------
// kh [bh][2048][128] -> khT [bh][128][2048]  (f16 transpose)
// ------------------------------------------------------------------
__global__ __launch_bounds__(256) void kT_kernel(const f16* __restrict__ kh,
                                                 f16* __restrict__ khT) {
    __shared__ f16 t[64][136];
    int bh = blockIdx.x >> 5;
    int s0 = (blockIdx.x & 31) * 64;
    int tid = threadIdx.x;
#pragma unroll
    for (int it = 0; it < 4; ++it) {
        int P = (tid + it * 256) * 8;
        int r = P >> 7, col = P & 127;
        *(f16x8*)&t[r][col] = *(const f16x8*)(kh + ((long)bh * 2048 + s0 + r) * 128 + col);
    }
    __syncthreads();
#pragma unroll
    for (int it = 0; it < 4; ++it) {
        int Q = (tid + it * 256) * 8;
        int dk = Q >> 6, sc = Q & 63;
        f16x8 v;
#pragma unroll
        for (int e = 0; e < 8; ++e) v[e] = t[sc + e][dk];
        *(f16x8*)(khT + ((long)bh * 128 + dk) * 2048 + s0 + sc) = v;
    }
}

// ------------------------------------------------------------------
// chunk_pre: per (b,hv,chunk of 32) — one wave.
// K/Q fragments loaded DIRECTLY from global (no LDS staging):
// LDS 40.5 -> 24.5 KB, occupancy ~4 -> ~6.5 waves/CU.
// ------------------------------------------------------------------
__global__ __launch_bounds__(64) void chunk_pre_kernel(const f16* __restrict__ qh,
                                                       const f16* __restrict__ kh,
                                                       const f16* __restrict__ vh,
                                                       const float* __restrict__ gb,
                                                       const float* __restrict__ bt,
                                                       f16* __restrict__ Wg,
                                                       f16* __restrict__ T2ng,
                                                       f16* __restrict__ d0g,
                                                       float* __restrict__ pvg) {
    __shared__ f16 VTl[128 * 32];    // beta*V as [dv][step], swz ^((dv&3)<<4)
    __shared__ float KKl[32 * 32];
    __shared__ float RL[32 * 32];
    __shared__ float Tf[32 * 33];
    __shared__ f16 Tl[32 * 64];
    __shared__ float cuml[32], bl[32], pl[32];

    int bid = blockIdx.x;
    int chunk = bid & 63;
    int hv = (bid >> 6) & 31;
    int b = bid >> 11;
    int bh = b * 16 + (hv >> 1);
    int l = threadIdx.x;
    int h = l >> 4, c = l & 15;
    long chid = bid;

    const f16* kbase = kh + ((long)bh * 2048 + chunk * 32) * 128;
    const f16* qbase = qh + ((long)bh * 2048 + chunk * 32) * 128;
    const f16* vbase = vh + (((long)b * 32 + hv) * 2048 + chunk * 32) * 128;
    const float* gp = gb + ((long)b * 32 + hv) * 2048 + chunk * 32;
    const float* bp = bt + ((long)b * 32 + hv) * 2048 + chunk * 32;

    // direct-from-global MFMA fragments (same values the old staged path read)
    f16x8 fk[2][4], fq[2][4];
#pragma unroll
    for (int ti = 0; ti < 2; ++ti)
#pragma unroll
        for (int kk = 0; kk < 4; ++kk) {
            fk[ti][kk] = *(const f16x8*)(kbase + (c + 16 * ti) * 128 + kk * 32 + h * 8);
            fq[ti][kk] = *(const f16x8*)(qbase + (c + 16 * ti) * 128 + kk * 32 + h * 8);
        }

    // scalars: inclusive scan of g over lanes 0..31
    float gv = (l < 32) ? gp[l] : 0.f;
#pragma unroll
    for (int d = 1; d < 32; d <<= 1) {
        float t2 = __shfl_up(gv, d);
        if (l >= d) gv += t2;
    }
    if (l < 32) { cuml[l] = gv; bl[l] = bp[l]; pl[l] = expf(gv); }
    __syncthreads();

    // stage beta*V transposed, build RL
#pragma unroll
    for (int it = 0; it < 8; ++it) {
        int idx = (l + it * 64) * 8;
        int row = idx >> 7, col = idx & 127;
        f16x8 v = *(const f16x8*)(vbase + (long)row * 128 + col);
        float be = bl[row];
#pragma unroll
        for (int e = 0; e < 8; ++e) {
            int dv = col + e;
            int byte = (dv * 64 + row * 2) ^ ((dv & 3) << 4);
            *(f16*)((char*)VTl + byte) = (f16)((float)v[e] * be);
        }
    }
#pragma unroll
    for (int it = 0; it < 16; ++it) {
        int e = l * 16 + it;
        int i = e >> 5, j = e & 31;
        RL[e] = (j <= i) ? expf(cuml[i] - cuml[j]) : 0.f;
    }
    __syncthreads();

    // KK = K @ K^T
    {
        f32x4 acc[2][2] = {};
#pragma unroll
        for (int kk = 0; kk < 4; ++kk) {
            acc[0][0] = __builtin_amdgcn_mfma_f32_16x16x32_f16(fk[0][kk], fk[0][kk], acc[0][0], 0, 0, 0);
            acc[0][1] = __builtin_amdgcn_mfma_f32_16x16x32_f16(fk[0][kk], fk[1][kk], acc[0][1], 0, 0, 0);
            acc[1][0] = __builtin_amdgcn_mfma_f32_16x16x32_f16(fk[1][kk], fk[0][kk], acc[1][0], 0, 0, 0);
            acc[1][1] = __builtin_amdgcn_mfma_f32_16x16x32_f16(fk[1][kk], fk[1][kk], acc[1][1], 0, 0, 0);
        }
#pragma unroll
        for (int ti = 0; ti < 2; ++ti)
#pragma unroll
            for (int tj = 0; tj < 2; ++tj)
#pragma unroll
                for (int r = 0; r < 4; ++r)
                    KKl[(h * 4 + r + 16 * ti) * 32 + c + 16 * tj] = acc[ti][tj][r];
    }
    // QK = Q @ K^T -> W
    {
        f32x4 acc[2][2] = {};
#pragma unroll
        for (int kk = 0; kk < 4; ++kk) {
            acc[0][0] = __builtin_amdgcn_mfma_f32_16x16x32_f16(fq[0][kk], fk[0][kk], acc[0][0], 0, 0, 0);
            acc[0][1] = __builtin_amdgcn_mfma_f32_16x16x32_f16(fq[0][kk], fk[1][kk], acc[0][1], 0, 0, 0);
            acc[1][0] = __builtin_amdgcn_mfma_f32_16x16x32_f16(fq[1][kk], fk[0][kk], acc[1][0], 0, 0, 0);
            acc[1][1] = __builtin_amdgcn_mfma_f32_16x16x32_f16(fq[1][kk], fk[1][kk], acc[1][1], 0, 0, 0);
        }
        __syncthreads();  // KKl writes visible before T-inv
#pragma unroll
        for (int ti = 0; ti < 2; ++ti)
#pragma unroll
            for (int tj = 0; tj < 2; ++tj)
#pragma unroll
                for (int r = 0; r < 4; ++r) {
                    int i = h * 4 + r + 16 * ti, j = c + 16 * tj;
                    Wg[chid * 1024 + i * 32 + j] = (f16)(acc[ti][tj][r] * RL[i * 32 + j]);
                }
    }

    // T inversion (forward substitution), lane j owns column j
    if (l < 32) {
        int j = l;
        for (int i = 0; i < 32; ++i) {
            float s = (i == j) ? 1.f : 0.f;
            float bi = bl[i];
            for (int ll = j; ll < i; ++ll)
                s -= bi * KKl[i * 32 + ll] * RL[i * 32 + ll] * Tf[ll * 33 + j];
            Tf[i * 33 + j] = s;
        }
        float bpj = bl[j] * pl[j];
        for (int i = 0; i < 32; ++i) {
            float tv = (i >= j) ? Tf[i * 33 + j] : 0.f;
            int byte = (i * 128 + j * 2) ^ ((i & 3) << 4);
            *(f16*)((char*)Tl + byte) = (f16)tv;
            T2ng[chid * 1024 + i * 32 + j] = (f16)(-tv * bpj);
        }
        pvg[chid * 64 + j] = pl[j];
        pvg[chid * 64 + 32 + j] = expf(cuml[31] - cuml[j]);
    }
    __syncthreads();

    // D0 = T @ (beta*V): M=32 N=128 K=32
    {
        f16x8 fT[2];
#pragma unroll
        for (int ti = 0; ti < 2; ++ti) {
            int row = c + 16 * ti;
            fT[ti] = *(const f16x8*)((const char*)Tl + ((row * 128 + h * 16) ^ ((row & 3) << 4)));
        }
#pragma unroll
        for (int nj = 0; nj < 8; ++nj) {
            int dv = c + 16 * nj;
            f16x8 fv = *(const f16x8*)((const char*)VTl + ((dv * 64 + h * 16) ^ ((dv & 3) << 4)));
            f32x4 a0 = {}, a1 = {};
            a0 = __builtin_amdgcn_mfma_f32_16x16x32_f16(fT[0], fv, a0, 0, 0, 0);
            a1 = __builtin_amdgcn_mfma_f32_16x16x32_f16(fT[1], fv, a1, 0, 0, 0);
            f16x4 s0, s1;
#pragma unroll
            for (int r = 0; r < 4; ++r) { s0[r] = (f16)a0[r]; s1[r] = (f16)a1[r]; }
            *(f16x4*)(d0g + chid * 4096 + (long)dv * 32 + 4 * h) = s0;
            *(f16x4*)(d0g + chid * 4096 + (long)dv * 32 + 16 + 4 * h) = s1;
        }
    }
}

// ------------------------------------------------------------------
// sequential chunked scan: grid 512 = (b,hv,vs of 16 dv); 1 wave.
// ------------------------------------------------------------------
__global__ __launch_bounds__(64) void scan_kernel(const f16* __restrict__ qh,
                                                  const f16* __restrict__ kh,
                                                  const f16* __restrict__ khT,
                                                  const f16* __restrict__ Wg,
                                                  const f16* __restrict__ T2ng,
                                                  const f16* __restrict__ d0g,
                                                  const float* __restrict__ pvg,
                                                  f16* __restrict__ ob) {
    __shared__ f16 Sl[2][16 * 128];
    __shared__ f16 AKl[16 * 32];
    __shared__ f16 Dl[16 * 32];

    int pbid = blockIdx.x;
    int bid = (pbid & 7) * 64 + (pbid >> 3);
    int vs = bid & 7;
    int hv = (bid >> 3) & 31;
    int b = bid >> 8;
    int bh32 = b * 32 + hv;
    int bh = b * 16 + (hv >> 1);
    int l = threadIdx.x, h = l >> 4, c = l & 15;

    const f16* kb = kh + (long)bh * 2048 * 128;
    const f16* qb = qh + (long)bh * 2048 * 128;
    const f16* ktb = khT + (long)bh * 128 * 2048;

    f16x8 z = {};
#pragma unroll
    for (int it = 0; it < 4; ++it) *(f16x8*)((char*)Sl[0] + (l + it * 64) * 16) = z;
    __syncthreads();

    int cur = 0;
    for (int ch = 0; ch < 64; ++ch) {
        long chid = (long)bh32 * 64 + ch;
        f16x8 fk[2][4], fq[2][4], fkt[8], fT[2], fW[2];
#pragma unroll
        for (int ti = 0; ti < 2; ++ti) {
            long row = ch * 32 + c + 16 * ti;
#pragma unroll
            for (int kk = 0; kk < 4; ++kk) {
                fk[ti][kk] = *(const f16x8*)(kb + row * 128 + kk * 32 + h * 8);
                fq[ti][kk] = *(const f16x8*)(qb + row * 128 + kk * 32 + h * 8);
            }
            fT[ti] = *(const f16x8*)(T2ng + chid * 1024 + (c + 16 * ti) * 32 + h * 8);
            fW[ti] = *(const f16x8*)(Wg + chid * 1024 + (c + 16 * ti) * 32 + h * 8);
        }
#pragma unroll
        for (int ti = 0; ti < 8; ++ti)
            fkt[ti] = *(const f16x8*)(ktb + (long)(c + 16 * ti) * 2048 + ch * 32 + h * 8);
        f16x4 fd0[2];
#pragma unroll
        for (int ti = 0; ti < 2; ++ti)
            fd0[ti] = *(const f16x4*)(d0g + chid * 4096 +
                                      (long)(vs * 16 + c) * 32 + 16 * ti + 4 * h);
        f32x4 pva = *(const f32x4*)(pvg + chid * 64 + 4 * h);
        f32x4 pvb = *(const f32x4*)(pvg + chid * 64 + 16 + 4 * h);
        float pc = pvg[chid * 64 + 31];
        f32x4 kwa = *(const f32x4*)(pvg + chid * 64 + 32 + h * 8);
        f32x4 kwb = *(const f32x4*)(pvg + chid * 64 + 36 + h * 8);

        const int dv = c;
        f16x8 fS[4];
#pragma unroll
        for (int kk = 0; kk < 4; ++kk)
            fS[kk] = *(const f16x8*)((char*)Sl[cur] +
                                     (dv * 256 + ((kk * 64 + h * 16) ^ ((dv & 7) << 4))));
        f32x4 AK[2] = {}, AQ[2] = {};
#pragma unroll
        for (int ti = 0; ti < 2; ++ti)
#pragma unroll
            for (int kk = 0; kk < 4; ++kk) {
                AK[ti] = __builtin_amdgcn_mfma_f32_16x16x32_f16(fk[ti][kk], fS[kk], AK[ti], 0, 0, 0);
                AQ[ti] = __builtin_amdgcn_mfma_f32_16x16x32_f16(fq[ti][kk], fS[kk], AQ[ti], 0, 0, 0);
            }
#pragma unroll
        for (int ti = 0; ti < 2; ++ti) {
            f16x4 t;
#pragma unroll
            for (int r = 0; r < 4; ++r) t[r] = (f16)AK[ti][r];
            *(f16x4*)((char*)AKl + ((dv * 64 + 32 * ti + 8 * h) ^ ((dv & 3) << 4))) = t;
        }
        f32x4 Dv[2];
#pragma unroll
        for (int ti = 0; ti < 2; ++ti)
#pragma unroll
            for (int r = 0; r < 4; ++r) Dv[ti][r] = (float)fd0[ti][r];
        {
            f16x8 fak = *(const f16x8*)((char*)AKl + ((dv * 64 + h * 16) ^ ((dv & 3) << 4)));
#pragma unroll
            for (int ti = 0; ti < 2; ++ti)
                Dv[ti] = __builtin_amdgcn_mfma_f32_16x16x32_f16(fT[ti], fak, Dv[ti], 0, 0, 0);
        }
#pragma unroll
        for (int ti = 0; ti < 2; ++ti) {
            f16x4 t;
#pragma unroll
            for (int r = 0; r < 4; ++r) t[r] = (f16)Dv[ti][r];
            *(f16x4*)((char*)Dl + ((dv * 64 + 32 * ti + 8 * h) ^ ((dv & 3) << 4))) = t;
        }
        f16x8 fdl = *(const f16x8*)((char*)Dl + ((dv * 64 + h * 16) ^ ((dv & 3) << 4)));
        f32x4 Ov[2];
#pragma unroll
        for (int ti = 0; ti < 2; ++ti)
#pragma unroll
            for (int r = 0; r < 4; ++r)
                Ov[ti][r] = AQ[ti][r] * (ti ? pvb[r] : pva[r]);
#pragma unroll
        for (int ti = 0; ti < 2; ++ti)
            Ov[ti] = __builtin_amdgcn_mfma_f32_16x16x32_f16(fW[ti], fdl, Ov[ti], 0, 0, 0);
#pragma unroll
        for (int ti = 0; ti < 2; ++ti)
#pragma unroll
            for (int r = 0; r < 4; ++r) {
                long tok = (long)b * 2048 + ch * 32 + 16 * ti + 4 * h + r;
                ob[tok * 4096 + hv * 128 + vs * 16 + c] = (f16)Ov[ti][r];
            }
#pragma unroll
        for (int ti = 0; ti < 8; ++ti) {
            f16x8 fa;
#pragma unroll
            for (int e = 0; e < 8; ++e)
                fa[e] = (f16)((float)fkt[ti][e] * (e < 4 ? kwa[e] : kwb[e - 4]));
            int sbyte = (dv * 256 + (32 * ti + 8 * h)) ^ ((dv & 7) << 4);
            f16x4 sold = *(const f16x4*)((char*)Sl[cur] + sbyte);
            f32x4 acc;
#pragma unroll
            for (int r = 0; r < 4; ++r) acc[r] = pc * (float)sold[r];
            acc = __builtin_amdgcn_mfma_f32_16x16x32_f16(fa, fdl, acc, 0, 0, 0);
            f16x4 snew;
#pragma unroll
            for (int r = 0; r < 4; ++r) snew[r] = (f16)acc[r];
            *(f16x4*)((char*)Sl[cur ^ 1] + sbyte) = snew;
        }
        cur ^= 1;
        __syncthreads();
    }
}

// ------------------------------------------------------------------
// y = rmsnorm(o * silu(z)) * norm_w  -> f16  (vectorized f16x8)
// ------------------------------------------------------------------
__global__ __launch_bounds__(256) void gate_kernel(const f16* __restrict__ o,
                                                   const f16* __restrict__ qkvz,
                                                   const float* __restrict__ norm_w,
                                                   f16* __restrict__ y) {
    int token = blockIdx.x;  // b*2048 + s
    int tid = threadIdx.x;
    int hv = tid >> 3, part = tid & 7;
    int dv0 = part * 16;
    const f16* orow = o + ((long)token * 32 + hv) * 128 + dv0;
    long zcol = (long)(hv >> 1) * 768 + 512 + (hv & 1) * 128 + dv0;
    const f16* zrow = qkvz + (long)token * 12288 + zcol;
    f16x8 ov0 = *(const f16x8*)orow, ov1 = *(const f16x8*)(orow + 8);
    f16x8 zv0 = *(const f16x8*)zrow, zv1 = *(const f16x8*)(zrow + 8);
    float yv[16];
    float ss = 0.f;
#pragma unroll
    for (int i = 0; i < 16; ++i) {
        float ovf = (float)(i < 8 ? ov0[i] : ov1[i - 8]);
        float zvf = (float)(i < 8 ? zv0[i] : zv1[i - 8]);
        float gt = zvf / (1.f + expf(-zvf));
        float v = ovf * gt;
        yv[i] = v;
        ss += v * v;
    }
    ss += __shfl_xor(ss, 1); ss += __shfl_xor(ss, 2); ss += __shfl_xor(ss, 4);
    float scale = rsqrtf(ss * (1.f / 128.f) + 1e-6f);
    f16* yrow = y + (long)token * 4096 + hv * 128 + dv0;
    f16x8 y0, y1;
#pragma unroll
    for (int i = 0; i < 8; ++i) {
        y0[i] = (f16)(yv[i] * scale * norm_w[dv0 + i]);
        y1[i] = (f16)(yv[8 + i] * scale * norm_w[dv0 + 8 + i]);
    }
    *(f16x8*)yrow = y0;
    *(f16x8*)(yrow + 8) = y1;
}

// ------------------------------------------------------------------
// Workspace (242 MB, time-aliased) — lifetime-audited:
//   [0,96)    qkvz16  (gemm1 -> gate)
//   [96,112)  x16 (cvt -> gemm1); then d0g (chunk_pre -> scan)
//   [112,160) WT (transpose -> gemm1); then d0g tail / Wg / T2ng / khT
//   [96,128)  d0g ; [128,136) Wg ; [136,144) T2ng ; [144,160) khT
//   [160,176) WTo (transpose -> gemm2)
//   [176,208) qh,kh (conv -> scan); y16 over it after scan
//   [208,240) vh (conv -> chunk_pre); ob over it (scan -> gate)
//   [240,240.5) gbuf ; [240.5,241) btb ; [241,242) pvg
// ------------------------------------------------------------------
extern "C" void kernel_launch(void* const* d_in, const int* in_sizes, int n_in,
                              void* d_out, int out_size, void* d_ws, size_t ws_size,
                              hipStream_t stream) {
    const float* x       = (const float*)d_in[0];
    const float* w_qkvz  = (const float*)d_in[1];
    const float* w_ba    = (const float*)d_in[2];
    const float* conv_w  = (const float*)d_in[3];
    const float* conv_b  = (const float*)d_in[4];
    const float* a_log   = (const float*)d_in[5];
    const float* dt_bias = (const float*)d_in[6];
    const float* norm_w  = (const float*)d_in[7];
    const float* w_o     = (const float*)d_in[8];
    float* out = (float*)d_out;

    char* ws = (char*)d_ws;
    const size_t MB = 1024 * 1024;
    f16*   qkvz16 = (f16*)ws;
    f16*   x16    = (f16*)(ws + 96 * MB);
    f16*   WT     = (f16*)(ws + 112 * MB);
    f16*   d0g    = (f16*)(ws + 96 * MB);
    f16*   Wg     = (f16*)(ws + 128 * MB);
    f16*   T2ng   = (f16*)(ws + 136 * MB);
    f16*   khT    = (f16*)(ws + 144 * MB);
    f16*   WTo    = (f16*)(ws + 160 * MB);
    f16*   qh     = (f16*)(ws + 176 * MB);
    f16*   kh     = (f16*)(ws + 192 * MB);
    f16*   vh     = (f16*)(ws + 208 * MB);
    f16*   ob     = (f16*)(ws + 208 * MB);
    f16*   y16    = (f16*)(ws + 176 * MB);
    float* gbuf   = (float*)(ws + 240 * MB);
    float* btb    = (float*)(ws + 240 * MB + 512 * 1024);
    float* pvg    = (float*)(ws + 241 * MB);

    // prep
    cvt16_kernel<<<8192, 256, 0, stream>>>(x, x16, 4096 * 2048 / 4);
    transpose16_kernel<<<dim3(12288 / 64, 2048 / 64), 256, 0, stream>>>(w_qkvz, WT, 2048, 12288);
    transpose16_kernel<<<dim3(2048 / 64, 4096 / 64), 256, 0, stream>>>(w_o, WTo, 4096, 2048);

    // qkvz = x @ w_qkvz  (256x256 deep-pipelined)
    gemm256_kernel<4, 1><<<dim3(12288 / 256, 4096 / 256), 512, 0, stream>>>(x16, WT, qkvz16, 4096, 12288, 2048);
    // ba = x @ w_ba  (fused g/beta epilogue)
    ba_gemm_kernel<<<256, 256, 0, stream>>>(x, w_ba, a_log, dt_bias, gbuf, btb);

    // conv + silu + l2norm
    conv_kernel<<<dim3(64, 64, 2), 256, 0, stream>>>(qkvz16, conv_w, conv_b, qh, kh, vh);
    // k transpose
    kT_kernel<<<1024, 256, 0, stream>>>(kh, khT);
    // per-chunk UT-transform precompute (no K/Q LDS staging)
    chunk_pre_kernel<<<4096, 64, 0, stream>>>(qh, kh, vh, gbuf, btb, Wg, T2ng, d0g, pvg);
    // sequential chunked MFMA scan
    scan_kernel<<<512, 64, 0, stream>>>(qh, kh, khT, Wg, T2ng, d0g, pvg, ob);

    // gating + rmsnorm -> y16
    gate_kernel<<<4096, 256, 0, stream>>>(ob, qkvz16, norm_w, y16);

    // out = y @ w_o  (256x128 deep-pipelined, f32 out)
    gemm256_kernel<2, 0><<<dim3(2048 / 128, 4096 / 256), 512, 0, stream>>>(y16, WTo, out, 4096, 2048, 4096);
}

// Round 16
// 747.964 us; speedup vs baseline: 1.6631x; 1.0975x over previous
//
#include <hip/hip_runtime.h>

typedef _Float16 f16;
typedef _Float16 f16x2 __attribute__((ext_vector_type(2)));
typedef _Float16 f16x4 __attribute__((ext_vector_type(4)));
typedef _Float16 f16x8 __attribute__((ext_vector_type(8)));
typedef float f32x4 __attribute__((ext_vector_type(4)));

#define QSCALE 0.08838834764831845f  // DK^-0.5

#define RAW_BARRIER() do { \
    asm volatile("s_waitcnt lgkmcnt(0)" ::: "memory"); \
    __builtin_amdgcn_s_barrier(); \
    __builtin_amdgcn_sched_barrier(0); \
} while (0)

// ------------------------------------------------------------------
// convert fp32 -> f16 (vectorized x4)
// ------------------------------------------------------------------
__global__ __launch_bounds__(256) void cvt16_kernel(const float* __restrict__ in,
                                                    f16* __restrict__ out, int n4) {
    int i = blockIdx.x * 256 + threadIdx.x;
    if (i >= n4) return;
    f32x4 v = ((const f32x4*)in)[i];
    f16x4 h;
    h[0] = (f16)v[0]; h[1] = (f16)v[1]; h[2] = (f16)v[2]; h[3] = (f16)v[3];
    ((f16x4*)out)[i] = h;
}

// ------------------------------------------------------------------
// transpose fp32 [R][C] -> f16 [C][R]
// ------------------------------------------------------------------
__global__ __launch_bounds__(256) void transpose16_kernel(const float* __restrict__ in,
                                                          f16* __restrict__ out, int R, int C) {
    __shared__ f16 tile[64][66];
    int c0 = blockIdx.x * 64, r0 = blockIdx.y * 64;
    int tid = threadIdx.x;
#pragma unroll
    for (int i = 0; i < 16; ++i) {
        int idx = i * 256 + tid;
        int r = idx >> 6, c = idx & 63;
        tile[r][c] = (f16)in[(long)(r0 + r) * C + (c0 + c)];
    }
    __syncthreads();
#pragma unroll
    for (int i = 0; i < 16; ++i) {
        int idx = i * 256 + tid;
        int orow = idx >> 6, oc = idx & 63;
        out[(long)(c0 + orow) * R + (r0 + oc)] = tile[oc][orow];
    }
}

// ------------------------------------------------------------------
// 256xBN deep-pipelined f16 MFMA GEMM. BN = 64*NJ.
// ------------------------------------------------------------------
template <int NJ, int F16OUT>
__global__ __launch_bounds__(512, 1) void gemm256_kernel(const f16* __restrict__ A,
                                                         const f16* __restrict__ Bt,
                                                         void* __restrict__ Cout,
                                                         int M, int N, int Kd) {
    constexpr int BN = 64 * NJ;
    constexpr int BNW = 16 * NJ;
    __shared__ f16 sA[2][256 * 64];
    __shared__ f16 sB[2][BN * 64];
    const int tid = threadIdx.x;
    const int lane = tid & 63, wv = tid >> 6;
    const int wm = wv >> 2, wn = wv & 3;
    const int m0 = blockIdx.y * 256, n0 = blockIdx.x * BN;
    const int lrow = lane & 15, lk = lane >> 4;
    const int nK = Kd >> 6;

    f32x4 acc[8][NJ] = {};
    f32x4 ra[4], rb[NJ];

    auto issue = [&](int k0) {
#pragma unroll
        for (int j = 0; j < 4; ++j) {
            int P = (tid + j * 512) * 16;
            int row = P >> 7;
            int koff = (P & 127) >> 1;
            ra[j] = *(const f32x4*)(A + (long)(m0 + row) * Kd + k0 + koff);
        }
#pragma unroll
        for (int j = 0; j < NJ; ++j) {
            int P = (tid + j * 512) * 16;
            int row = P >> 7;
            int koff = (P & 127) >> 1;
            rb[j] = *(const f32x4*)(Bt + (long)(n0 + row) * Kd + k0 + koff);
        }
    };
    auto commit = [&](int buf) {
#pragma unroll
        for (int j = 0; j < 4; ++j) {
            int P = (tid + j * 512) * 16;
            int row = P >> 7;
            int sw = P ^ ((row & 7) << 4);
            *(f32x4*)((char*)&sA[buf][0] + sw) = ra[j];
        }
#pragma unroll
        for (int j = 0; j < NJ; ++j) {
            int P = (tid + j * 512) * 16;
            int row = P >> 7;
            int sw = P ^ ((row & 7) << 4);
            *(f32x4*)((char*)&sB[buf][0] + sw) = rb[j];
        }
    };

    issue(0);
    commit(0);
    if (nK > 1) issue(64);
    RAW_BARRIER();

    int cur = 0;
    for (int t = 0; t < nK; ++t) {
        if (t + 1 < nK) commit(cur ^ 1);
        if (t + 2 < nK) issue((t + 2) * 64);
        const char* bA = (const char*)&sA[cur][0];
        const char* bB = (const char*)&sB[cur][0];
        __builtin_amdgcn_s_setprio(1);
#pragma unroll
        for (int kk = 0; kk < 2; ++kk) {
            f16x8 bf[NJ];
#pragma unroll
            for (int j = 0; j < NJ; ++j) {
                int brow = wn * BNW + j * 16 + lrow;
                int bbyte = brow * 128 + kk * 64 + lk * 16;
                bf[j] = *(const f16x8*)(bB + (bbyte ^ ((brow & 7) << 4)));
            }
#pragma unroll
            for (int i = 0; i < 8; ++i) {
                int arow = wm * 128 + i * 16 + lrow;
                int abyte = arow * 128 + kk * 64 + lk * 16;
                f16x8 af = *(const f16x8*)(bA + (abyte ^ ((arow & 7) << 4)));
#pragma unroll
                for (int j = 0; j < NJ; ++j)
                    acc[i][j] = __builtin_amdgcn_mfma_f32_16x16x32_f16(af, bf[j], acc[i][j], 0, 0, 0);
            }
        }
        __builtin_amdgcn_s_setprio(0);
        RAW_BARRIER();
        cur ^= 1;
    }

#pragma unroll
    for (int i = 0; i < 8; ++i) {
        int gm_base = m0 + wm * 128 + i * 16 + lk * 4;
#pragma unroll
        for (int j = 0; j < NJ; ++j) {
            int gn = n0 + wn * BNW + j * 16 + lrow;
#pragma unroll
            for (int r = 0; r < 4; ++r) {
                long idx = (long)(gm_base + r) * N + gn;
                if (F16OUT) ((f16*)Cout)[idx] = (f16)acc[i][j][r];
                else        ((float*)Cout)[idx] = acc[i][j][r];
            }
        }
    }
}

// ------------------------------------------------------------------
// ba = x @ w_ba, FUSED epilogue: g/beta directly.
// ------------------------------------------------------------------
__global__ __launch_bounds__(256) void ba_gemm_kernel(const float* __restrict__ x,
                                                      const float* __restrict__ w,
                                                      const float* __restrict__ a_log,
                                                      const float* __restrict__ dt_bias,
                                                      float* __restrict__ gout,
                                                      float* __restrict__ bt) {
    __shared__ float xs[16][256];
    int tid = threadIdx.x;
    int t0 = blockIdx.x * 16;
    int o = tid & 63, tg = tid >> 6;
    float acc[4] = {0.f, 0.f, 0.f, 0.f};
    for (int kc = 0; kc < 2048; kc += 256) {
        __syncthreads();
#pragma unroll
        for (int i = 0; i < 16; ++i) {
            int idx = i * 256 + tid;
            int tok = idx >> 8, k = idx & 255;
            xs[tok][k] = x[(long)(t0 + tok) * 2048 + kc + k];
        }
        __syncthreads();
        for (int k = 0; k < 256; ++k) {
            float wv = w[(long)(kc + k) * 64 + o];
#pragma unroll
            for (int j = 0; j < 4; ++j) acc[j] += xs[tg * 4 + j][k] * wv;
        }
    }
    int hv = ((o >> 2) << 1) | (o & 1);
    bool isB = (o & 2) == 0;
    float al = expf(a_log[hv]);
    float db = dt_bias[hv];
#pragma unroll
    for (int j = 0; j < 4; ++j) {
        int tok = t0 + tg * 4 + j;
        int b = tok >> 11, s = tok & 2047;
        long oidx = ((long)b * 32 + hv) * 2048 + s;
        if (isB) {
            bt[oidx] = 1.f / (1.f + expf(-acc[j]));
        } else {
            float xx = acc[j] + db;
            float sp = (xx > 20.f) ? xx : log1pf(expf(xx));
            gout[oidx] = -al * sp;
        }
    }
}

// ------------------------------------------------------------------
// depthwise causal conv(K=4) + bias + SiLU (+ L2norm for q/k heads)
// k-head blocks ALSO emit the transposed copy khT (kT kernel fused).
// ------------------------------------------------------------------
__global__ __launch_bounds__(256) void conv_kernel(const f16* __restrict__ qkvz,
                                                   const float* __restrict__ cw,
                                                   const float* __restrict__ cb,
                                                   f16* __restrict__ qh,
                                                   f16* __restrict__ kh,
                                                   f16* __restrict__ vh,
                                                   f16* __restrict__ khT) {
    __shared__ float Lin[35 * 128];
    __shared__ float Lout[32 * 128];
    __shared__ float Lsc[32];
    int g = blockIdx.x;
    int s0 = blockIdx.y * 32;
    int b = blockIdx.z;
    int tid = threadIdx.x;
    int colbase, chbase;
    f16* outp;
    bool donorm;
    bool isk = false;
    int hk = 0;
    float nmul;
    if (g < 16) {
        colbase = g * 768; chbase = g * 128;
        outp = qh + (((long)b * 16 + g) * 2048 + s0) * 128;
        donorm = true; nmul = QSCALE;
    } else if (g < 32) {
        hk = g - 16;
        colbase = hk * 768 + 128; chbase = 2048 + hk * 128;
        outp = kh + (((long)b * 16 + hk) * 2048 + s0) * 128;
        donorm = true; nmul = 1.f; isk = true;
    } else {
        int hv = g - 32;
        colbase = (hv >> 1) * 768 + 256 + (hv & 1) * 128; chbase = 4096 + hv * 128;
        outp = vh + (((long)b * 32 + hv) * 2048 + s0) * 128;
        donorm = false; nmul = 1.f;
    }
    for (int ci = tid; ci < 35 * 16; ci += 256) {
        int sr = ci >> 4, cc = (ci & 15) * 8;
        int s = s0 + sr - 3;
        f32x4 lo = {}, hi = {};
        if (s >= 0) {
            f16x8 v = *(const f16x8*)(qkvz + ((long)b * 2048 + s) * 12288 + colbase + cc);
#pragma unroll
            for (int e = 0; e < 4; ++e) { lo[e] = (float)v[e]; hi[e] = (float)v[4 + e]; }
        }
        *(f32x4*)&Lin[sr * 128 + cc] = lo;
        *(f32x4*)&Lin[sr * 128 + cc + 4] = hi;
    }
    __syncthreads();
    int c = tid & 127, sg = tid >> 7;
    float w0 = cw[(chbase + c) * 4 + 0];
    float w1 = cw[(chbase + c) * 4 + 1];
    float w2 = cw[(chbase + c) * 4 + 2];
    float w3 = cw[(chbase + c) * 4 + 3];
    float bias = cb[chbase + c];
#pragma unroll
    for (int j = 0; j < 16; ++j) {
        int sl = sg * 16 + j;
        float v = w0 * Lin[sl * 128 + c] + w1 * Lin[(sl + 1) * 128 + c] +
                  w2 * Lin[(sl + 2) * 128 + c] + w3 * Lin[(sl + 3) * 128 + c] + bias;
        v = v / (1.f + expf(-v));  // SiLU
        Lout[sl * 128 + c] = v;
    }
    __syncthreads();
    if (donorm) {
        int token = tid >> 3, part = tid & 7;
        float ss = 0.f;
#pragma unroll
        for (int i = 0; i < 16; ++i) {
            float v = Lout[token * 128 + part * 16 + i];
            ss += v * v;
        }
        ss += __shfl_xor(ss, 1); ss += __shfl_xor(ss, 2); ss += __shfl_xor(ss, 4);
        if (part == 0) Lsc[token] = rsqrtf(ss + 1e-6f) * nmul;
        __syncthreads();
#pragma unroll
        for (int j = 0; j < 16; ++j) {
            int sl = sg * 16 + j;
            outp[(long)sl * 128 + c] = (f16)(Lout[sl * 128 + c] * Lsc[sl]);
        }
        if (isk) {
            // transposed copy: thread (dk, sh) writes 16 contiguous s for one dk
            int dk = tid >> 1, sh = tid & 1;
            f16x8 v0, v1;
#pragma unroll
            for (int i = 0; i < 8; ++i) {
                v0[i] = (f16)(Lout[(sh * 16 + i) * 128 + dk] * Lsc[sh * 16 + i]);
                v1[i] = (f16)(Lout[(sh * 16 + 8 + i) * 128 + dk] * Lsc[sh * 16 + 8 + i]);
            }
            f16* kt = khT + ((long)(b * 16 + hk) * 128 + dk) * 2048 + s0 + sh * 16;
            *(f16x8*)kt = v0;
            *(f16x8*)(kt + 8) = v1;
        }
    } else {
#pragma unroll
        for (int j = 0; j < 16; ++j) {
            int sl = sg * 16 + j;
            outp[(long)sl * 128 + c] = (f16)Lout[sl * 128 + c];
        }
    }
}

// ------------------------------------------------------------------
// chunk_pre: per (b,hv,chunk of 32) — one wave. (r15 version, proven)
// ------------------------------------------------------------------
__global__ __launch_bounds__(64) void chunk_pre_kernel(const f16* __restrict__ qh,
                                                       const f16* __restrict__ kh,
                                                       const f16* __restrict__ vh,
                                                       const float* __restrict__ gb,
                                                       const float* __restrict__ bt,
                                                       f16* __restrict__ Wg,
                                                       f16* __restrict__ T2ng,
                                                       f16* __restrict__ d0g,
                                                       float* __restrict__ pvg) {
    __shared__ f16 VTl[128 * 32];
    __shared__ float KKl[32 * 32];
    __shared__ float RL[32 * 32];
    __shared__ float Tf[32 * 33];
    __shared__ f16 Tl[32 * 64];
    __shared__ float cuml[32], bl[32], pl[32];

    int bid = blockIdx.x;
    int chunk = bid & 63;
    int hv = (bid >> 6) & 31;
    int b = bid >> 11;
    int bh = b * 16 + (hv >> 1);
    int l = threadIdx.x;
    int h = l >> 4, c = l & 15;
    long chid = bid;

    const f16* kbase = kh + ((long)bh * 2048 + chunk * 32) * 128;
    const f16* qbase = qh + ((long)bh * 2048 + chunk * 32) * 128;
    const f16* vbase = vh + (((long)b * 32 + hv) * 2048 + chunk * 32) * 128;
    const float* gp = gb + ((long)b * 32 + hv) * 2048 + chunk * 32;
    const float* bp = bt + ((long)b * 32 + hv) * 2048 + chunk * 32;

    f16x8 fk[2][4], fq[2][4];
#pragma unroll
    for (int ti = 0; ti < 2; ++ti)
#pragma unroll
        for (int kk = 0; kk < 4; ++kk) {
            fk[ti][kk] = *(const f16x8*)(kbase + (c + 16 * ti) * 128 + kk * 32 + h * 8);
            fq[ti][kk] = *(const f16x8*)(qbase + (c + 16 * ti) * 128 + kk * 32 + h * 8);
        }

    float gv = (l < 32) ? gp[l] : 0.f;
#pragma unroll
    for (int d = 1; d < 32; d <<= 1) {
        float t2 = __shfl_up(gv, d);
        if (l >= d) gv += t2;
    }
    if (l < 32) { cuml[l] = gv; bl[l] = bp[l]; pl[l] = expf(gv); }
    __syncthreads();

#pragma unroll
    for (int it = 0; it < 8; ++it) {
        int idx = (l + it * 64) * 8;
        int row = idx >> 7, col = idx & 127;
        f16x8 v = *(const f16x8*)(vbase + (long)row * 128 + col);
        float be = bl[row];
#pragma unroll
        for (int e = 0; e < 8; ++e) {
            int dv = col + e;
            int byte = (dv * 64 + row * 2) ^ ((dv & 3) << 4);
            *(f16*)((char*)VTl + byte) = (f16)((float)v[e] * be);
        }
    }
#pragma unroll
    for (int it = 0; it < 16; ++it) {
        int e = l * 16 + it;
        int i = e >> 5, j = e & 31;
        RL[e] = (j <= i) ? expf(cuml[i] - cuml[j]) : 0.f;
    }
    __syncthreads();

    {
        f32x4 acc[2][2] = {};
#pragma unroll
        for (int kk = 0; kk < 4; ++kk) {
            acc[0][0] = __builtin_amdgcn_mfma_f32_16x16x32_f16(fk[0][kk], fk[0][kk], acc[0][0], 0, 0, 0);
            acc[0][1] = __builtin_amdgcn_mfma_f32_16x16x32_f16(fk[0][kk], fk[1][kk], acc[0][1], 0, 0, 0);
            acc[1][0] = __builtin_amdgcn_mfma_f32_16x16x32_f16(fk[1][kk], fk[0][kk], acc[1][0], 0, 0, 0);
            acc[1][1] = __builtin_amdgcn_mfma_f32_16x16x32_f16(fk[1][kk], fk[1][kk], acc[1][1], 0, 0, 0);
        }
#pragma unroll
        for (int ti = 0; ti < 2; ++ti)
#pragma unroll
            for (int tj = 0; tj < 2; ++tj)
#pragma unroll
                for (int r = 0; r < 4; ++r)
                    KKl[(h * 4 + r + 16 * ti) * 32 + c + 16 * tj] = acc[ti][tj][r];
    }
    {
        f32x4 acc[2][2] = {};
#pragma unroll
        for (int kk = 0; kk < 4; ++kk) {
            acc[0][0] = __builtin_amdgcn_mfma_f32_16x16x32_f16(fq[0][kk], fk[0][kk], acc[0][0], 0, 0, 0);
            acc[0][1] = __builtin_amdgcn_mfma_f32_16x16x32_f16(fq[0][kk], fk[1][kk], acc[0][1], 0, 0, 0);
            acc[1][0] = __builtin_amdgcn_mfma_f32_16x16x32_f16(fq[1][kk], fk[0][kk], acc[1][0], 0, 0, 0);
            acc[1][1] = __builtin_amdgcn_mfma_f32_16x16x32_f16(fq[1][kk], fk[1][kk], acc[1][1], 0, 0, 0);
        }
        __syncthreads();
#pragma unroll
        for (int ti = 0; ti < 2; ++ti)
#pragma unroll
            for (int tj = 0; tj < 2; ++tj)
#pragma unroll
                for (int r = 0; r < 4; ++r) {
                    int i = h * 4 + r + 16 * ti, j = c + 16 * tj;
                    Wg[chid * 1024 + i * 32 + j] = (f16)(acc[ti][tj][r] * RL[i * 32 + j]);
                }
    }

    if (l < 32) {
        int j = l;
        for (int i = 0; i < 32; ++i) {
            float s = (i == j) ? 1.f : 0.f;
            float bi = bl[i];
            for (int ll = j; ll < i; ++ll)
                s -= bi * KKl[i * 32 + ll] * RL[i * 32 + ll] * Tf[ll * 33 + j];
            Tf[i * 33 + j] = s;
        }
        float bpj = bl[j] * pl[j];
        for (int i = 0; i < 32; ++i) {
            float tv = (i >= j) ? Tf[i * 33 + j] : 0.f;
            int byte = (i * 128 + j * 2) ^ ((i & 3) << 4);
            *(f16*)((char*)Tl + byte) = (f16)tv;
            T2ng[chid * 1024 + i * 32 + j] = (f16)(-tv * bpj);
        }
        pvg[chid * 64 + j] = pl[j];
        pvg[chid * 64 + 32 + j] = expf(cuml[31] - cuml[j]);
    }
    __syncthreads();

    {
        f16x8 fT[2];
#pragma unroll
        for (int ti = 0; ti < 2; ++ti) {
            int row = c + 16 * ti;
            fT[ti] = *(const f16x8*)((const char*)Tl + ((row * 128 + h * 16) ^ ((row & 3) << 4)));
        }
#pragma unroll
        for (int nj = 0; nj < 8; ++nj) {
            int dv = c + 16 * nj;
            f16x8 fv = *(const f16x8*)((const char*)VTl + ((dv * 64 + h * 16) ^ ((dv & 3) << 4)));
            f32x4 a0 = {}, a1 = {};
            a0 = __builtin_amdgcn_mfma_f32_16x16x32_f16(fT[0], fv, a0, 0, 0, 0);
            a1 = __builtin_amdgcn_mfma_f32_16x16x32_f16(fT[1], fv, a1, 0, 0, 0);
            f16x4 s0, s1;
#pragma unroll
            for (int r = 0; r < 4; ++r) { s0[r] = (f16)a0[r]; s1[r] = (f16)a1[r]; }
            *(f16x4*)(d0g + chid * 4096 + (long)dv * 32 + 4 * h) = s0;
            *(f16x4*)(d0g + chid * 4096 + (long)dv * 32 + 16 + 4 * h) = s1;
        }
    }
}

// ------------------------------------------------------------------
// sequential chunked scan: grid 512 = (b,hv,vs of 16 dv); 1 wave.
// 2-chunk REGISTER double-buffer: next chunk's global operands load
// during this chunk's MFMA chain (RAW_BARRIER = lgkmcnt only, loads
// stay in flight).
// ------------------------------------------------------------------
struct CR {
    f16x8 fk[2][4], fq[2][4], fkt[8], fT[2], fW[2];
    f16x4 fd0[2];
    f32x4 pva, pvb, kwa, kwb;
    float pc;
};

__global__ __launch_bounds__(64, 1) void scan_kernel(const f16* __restrict__ qh,
                                                     const f16* __restrict__ kh,
                                                     const f16* __restrict__ khT,
                                                     const f16* __restrict__ Wg,
                                                     const f16* __restrict__ T2ng,
                                                     const f16* __restrict__ d0g,
                                                     const float* __restrict__ pvg,
                                                     f16* __restrict__ ob) {
    __shared__ f16 Sl[2][16 * 128];
    __shared__ f16 AKl[16 * 32];
    __shared__ f16 Dl[16 * 32];

    int pbid = blockIdx.x;
    int bid = (pbid & 7) * 64 + (pbid >> 3);
    int vs = bid & 7;
    int hv = (bid >> 3) & 31;
    int b = bid >> 8;
    int bh32 = b * 32 + hv;
    int bh = b * 16 + (hv >> 1);
    int l = threadIdx.x, h = l >> 4, c = l & 15;

    const f16* kb = kh + (long)bh * 2048 * 128;
    const f16* qb = qh + (long)bh * 2048 * 128;
    const f16* ktb = khT + (long)bh * 128 * 2048;

    f16x8 z = {};
#pragma unroll
    for (int it = 0; it < 4; ++it) *(f16x8*)((char*)Sl[0] + (l + it * 64) * 16) = z;

    int cur = 0;

    auto loadC = [&](CR& R, int ch) {
        long chid = (long)bh32 * 64 + ch;
#pragma unroll
        for (int ti = 0; ti < 2; ++ti) {
            long row = (long)ch * 32 + c + 16 * ti;
#pragma unroll
            for (int kk = 0; kk < 4; ++kk) {
                R.fk[ti][kk] = *(const f16x8*)(kb + row * 128 + kk * 32 + h * 8);
                R.fq[ti][kk] = *(const f16x8*)(qb + row * 128 + kk * 32 + h * 8);
            }
            R.fT[ti] = *(const f16x8*)(T2ng + chid * 1024 + (c + 16 * ti) * 32 + h * 8);
            R.fW[ti] = *(const f16x8*)(Wg + chid * 1024 + (c + 16 * ti) * 32 + h * 8);
        }
#pragma unroll
        for (int ti = 0; ti < 8; ++ti)
            R.fkt[ti] = *(const f16x8*)(ktb + (long)(c + 16 * ti) * 2048 + ch * 32 + h * 8);
#pragma unroll
        for (int ti = 0; ti < 2; ++ti)
            R.fd0[ti] = *(const f16x4*)(d0g + chid * 4096 +
                                        (long)(vs * 16 + c) * 32 + 16 * ti + 4 * h);
        R.pva = *(const f32x4*)(pvg + chid * 64 + 4 * h);
        R.pvb = *(const f32x4*)(pvg + chid * 64 + 16 + 4 * h);
        R.pc = pvg[chid * 64 + 31];
        R.kwa = *(const f32x4*)(pvg + chid * 64 + 32 + h * 8);
        R.kwb = *(const f32x4*)(pvg + chid * 64 + 36 + h * 8);
    };

    auto computeC = [&](const CR& R, int ch) {
        const int dv = c;
        f16x8 fS[4];
#pragma unroll
        for (int kk = 0; kk < 4; ++kk)
            fS[kk] = *(const f16x8*)((char*)Sl[cur] +
                                     (dv * 256 + ((kk * 64 + h * 16) ^ ((dv & 7) << 4))));
        f32x4 AK[2] = {}, AQ[2] = {};
#pragma unroll
        for (int ti = 0; ti < 2; ++ti)
#pragma unroll
            for (int kk = 0; kk < 4; ++kk) {
                AK[ti] = __builtin_amdgcn_mfma_f32_16x16x32_f16(R.fk[ti][kk], fS[kk], AK[ti], 0, 0, 0);
                AQ[ti] = __builtin_amdgcn_mfma_f32_16x16x32_f16(R.fq[ti][kk], fS[kk], AQ[ti], 0, 0, 0);
            }
#pragma unroll
        for (int ti = 0; ti < 2; ++ti) {
            f16x4 t;
#pragma unroll
            for (int r = 0; r < 4; ++r) t[r] = (f16)AK[ti][r];
            *(f16x4*)((char*)AKl + ((dv * 64 + 32 * ti + 8 * h) ^ ((dv & 3) << 4))) = t;
        }
        f32x4 Dv[2];
#pragma unroll
        for (int ti = 0; ti < 2; ++ti)
#pragma unroll
            for (int r = 0; r < 4; ++r) Dv[ti][r] = (float)R.fd0[ti][r];
        {
            f16x8 fak = *(const f16x8*)((char*)AKl + ((dv * 64 + h * 16) ^ ((dv & 3) << 4)));
#pragma unroll
            for (int ti = 0; ti < 2; ++ti)
                Dv[ti] = __builtin_amdgcn_mfma_f32_16x16x32_f16(R.fT[ti], fak, Dv[ti], 0, 0, 0);
        }
#pragma unroll
        for (int ti = 0; ti < 2; ++ti) {
            f16x4 t;
#pragma unroll
            for (int r = 0; r < 4; ++r) t[r] = (f16)Dv[ti][r];
            *(f16x4*)((char*)Dl + ((dv * 64 + 32 * ti + 8 * h) ^ ((dv & 3) << 4))) = t;
        }
        f16x8 fdl = *(const f16x8*)((char*)Dl + ((dv * 64 + h * 16) ^ ((dv & 3) << 4)));
        f32x4 Ov[2];
#pragma unroll
        for (int ti = 0; ti < 2; ++ti)
#pragma unroll
            for (int r = 0; r < 4; ++r)
                Ov[ti][r] = AQ[ti][r] * (ti ? R.pvb[r] : R.pva[r]);
#pragma unroll
        for (int ti = 0; ti < 2; ++ti)
            Ov[ti] = __builtin_amdgcn_mfma_f32_16x16x32_f16(R.fW[ti], fdl, Ov[ti], 0, 0, 0);
#pragma unroll
        for (int ti = 0; ti < 2; ++ti)
#pragma unroll
            for (int r = 0; r < 4; ++r) {
                long tok = (long)b * 2048 + ch * 32 + 16 * ti + 4 * h + r;
                ob[tok * 4096 + hv * 128 + vs * 16 + c] = (f16)Ov[ti][r];
            }
#pragma unroll
        for (int ti = 0; ti < 8; ++ti) {
            f16x8 fa;
#pragma unroll
            for (int e = 0; e < 8; ++e)
                fa[e] = (f16)((float)R.fkt[ti][e] * (e < 4 ? R.kwa[e] : R.kwb[e - 4]));
            int sbyte = (dv * 256 + (32 * ti + 8 * h)) ^ ((dv & 7) << 4);
            f16x4 sold = *(const f16x4*)((char*)Sl[cur] + sbyte);
            f32x4 acc;
#pragma unroll
            for (int r = 0; r < 4; ++r) acc[r] = R.pc * (float)sold[r];
            acc = __builtin_amdgcn_mfma_f32_16x16x32_f16(fa, fdl, acc, 0, 0, 0);
            f16x4 snew;
#pragma unroll
            for (int r = 0; r < 4; ++r) snew[r] = (f16)acc[r];
            *(f16x4*)((char*)Sl[cur ^ 1] + sbyte) = snew;
        }
        cur ^= 1;
        RAW_BARRIER();
    };

    CR A, B;
    loadC(A, 0);
    RAW_BARRIER();  // covers the Sl[0] zero-init ds_writes
    for (int ch = 0; ch < 64; ch += 2) {
        loadC(B, ch + 1);
        computeC(A, ch);
        loadC(A, ch + 2 < 64 ? ch + 2 : 63);
        computeC(B, ch + 1);
    }
}

// ------------------------------------------------------------------
// y = rmsnorm(o * silu(z)) * norm_w  -> f16  (vectorized f16x8)
// ------------------------------------------------------------------
__global__ __launch_bounds__(256) void gate_kernel(const f16* __restrict__ o,
                                                   const f16* __restrict__ qkvz,
                                                   const float* __restrict__ norm_w,
                                                   f16* __restrict__ y) {
    int token = blockIdx.x;  // b*2048 + s
    int tid = threadIdx.x;
    int hv = tid >> 3, part = tid & 7;
    int dv0 = part * 16;
    const f16* orow = o + ((long)token * 32 + hv) * 128 + dv0;
    long zcol = (long)(hv >> 1) * 768 + 512 + (hv & 1) * 128 + dv0;
    const f16* zrow = qkvz + (long)token * 12288 + zcol;
    f16x8 ov0 = *(const f16x8*)orow, ov1 = *(const f16x8*)(orow + 8);
    f16x8 zv0 = *(const f16x8*)zrow, zv1 = *(const f16x8*)(zrow + 8);
    float yv[16];
    float ss = 0.f;
#pragma unroll
    for (int i = 0; i < 16; ++i) {
        float ovf = (float)(i < 8 ? ov0[i] : ov1[i - 8]);
        float zvf = (float)(i < 8 ? zv0[i] : zv1[i - 8]);
        float gt = zvf / (1.f + expf(-zvf));
        float v = ovf * gt;
        yv[i] = v;
        ss += v * v;
    }
    ss += __shfl_xor(ss, 1); ss += __shfl_xor(ss, 2); ss += __shfl_xor(ss, 4);
    float scale = rsqrtf(ss * (1.f / 128.f) + 1e-6f);
    f16* yrow = y + (long)token * 4096 + hv * 128 + dv0;
    f16x8 y0, y1;
#pragma unroll
    for (int i = 0; i < 8; ++i) {
        y0[i] = (f16)(yv[i] * scale * norm_w[dv0 + i]);
        y1[i] = (f16)(yv[8 + i] * scale * norm_w[dv0 + 8 + i]);
    }
    *(f16x8*)yrow = y0;
    *(f16x8*)(yrow + 8) = y1;
}

// ------------------------------------------------------------------
// Workspace (242 MB, time-aliased) — lifetime-audited (r15 layout).
// ------------------------------------------------------------------
extern "C" void kernel_launch(void* const* d_in, const int* in_sizes, int n_in,
                              void* d_out, int out_size, void* d_ws, size_t ws_size,
                              hipStream_t stream) {
    const float* x       = (const float*)d_in[0];
    const float* w_qkvz  = (const float*)d_in[1];
    const float* w_ba    = (const float*)d_in[2];
    const float* conv_w  = (const float*)d_in[3];
    const float* conv_b  = (const float*)d_in[4];
    const float* a_log   = (const float*)d_in[5];
    const float* dt_bias = (const float*)d_in[6];
    const float* norm_w  = (const float*)d_in[7];
    const float* w_o     = (const float*)d_in[8];
    float* out = (float*)d_out;

    char* ws = (char*)d_ws;
    const size_t MB = 1024 * 1024;
    f16*   qkvz16 = (f16*)ws;
    f16*   x16    = (f16*)(ws + 96 * MB);
    f16*   WT     = (f16*)(ws + 112 * MB);
    f16*   d0g    = (f16*)(ws + 96 * MB);
    f16*   Wg     = (f16*)(ws + 128 * MB);
    f16*   T2ng   = (f16*)(ws + 136 * MB);
    f16*   khT    = (f16*)(ws + 144 * MB);
    f16*   WTo    = (f16*)(ws + 160 * MB);
    f16*   qh     = (f16*)(ws + 176 * MB);
    f16*   kh     = (f16*)(ws + 192 * MB);
    f16*   vh     = (f16*)(ws + 208 * MB);
    f16*   ob     = (f16*)(ws + 208 * MB);
    f16*   y16    = (f16*)(ws + 176 * MB);
    float* gbuf   = (float*)(ws + 240 * MB);
    float* btb    = (float*)(ws + 240 * MB + 512 * 1024);
    float* pvg    = (float*)(ws + 241 * MB);

    // prep
    cvt16_kernel<<<8192, 256, 0, stream>>>(x, x16, 4096 * 2048 / 4);
    transpose16_kernel<<<dim3(12288 / 64, 2048 / 64), 256, 0, stream>>>(w_qkvz, WT, 2048, 12288);
    transpose16_kernel<<<dim3(2048 / 64, 4096 / 64), 256, 0, stream>>>(w_o, WTo, 4096, 2048);

    // qkvz = x @ w_qkvz  (256x256 deep-pipelined)
    gemm256_kernel<4, 1><<<dim3(12288 / 256, 4096 / 256), 512, 0, stream>>>(x16, WT, qkvz16, 4096, 12288, 2048);
    // ba = x @ w_ba  (fused g/beta epilogue)
    ba_gemm_kernel<<<256, 256, 0, stream>>>(x, w_ba, a_log, dt_bias, gbuf, btb);

    // conv + silu + l2norm (+ fused khT transpose for k-heads)
    conv_kernel<<<dim3(64, 64, 2), 256, 0, stream>>>(qkvz16, conv_w, conv_b, qh, kh, vh, khT);
    // per-chunk UT-transform precompute
    chunk_pre_kernel<<<4096, 64, 0, stream>>>(qh, kh, vh, gbuf, btb, Wg, T2ng, d0g, pvg);
    // sequential chunked MFMA scan (register double-buffered chunk loads)
    scan_kernel<<<512, 64, 0, stream>>>(qh, kh, khT, Wg, T2ng, d0g, pvg, ob);

    // gating + rmsnorm -> y16
    gate_kernel<<<4096, 256, 0, stream>>>(ob, qkvz16, norm_w, y16);

    // out = y @ w_o  (256x128 deep-pipelined, f32 out)
    gemm256_kernel<2, 0><<<dim3(2048 / 128, 4096 / 256), 512, 0, stream>>>(y16, WTo, out, 4096, 2048, 4096);
}

// Round 17
// 694.360 us; speedup vs baseline: 1.7915x; 1.0772x over previous
//
#include <hip/hip_runtime.h>

typedef _Float16 f16;
typedef _Float16 f16x2 __attribute__((ext_vector_type(2)));
typedef _Float16 f16x4 __attribute__((ext_vector_type(4)));
typedef _Float16 f16x8 __attribute__((ext_vector_type(8)));
typedef float f32x4 __attribute__((ext_vector_type(4)));

#define QSCALE 0.08838834764831845f  // DK^-0.5

#define RAW_BARRIER() do { \
    asm volatile("s_waitcnt lgkmcnt(0)" ::: "memory"); \
    __builtin_amdgcn_s_barrier(); \
    __builtin_amdgcn_sched_barrier(0); \
} while (0)

// ------------------------------------------------------------------
// convert fp32 -> f16 (vectorized x4)
// ------------------------------------------------------------------
__global__ __launch_bounds__(256) void cvt16_kernel(const float* __restrict__ in,
                                                    f16* __restrict__ out, int n4) {
    int i = blockIdx.x * 256 + threadIdx.x;
    if (i >= n4) return;
    f32x4 v = ((const f32x4*)in)[i];
    f16x4 h;
    h[0] = (f16)v[0]; h[1] = (f16)v[1]; h[2] = (f16)v[2]; h[3] = (f16)v[3];
    ((f16x4*)out)[i] = h;
}

// ------------------------------------------------------------------
// transpose fp32 [R][C] -> f16 [C][R]
// ------------------------------------------------------------------
__global__ __launch_bounds__(256) void transpose16_kernel(const float* __restrict__ in,
                                                          f16* __restrict__ out, int R, int C) {
    __shared__ f16 tile[64][66];
    int c0 = blockIdx.x * 64, r0 = blockIdx.y * 64;
    int tid = threadIdx.x;
#pragma unroll
    for (int i = 0; i < 16; ++i) {
        int idx = i * 256 + tid;
        int r = idx >> 6, c = idx & 63;
        tile[r][c] = (f16)in[(long)(r0 + r) * C + (c0 + c)];
    }
    __syncthreads();
#pragma unroll
    for (int i = 0; i < 16; ++i) {
        int idx = i * 256 + tid;
        int orow = idx >> 6, oc = idx & 63;
        out[(long)(c0 + orow) * R + (r0 + oc)] = tile[oc][orow];
    }
}

// ------------------------------------------------------------------
// 256xBN deep-pipelined f16 MFMA GEMM. BN = 64*NJ.
// r17: commit/issue AFTER the MFMA phase so MFMA ds_reads don't queue
// behind staging ds_writes at phase start.
// ------------------------------------------------------------------
template <int NJ, int F16OUT>
__global__ __launch_bounds__(512, 1) void gemm256_kernel(const f16* __restrict__ A,
                                                         const f16* __restrict__ Bt,
                                                         void* __restrict__ Cout,
                                                         int M, int N, int Kd) {
    constexpr int BN = 64 * NJ;
    constexpr int BNW = 16 * NJ;
    __shared__ f16 sA[2][256 * 64];
    __shared__ f16 sB[2][BN * 64];
    const int tid = threadIdx.x;
    const int lane = tid & 63, wv = tid >> 6;
    const int wm = wv >> 2, wn = wv & 3;
    const int m0 = blockIdx.y * 256, n0 = blockIdx.x * BN;
    const int lrow = lane & 15, lk = lane >> 4;
    const int nK = Kd >> 6;

    f32x4 acc[8][NJ] = {};
    f32x4 ra[4], rb[NJ];

    auto issue = [&](int k0) {
#pragma unroll
        for (int j = 0; j < 4; ++j) {
            int P = (tid + j * 512) * 16;
            int row = P >> 7;
            int koff = (P & 127) >> 1;
            ra[j] = *(const f32x4*)(A + (long)(m0 + row) * Kd + k0 + koff);
        }
#pragma unroll
        for (int j = 0; j < NJ; ++j) {
            int P = (tid + j * 512) * 16;
            int row = P >> 7;
            int koff = (P & 127) >> 1;
            rb[j] = *(const f32x4*)(Bt + (long)(n0 + row) * Kd + k0 + koff);
        }
    };
    auto commit = [&](int buf) {
#pragma unroll
        for (int j = 0; j < 4; ++j) {
            int P = (tid + j * 512) * 16;
            int row = P >> 7;
            int sw = P ^ ((row & 7) << 4);
            *(f32x4*)((char*)&sA[buf][0] + sw) = ra[j];
        }
#pragma unroll
        for (int j = 0; j < NJ; ++j) {
            int P = (tid + j * 512) * 16;
            int row = P >> 7;
            int sw = P ^ ((row & 7) << 4);
            *(f32x4*)((char*)&sB[buf][0] + sw) = rb[j];
        }
    };

    issue(0);
    commit(0);
    if (nK > 1) issue(64);
    RAW_BARRIER();

    int cur = 0;
    for (int t = 0; t < nK; ++t) {
        const char* bA = (const char*)&sA[cur][0];
        const char* bB = (const char*)&sB[cur][0];
        __builtin_amdgcn_s_setprio(1);
#pragma unroll
        for (int kk = 0; kk < 2; ++kk) {
            f16x8 bf[NJ];
#pragma unroll
            for (int j = 0; j < NJ; ++j) {
                int brow = wn * BNW + j * 16 + lrow;
                int bbyte = brow * 128 + kk * 64 + lk * 16;
                bf[j] = *(const f16x8*)(bB + (bbyte ^ ((brow & 7) << 4)));
            }
#pragma unroll
            for (int i = 0; i < 8; ++i) {
                int arow = wm * 128 + i * 16 + lrow;
                int abyte = arow * 128 + kk * 64 + lk * 16;
                f16x8 af = *(const f16x8*)(bA + (abyte ^ ((arow & 7) << 4)));
#pragma unroll
                for (int j = 0; j < NJ; ++j)
                    acc[i][j] = __builtin_amdgcn_mfma_f32_16x16x32_f16(af, bf[j], acc[i][j], 0, 0, 0);
            }
        }
        __builtin_amdgcn_s_setprio(0);
        if (t + 1 < nK) commit(cur ^ 1);        // t+1 data (loads long complete)
        if (t + 2 < nK) issue((t + 2) * 64);    // reuses ra/rb after commit
        RAW_BARRIER();
        cur ^= 1;
    }

#pragma unroll
    for (int i = 0; i < 8; ++i) {
        int gm_base = m0 + wm * 128 + i * 16 + lk * 4;
#pragma unroll
        for (int j = 0; j < NJ; ++j) {
            int gn = n0 + wn * BNW + j * 16 + lrow;
#pragma unroll
            for (int r = 0; r < 4; ++r) {
                long idx = (long)(gm_base + r) * N + gn;
                if (F16OUT) ((f16*)Cout)[idx] = (f16)acc[i][j][r];
                else        ((float*)Cout)[idx] = acc[i][j][r];
            }
        }
    }
}

// ------------------------------------------------------------------
// ba = x @ w_ba, FUSED g/beta epilogue.
// r17: grid 1024 (4 tokens/block, 1 token/thread) -> 4 blocks/CU,
// 4 waves/SIMD to hide the k-loop latency (was 1 block/CU).
// ------------------------------------------------------------------
__global__ __launch_bounds__(256) void ba_gemm_kernel(const float* __restrict__ x,
                                                      const float* __restrict__ w,
                                                      const float* __restrict__ a_log,
                                                      const float* __restrict__ dt_bias,
                                                      float* __restrict__ gout,
                                                      float* __restrict__ bt) {
    __shared__ float xs[4][2048];
    int tid = threadIdx.x;
    int t0 = blockIdx.x * 4;
    int o = tid & 63, tg = tid >> 6;
    // stage 4 tokens of x (32 KB)
    for (int i = tid; i < 4 * 512; i += 256) {
        int tok = i >> 9, kq = i & 511;
        ((f32x4*)&xs[tok][0])[kq] = ((const f32x4*)(x + (long)(t0 + tok) * 2048))[kq];
    }
    __syncthreads();
    const float* xr = &xs[tg][0];
    float acc = 0.f;
    for (int k = 0; k < 2048; ++k)
        acc = fmaf(xr[k], w[(long)k * 64 + o], acc);

    int hv = ((o >> 2) << 1) | (o & 1);
    bool isB = (o & 2) == 0;
    int tok = t0 + tg;
    int b = tok >> 11, s = tok & 2047;
    long oidx = ((long)b * 32 + hv) * 2048 + s;
    if (isB) {
        bt[oidx] = 1.f / (1.f + expf(-acc));
    } else {
        float xx = acc + dt_bias[hv];
        float sp = (xx > 20.f) ? xx : log1pf(expf(xx));
        gout[oidx] = -expf(a_log[hv]) * sp;
    }
}

// ------------------------------------------------------------------
// depthwise causal conv(K=4) + bias + SiLU (+ L2norm for q/k heads)
// k-head blocks ALSO emit the transposed copy khT.
// ------------------------------------------------------------------
__global__ __launch_bounds__(256) void conv_kernel(const f16* __restrict__ qkvz,
                                                   const float* __restrict__ cw,
                                                   const float* __restrict__ cb,
                                                   f16* __restrict__ qh,
                                                   f16* __restrict__ kh,
                                                   f16* __restrict__ vh,
                                                   f16* __restrict__ khT) {
    __shared__ float Lin[35 * 128];
    __shared__ float Lout[32 * 128];
    __shared__ float Lsc[32];
    int g = blockIdx.x;
    int s0 = blockIdx.y * 32;
    int b = blockIdx.z;
    int tid = threadIdx.x;
    int colbase, chbase;
    f16* outp;
    bool donorm;
    bool isk = false;
    int hk = 0;
    float nmul;
    if (g < 16) {
        colbase = g * 768; chbase = g * 128;
        outp = qh + (((long)b * 16 + g) * 2048 + s0) * 128;
        donorm = true; nmul = QSCALE;
    } else if (g < 32) {
        hk = g - 16;
        colbase = hk * 768 + 128; chbase = 2048 + hk * 128;
        outp = kh + (((long)b * 16 + hk) * 2048 + s0) * 128;
        donorm = true; nmul = 1.f; isk = true;
    } else {
        int hv = g - 32;
        colbase = (hv >> 1) * 768 + 256 + (hv & 1) * 128; chbase = 4096 + hv * 128;
        outp = vh + (((long)b * 32 + hv) * 2048 + s0) * 128;
        donorm = false; nmul = 1.f;
    }
    for (int ci = tid; ci < 35 * 16; ci += 256) {
        int sr = ci >> 4, cc = (ci & 15) * 8;
        int s = s0 + sr - 3;
        f32x4 lo = {}, hi = {};
        if (s >= 0) {
            f16x8 v = *(const f16x8*)(qkvz + ((long)b * 2048 + s) * 12288 + colbase + cc);
#pragma unroll
            for (int e = 0; e < 4; ++e) { lo[e] = (float)v[e]; hi[e] = (float)v[4 + e]; }
        }
        *(f32x4*)&Lin[sr * 128 + cc] = lo;
        *(f32x4*)&Lin[sr * 128 + cc + 4] = hi;
    }
    __syncthreads();
    int c = tid & 127, sg = tid >> 7;
    float w0 = cw[(chbase + c) * 4 + 0];
    float w1 = cw[(chbase + c) * 4 + 1];
    float w2 = cw[(chbase + c) * 4 + 2];
    float w3 = cw[(chbase + c) * 4 + 3];
    float bias = cb[chbase + c];
#pragma unroll
    for (int j = 0; j < 16; ++j) {
        int sl = sg * 16 + j;
        float v = w0 * Lin[sl * 128 + c] + w1 * Lin[(sl + 1) * 128 + c] +
                  w2 * Lin[(sl + 2) * 128 + c] + w3 * Lin[(sl + 3) * 128 + c] + bias;
        v = v / (1.f + expf(-v));  // SiLU
        Lout[sl * 128 + c] = v;
    }
    __syncthreads();
    if (donorm) {
        int token = tid >> 3, part = tid & 7;
        float ss = 0.f;
#pragma unroll
        for (int i = 0; i < 16; ++i) {
            float v = Lout[token * 128 + part * 16 + i];
            ss += v * v;
        }
        ss += __shfl_xor(ss, 1); ss += __shfl_xor(ss, 2); ss += __shfl_xor(ss, 4);
        if (part == 0) Lsc[token] = rsqrtf(ss + 1e-6f) * nmul;
        __syncthreads();
#pragma unroll
        for (int j = 0; j < 16; ++j) {
            int sl = sg * 16 + j;
            outp[(long)sl * 128 + c] = (f16)(Lout[sl * 128 + c] * Lsc[sl]);
        }
        if (isk) {
            int dk = tid >> 1, sh = tid & 1;
            f16x8 v0, v1;
#pragma unroll
            for (int i = 0; i < 8; ++i) {
                v0[i] = (f16)(Lout[(sh * 16 + i) * 128 + dk] * Lsc[sh * 16 + i]);
                v1[i] = (f16)(Lout[(sh * 16 + 8 + i) * 128 + dk] * Lsc[sh * 16 + 8 + i]);
            }
            f16* kt = khT + ((long)(b * 16 + hk) * 128 + dk) * 2048 + s0 + sh * 16;
            *(f16x8*)kt = v0;
            *(f16x8*)(kt + 8) = v1;
        }
    } else {
#pragma unroll
        for (int j = 0; j < 16; ++j) {
            int sl = sg * 16 + j;
            outp[(long)sl * 128 + c] = (f16)Lout[sl * 128 + c];
        }
    }
}

// ------------------------------------------------------------------
// chunk_pre: per (b,hv,chunk of 32) — one wave.
// ------------------------------------------------------------------
__global__ __launch_bounds__(64) void chunk_pre_kernel(const f16* __restrict__ qh,
                                                       const f16* __restrict__ kh,
                                                       const f16* __restrict__ vh,
                                                       const float* __restrict__ gb,
                                                       const float* __restrict__ bt,
                                                       f16* __restrict__ Wg,
                                                       f16* __restrict__ T2ng,
                                                       f16* __restrict__ d0g,
                                                       float* __restrict__ pvg) {
    __shared__ f16 VTl[128 * 32];
    __shared__ float KKl[32 * 32];
    __shared__ float RL[32 * 32];
    __shared__ float Tf[32 * 33];
    __shared__ f16 Tl[32 * 64];
    __shared__ float cuml[32], bl[32], pl[32];

    int bid = blockIdx.x;
    int chunk = bid & 63;
    int hv = (bid >> 6) & 31;
    int b = bid >> 11;
    int bh = b * 16 + (hv >> 1);
    int l = threadIdx.x;
    int h = l >> 4, c = l & 15;
    long chid = bid;

    const f16* kbase = kh + ((long)bh * 2048 + chunk * 32) * 128;
    const f16* qbase = qh + ((long)bh * 2048 + chunk * 32) * 128;
    const f16* vbase = vh + (((long)b * 32 + hv) * 2048 + chunk * 32) * 128;
    const float* gp = gb + ((long)b * 32 + hv) * 2048 + chunk * 32;
    const float* bp = bt + ((long)b * 32 + hv) * 2048 + chunk * 32;

    f16x8 fk[2][4], fq[2][4];
#pragma unroll
    for (int ti = 0; ti < 2; ++ti)
#pragma unroll
        for (int kk = 0; kk < 4; ++kk) {
            fk[ti][kk] = *(const f16x8*)(kbase + (c + 16 * ti) * 128 + kk * 32 + h * 8);
            fq[ti][kk] = *(const f16x8*)(qbase + (c + 16 * ti) * 128 + kk * 32 + h * 8);
        }

    float gv = (l < 32) ? gp[l] : 0.f;
#pragma unroll
    for (int d = 1; d < 32; d <<= 1) {
        float t2 = __shfl_up(gv, d);
        if (l >= d) gv += t2;
    }
    if (l < 32) { cuml[l] = gv; bl[l] = bp[l]; pl[l] = expf(gv); }
    __syncthreads();

#pragma unroll
    for (int it = 0; it < 8; ++it) {
        int idx = (l + it * 64) * 8;
        int row = idx >> 7, col = idx & 127;
        f16x8 v = *(const f16x8*)(vbase + (long)row * 128 + col);
        float be = bl[row];
#pragma unroll
        for (int e = 0; e < 8; ++e) {
            int dv = col + e;
            int byte = (dv * 64 + row * 2) ^ ((dv & 3) << 4);
            *(f16*)((char*)VTl + byte) = (f16)((float)v[e] * be);
        }
    }
#pragma unroll
    for (int it = 0; it < 16; ++it) {
        int e = l * 16 + it;
        int i = e >> 5, j = e & 31;
        RL[e] = (j <= i) ? expf(cuml[i] - cuml[j]) : 0.f;
    }
    __syncthreads();

    {
        f32x4 acc[2][2] = {};
#pragma unroll
        for (int kk = 0; kk < 4; ++kk) {
            acc[0][0] = __builtin_amdgcn_mfma_f32_16x16x32_f16(fk[0][kk], fk[0][kk], acc[0][0], 0, 0, 0);
            acc[0][1] = __builtin_amdgcn_mfma_f32_16x16x32_f16(fk[0][kk], fk[1][kk], acc[0][1], 0, 0, 0);
            acc[1][0] = __builtin_amdgcn_mfma_f32_16x16x32_f16(fk[1][kk], fk[0][kk], acc[1][0], 0, 0, 0);
            acc[1][1] = __builtin_amdgcn_mfma_f32_16x16x32_f16(fk[1][kk], fk[1][kk], acc[1][1], 0, 0, 0);
        }
#pragma unroll
        for (int ti = 0; ti < 2; ++ti)
#pragma unroll
            for (int tj = 0; tj < 2; ++tj)
#pragma unroll
                for (int r = 0; r < 4; ++r)
                    KKl[(h * 4 + r + 16 * ti) * 32 + c + 16 * tj] = acc[ti][tj][r];
    }
    {
        f32x4 acc[2][2] = {};
#pragma unroll
        for (int kk = 0; kk < 4; ++kk) {
            acc[0][0] = __builtin_amdgcn_mfma_f32_16x16x32_f16(fq[0][kk], fk[0][kk], acc[0][0], 0, 0, 0);
            acc[0][1] = __builtin_amdgcn_mfma_f32_16x16x32_f16(fq[0][kk], fk[1][kk], acc[0][1], 0, 0, 0);
            acc[1][0] = __builtin_amdgcn_mfma_f32_16x16x32_f16(fq[1][kk], fk[0][kk], acc[1][0], 0, 0, 0);
            acc[1][1] = __builtin_amdgcn_mfma_f32_16x16x32_f16(fq[1][kk], fk[1][kk], acc[1][1], 0, 0, 0);
        }
        __syncthreads();
#pragma unroll
        for (int ti = 0; ti < 2; ++ti)
#pragma unroll
            for (int tj = 0; tj < 2; ++tj)
#pragma unroll
                for (int r = 0; r < 4; ++r) {
                    int i = h * 4 + r + 16 * ti, j = c + 16 * tj;
                    Wg[chid * 1024 + i * 32 + j] = (f16)(acc[ti][tj][r] * RL[i * 32 + j]);
                }
    }

    if (l < 32) {
        int j = l;
        for (int i = 0; i < 32; ++i) {
            float s = (i == j) ? 1.f : 0.f;
            float bi = bl[i];
            for (int ll = j; ll < i; ++ll)
                s -= bi * KKl[i * 32 + ll] * RL[i * 32 + ll] * Tf[ll * 33 + j];
            Tf[i * 33 + j] = s;
        }
        float bpj = bl[j] * pl[j];
        for (int i = 0; i < 32; ++i) {
            float tv = (i >= j) ? Tf[i * 33 + j] : 0.f;
            int byte = (i * 128 + j * 2) ^ ((i & 3) << 4);
            *(f16*)((char*)Tl + byte) = (f16)tv;
            T2ng[chid * 1024 + i * 32 + j] = (f16)(-tv * bpj);
        }
        pvg[chid * 64 + j] = pl[j];
        pvg[chid * 64 + 32 + j] = expf(cuml[31] - cuml[j]);
    }
    __syncthreads();

    {
        f16x8 fT[2];
#pragma unroll
        for (int ti = 0; ti < 2; ++ti) {
            int row = c + 16 * ti;
            fT[ti] = *(const f16x8*)((const char*)Tl + ((row * 128 + h * 16) ^ ((row & 3) << 4)));
        }
#pragma unroll
        for (int nj = 0; nj < 8; ++nj) {
            int dv = c + 16 * nj;
            f16x8 fv = *(const f16x8*)((const char*)VTl + ((dv * 64 + h * 16) ^ ((dv & 3) << 4)));
            f32x4 a0 = {}, a1 = {};
            a0 = __builtin_amdgcn_mfma_f32_16x16x32_f16(fT[0], fv, a0, 0, 0, 0);
            a1 = __builtin_amdgcn_mfma_f32_16x16x32_f16(fT[1], fv, a1, 0, 0, 0);
            f16x4 s0, s1;
#pragma unroll
            for (int r = 0; r < 4; ++r) { s0[r] = (f16)a0[r]; s1[r] = (f16)a1[r]; }
            *(f16x4*)(d0g + chid * 4096 + (long)dv * 32 + 4 * h) = s0;
            *(f16x4*)(d0g + chid * 4096 + (long)dv * 32 + 16 + 4 * h) = s1;
        }
    }
}

// ------------------------------------------------------------------
// sequential chunked scan: grid 512 = (b,hv,vs of 16 dv); 1 wave.
// 2-chunk register double-buffer (r16, proven).
// ------------------------------------------------------------------
struct CR {
    f16x8 fk[2][4], fq[2][4], fkt[8], fT[2], fW[2];
    f16x4 fd0[2];
    f32x4 pva, pvb, kwa, kwb;
    float pc;
};

__global__ __launch_bounds__(64, 1) void scan_kernel(const f16* __restrict__ qh,
                                                     const f16* __restrict__ kh,
                                                     const f16* __restrict__ khT,
                                                     const f16* __restrict__ Wg,
                                                     const f16* __restrict__ T2ng,
                                                     const f16* __restrict__ d0g,
                                                     const float* __restrict__ pvg,
                                                     f16* __restrict__ ob) {
    __shared__ f16 Sl[2][16 * 128];
    __shared__ f16 AKl[16 * 32];
    __shared__ f16 Dl[16 * 32];

    int pbid = blockIdx.x;
    int bid = (pbid & 7) * 64 + (pbid >> 3);
    int vs = bid & 7;
    int hv = (bid >> 3) & 31;
    int b = bid >> 8;
    int bh32 = b * 32 + hv;
    int bh = b * 16 + (hv >> 1);
    int l = threadIdx.x, h = l >> 4, c = l & 15;

    const f16* kb = kh + (long)bh * 2048 * 128;
    const f16* qb = qh + (long)bh * 2048 * 128;
    const f16* ktb = khT + (long)bh * 128 * 2048;

    f16x8 z = {};
#pragma unroll
    for (int it = 0; it < 4; ++it) *(f16x8*)((char*)Sl[0] + (l + it * 64) * 16) = z;

    int cur = 0;

    auto loadC = [&](CR& R, int ch) {
        long chid = (long)bh32 * 64 + ch;
#pragma unroll
        for (int ti = 0; ti < 2; ++ti) {
            long row = (long)ch * 32 + c + 16 * ti;
#pragma unroll
            for (int kk = 0; kk < 4; ++kk) {
                R.fk[ti][kk] = *(const f16x8*)(kb + row * 128 + kk * 32 + h * 8);
                R.fq[ti][kk] = *(const f16x8*)(qb + row * 128 + kk * 32 + h * 8);
            }
            R.fT[ti] = *(const f16x8*)(T2ng + chid * 1024 + (c + 16 * ti) * 32 + h * 8);
            R.fW[ti] = *(const f16x8*)(Wg + chid * 1024 + (c + 16 * ti) * 32 + h * 8);
        }
#pragma unroll
        for (int ti = 0; ti < 8; ++ti)
            R.fkt[ti] = *(const f16x8*)(ktb + (long)(c + 16 * ti) * 2048 + ch * 32 + h * 8);
#pragma unroll
        for (int ti = 0; ti < 2; ++ti)
            R.fd0[ti] = *(const f16x4*)(d0g + chid * 4096 +
                                        (long)(vs * 16 + c) * 32 + 16 * ti + 4 * h);
        R.pva = *(const f32x4*)(pvg + chid * 64 + 4 * h);
        R.pvb = *(const f32x4*)(pvg + chid * 64 + 16 + 4 * h);
        R.pc = pvg[chid * 64 + 31];
        R.kwa = *(const f32x4*)(pvg + chid * 64 + 32 + h * 8);
        R.kwb = *(const f32x4*)(pvg + chid * 64 + 36 + h * 8);
    };

    auto computeC = [&](const CR& R, int ch) {
        const int dv = c;
        f16x8 fS[4];
#pragma unroll
        for (int kk = 0; kk < 4; ++kk)
            fS[kk] = *(const f16x8*)((char*)Sl[cur] +
                                     (dv * 256 + ((kk * 64 + h * 16) ^ ((dv & 7) << 4))));
        f32x4 AK[2] = {}, AQ[2] = {};
#pragma unroll
        for (int ti = 0; ti < 2; ++ti)
#pragma unroll
            for (int kk = 0; kk < 4; ++kk) {
                AK[ti] = __builtin_amdgcn_mfma_f32_16x16x32_f16(R.fk[ti][kk], fS[kk], AK[ti], 0, 0, 0);
                AQ[ti] = __builtin_amdgcn_mfma_f32_16x16x32_f16(R.fq[ti][kk], fS[kk], AQ[ti], 0, 0, 0);
            }
#pragma unroll
        for (int ti = 0; ti < 2; ++ti) {
            f16x4 t;
#pragma unroll
            for (int r = 0; r < 4; ++r) t[r] = (f16)AK[ti][r];
            *(f16x4*)((char*)AKl + ((dv * 64 + 32 * ti + 8 * h) ^ ((dv & 3) << 4))) = t;
        }
        f32x4 Dv[2];
#pragma unroll
        for (int ti = 0; ti < 2; ++ti)
#pragma unroll
            for (int r = 0; r < 4; ++r) Dv[ti][r] = (float)R.fd0[ti][r];
        {
            f16x8 fak = *(const f16x8*)((char*)AKl + ((dv * 64 + h * 16) ^ ((dv & 3) << 4)));
#pragma unroll
            for (int ti = 0; ti < 2; ++ti)
                Dv[ti] = __builtin_amdgcn_mfma_f32_16x16x32_f16(R.fT[ti], fak, Dv[ti], 0, 0, 0);
        }
#pragma unroll
        for (int ti = 0; ti < 2; ++ti) {
            f16x4 t;
#pragma unroll
            for (int r = 0; r < 4; ++r) t[r] = (f16)Dv[ti][r];
            *(f16x4*)((char*)Dl + ((dv * 64 + 32 * ti + 8 * h) ^ ((dv & 3) << 4))) = t;
        }
        f16x8 fdl = *(const f16x8*)((char*)Dl + ((dv * 64 + h * 16) ^ ((dv & 3) << 4)));
        f32x4 Ov[2];
#pragma unroll
        for (int ti = 0; ti < 2; ++ti)
#pragma unroll
            for (int r = 0; r < 4; ++r)
                Ov[ti][r] = AQ[ti][r] * (ti ? R.pvb[r] : R.pva[r]);
#pragma unroll
        for (int ti = 0; ti < 2; ++ti)
            Ov[ti] = __builtin_amdgcn_mfma_f32_16x16x32_f16(R.fW[ti], fdl, Ov[ti], 0, 0, 0);
#pragma unroll
        for (int ti = 0; ti < 2; ++ti)
#pragma unroll
            for (int r = 0; r < 4; ++r) {
                long tok = (long)b * 2048 + ch * 32 + 16 * ti + 4 * h + r;
                ob[tok * 4096 + hv * 128 + vs * 16 + c] = (f16)Ov[ti][r];
            }
#pragma unroll
        for (int ti = 0; ti < 8; ++ti) {
            f16x8 fa;
#pragma unroll
            for (int e = 0; e < 8; ++e)
                fa[e] = (f16)((float)R.fkt[ti][e] * (e < 4 ? R.kwa[e] : R.kwb[e - 4]));
            int sbyte = (dv * 256 + (32 * ti + 8 * h)) ^ ((dv & 7) << 4);
            f16x4 sold = *(const f16x4*)((char*)Sl[cur] + sbyte);
            f32x4 acc;
#pragma unroll
            for (int r = 0; r < 4; ++r) acc[r] = R.pc * (float)sold[r];
            acc = __builtin_amdgcn_mfma_f32_16x16x32_f16(fa, fdl, acc, 0, 0, 0);
            f16x4 snew;
#pragma unroll
            for (int r = 0; r < 4; ++r) snew[r] = (f16)acc[r];
            *(f16x4*)((char*)Sl[cur ^ 1] + sbyte) = snew;
        }
        cur ^= 1;
        RAW_BARRIER();
    };

    CR A, B;
    loadC(A, 0);
    RAW_BARRIER();  // covers the Sl[0] zero-init ds_writes
    for (int ch = 0; ch < 64; ch += 2) {
        loadC(B, ch + 1);
        computeC(A, ch);
        loadC(A, ch + 2 < 64 ? ch + 2 : 63);
        computeC(B, ch + 1);
    }
}

// ------------------------------------------------------------------
// y = rmsnorm(o * silu(z)) * norm_w  -> f16  (vectorized f16x8)
// ------------------------------------------------------------------
__global__ __launch_bounds__(256) void gate_kernel(const f16* __restrict__ o,
                                                   const f16* __restrict__ qkvz,
                                                   const float* __restrict__ norm_w,
                                                   f16* __restrict__ y) {
    int token = blockIdx.x;  // b*2048 + s
    int tid = threadIdx.x;
    int hv = tid >> 3, part = tid & 7;
    int dv0 = part * 16;
    const f16* orow = o + ((long)token * 32 + hv) * 128 + dv0;
    long zcol = (long)(hv >> 1) * 768 + 512 + (hv & 1) * 128 + dv0;
    const f16* zrow = qkvz + (long)token * 12288 + zcol;
    f16x8 ov0 = *(const f16x8*)orow, ov1 = *(const f16x8*)(orow + 8);
    f16x8 zv0 = *(const f16x8*)zrow, zv1 = *(const f16x8*)(zrow + 8);
    float yv[16];
    float ss = 0.f;
#pragma unroll
    for (int i = 0; i < 16; ++i) {
        float ovf = (float)(i < 8 ? ov0[i] : ov1[i - 8]);
        float zvf = (float)(i < 8 ? zv0[i] : zv1[i - 8]);
        float gt = zvf / (1.f + expf(-zvf));
        float v = ovf * gt;
        yv[i] = v;
        ss += v * v;
    }
    ss += __shfl_xor(ss, 1); ss += __shfl_xor(ss, 2); ss += __shfl_xor(ss, 4);
    float scale = rsqrtf(ss * (1.f / 128.f) + 1e-6f);
    f16* yrow = y + (long)token * 4096 + hv * 128 + dv0;
    f16x8 y0, y1;
#pragma unroll
    for (int i = 0; i < 8; ++i) {
        y0[i] = (f16)(yv[i] * scale * norm_w[dv0 + i]);
        y1[i] = (f16)(yv[8 + i] * scale * norm_w[dv0 + 8 + i]);
    }
    *(f16x8*)yrow = y0;
    *(f16x8*)(yrow + 8) = y1;
}

// ------------------------------------------------------------------
// Workspace (242 MB, time-aliased) — lifetime-audited (r15/r16 layout).
// ------------------------------------------------------------------
extern "C" void kernel_launch(void* const* d_in, const int* in_sizes, int n_in,
                              void* d_out, int out_size, void* d_ws, size_t ws_size,
                              hipStream_t stream) {
    const float* x       = (const float*)d_in[0];
    const float* w_qkvz  = (const float*)d_in[1];
    const float* w_ba    = (const float*)d_in[2];
    const float* conv_w  = (const float*)d_in[3];
    const float* conv_b  = (const float*)d_in[4];
    const float* a_log   = (const float*)d_in[5];
    const float* dt_bias = (const float*)d_in[6];
    const float* norm_w  = (const float*)d_in[7];
    const float* w_o     = (const float*)d_in[8];
    float* out = (float*)d_out;

    char* ws = (char*)d_ws;
    const size_t MB = 1024 * 1024;
    f16*   qkvz16 = (f16*)ws;
    f16*   x16    = (f16*)(ws + 96 * MB);
    f16*   WT     = (f16*)(ws + 112 * MB);
    f16*   d0g    = (f16*)(ws + 96 * MB);
    f16*   Wg     = (f16*)(ws + 128 * MB);
    f16*   T2ng   = (f16*)(ws + 136 * MB);
    f16*   khT    = (f16*)(ws + 144 * MB);
    f16*   WTo    = (f16*)(ws + 160 * MB);
    f16*   qh     = (f16*)(ws + 176 * MB);
    f16*   kh     = (f16*)(ws + 192 * MB);
    f16*   vh     = (f16*)(ws + 208 * MB);
    f16*   ob     = (f16*)(ws + 208 * MB);
    f16*   y16    = (f16*)(ws + 176 * MB);
    float* gbuf   = (float*)(ws + 240 * MB);
    float* btb    = (float*)(ws + 240 * MB + 512 * 1024);
    float* pvg    = (float*)(ws + 241 * MB);

    // prep
    cvt16_kernel<<<8192, 256, 0, stream>>>(x, x16, 4096 * 2048 / 4);
    transpose16_kernel<<<dim3(12288 / 64, 2048 / 64), 256, 0, stream>>>(w_qkvz, WT, 2048, 12288);
    transpose16_kernel<<<dim3(2048 / 64, 4096 / 64), 256, 0, stream>>>(w_o, WTo, 4096, 2048);

    // qkvz = x @ w_qkvz  (256x256 deep-pipelined, MFMA-first schedule)
    gemm256_kernel<4, 1><<<dim3(12288 / 256, 4096 / 256), 512, 0, stream>>>(x16, WT, qkvz16, 4096, 12288, 2048);
    // ba = x @ w_ba  (fused g/beta epilogue, 4 blocks/CU)
    ba_gemm_kernel<<<1024, 256, 0, stream>>>(x, w_ba, a_log, dt_bias, gbuf, btb);

    // conv + silu + l2norm (+ fused khT transpose for k-heads)
    conv_kernel<<<dim3(64, 64, 2), 256, 0, stream>>>(qkvz16, conv_w, conv_b, qh, kh, vh, khT);
    // per-chunk UT-transform precompute
    chunk_pre_kernel<<<4096, 64, 0, stream>>>(qh, kh, vh, gbuf, btb, Wg, T2ng, d0g, pvg);
    // sequential chunked MFMA scan (register double-buffered chunk loads)
    scan_kernel<<<512, 64, 0, stream>>>(qh, kh, khT, Wg, T2ng, d0g, pvg, ob);

    // gating + rmsnorm -> y16
    gate_kernel<<<4096, 256, 0, stream>>>(ob, qkvz16, norm_w, y16);

    // out = y @ w_o  (256x128 deep-pipelined, f32 out)
    gemm256_kernel<2, 0><<<dim3(2048 / 128, 4096 / 256), 512, 0, stream>>>(y16, WTo, out, 4096, 2048, 4096);
}